// Round 15
// baseline (212.896 us; speedup 1.0000x reference)
//
#include <hip/hip_runtime.h>
#include <cmath>

typedef unsigned short u16;
typedef __attribute__((ext_vector_type(8))) short bf16x8;
typedef __attribute__((ext_vector_type(4))) float f32x4;
typedef __attribute__((ext_vector_type(8))) unsigned short u16x8;

#define B_  32
#define N_  1024
#define L_  256
#define S_  8
#define DT_ 512
#define BAND_ 16

__device__ __forceinline__ u16 f2bf(float f) {
  union { float f; unsigned u; } x; x.f = f;
  unsigned r = (x.u + 0x7fffu + ((x.u >> 16) & 1u)) >> 16;
  return (u16)r;
}
__device__ __forceinline__ float bf2f(u16 h) {
  union { unsigned u; float f; } x; x.u = ((unsigned)h) << 16;
  return x.f;
}
// packed f32x2 -> bf16x2 (RNE), 1 instr
__device__ __forceinline__ unsigned cvtpk(float lo, float hi) {
  unsigned r;
  asm volatile("v_cvt_pk_bf16_f32 %0, %1, %2" : "=v"(r) : "v"(lo), "v"(hi));
  return r;
}

#define B1_WAIT(N)                                       \
  asm volatile("s_waitcnt vmcnt(" #N ")" ::: "memory");  \
  __builtin_amdgcn_s_barrier();                          \
  __builtin_amdgcn_sched_barrier(0);
#define B2_BAR()                                         \
  __builtin_amdgcn_sched_barrier(0);                     \
  __builtin_amdgcn_s_barrier();

// ---------------------------------------------------------------------------
// All small weights in one launch.
// ---------------------------------------------------------------------------
__global__ __launch_bounds__(256) void cvt_weights(
    const float* __restrict__ e, const float* __restrict__ q,
    const float* __restrict__ k, const float* __restrict__ v,
    const float* __restrict__ t, const float* __restrict__ pw,
    u16* __restrict__ eo, u16* __restrict__ qo, u16* __restrict__ kvo,
    u16* __restrict__ to, u16* __restrict__ po) {
  int i = blockIdx.x * 256 + threadIdx.x;
  const float* src; u16* dst; int soff, doff;
  if (i < 131072)      { src = e;  dst = eo;  soff = i;          doff = soff; }
  else if (i < 196608) { src = q;  dst = qo;  soff = i - 131072; doff = soff; }
  else if (i < 262144) { src = k;  dst = kvo; soff = i - 196608; doff = soff; }
  else if (i < 327680) { src = v;  dst = kvo; soff = i - 262144; doff = soff + 65536; }
  else if (i < 393216) { src = t;  dst = to;  soff = i - 327680; doff = soff; }
  else                 { src = pw; dst = po;  soff = i - 393216; doff = soff; }
  float4 vv = ((const float4*)src)[soff];
  ushort4 o;
  o.x = f2bf(vv.x); o.y = f2bf(vv.y); o.z = f2bf(vv.z); o.w = f2bf(vv.w);
  ((ushort4*)dst)[doff] = o;
}

// ---------------------------------------------------------------------------
// K1: gather emb rows, depthwise conv, silu, means
// ---------------------------------------------------------------------------
__global__ __launch_bounds__(256) void text_front(
    const int* __restrict__ ids, const float* __restrict__ emb,
    const float* __restrict__ dwk, u16* __restrict__ shm,
    float* __restrict__ mbuf) {
  int bl = blockIdx.x;
  int tid = threadIdx.x;
  __shared__ int sid[S_];
  if (tid < S_) sid[tid] = ids[bl * S_ + tid];
  __syncthreads();
  for (int c = tid; c < DT_; c += 256) {
    float x[S_];
#pragma unroll
    for (int s = 0; s < S_; ++s) x[s] = emb[(size_t)sid[s] * DT_ + c];
    float k0 = dwk[c * 3 + 0], k1 = dwk[c * 3 + 1], k2 = dwk[c * 3 + 2];
    float me = 0.f, sh = 0.f;
#pragma unroll
    for (int s = 0; s < S_; ++s) {
      float xm = (s > 0) ? x[s - 1] : 0.0f;
      float xp = (s < S_ - 1) ? x[s + 1] : 0.0f;
      float h = k0 * xm + k1 * x[s] + k2 * xp;
      float si = h / (1.0f + expf(-h));  // silu
      me += x[s];
      sh += si;
    }
    shm[(size_t)bl * DT_ + c] = f2bf(sh * (1.0f / S_));
    mbuf[(size_t)bl * DT_ + c] = me * (1.0f / S_);
  }
}

// ---------------------------------------------------------------------------
// KV GEMM, 256x256 tile, BK=32, 8 waves, 4-deep LDS ring, counted vmcnt,
// FUSED f32->bf16 on A: reg-staged 3 steps ahead, cvt_pk + swizzled ds_write
// one group before use. B via global_load_lds with source swizzle.
// LDS image (A and B): chunk kc of row r stored at position kc^((r>>1)&3);
// frag reads apply the matching XOR (conflict-free, verified r14).
// Ledger (steady, group s): queue [B(s+1)2,A(s+2)4,B(s+2)2,A(s+3)4,B(s+3)2]
// -> vmcnt(8) drains B(s+1)+A(s+2); WRITEA(s+2). Tails 2/2/0.
// C_bf16 = A_f32 @ B_bf16^T. Grid (N/256, M/256). K == 512 (nt == 16).
// ---------------------------------------------------------------------------
__global__ __launch_bounds__(512) void gemm_kv_8ph(
    const float* __restrict__ A, const u16* __restrict__ B,
    u16* __restrict__ Cb, int M, int N, int K) {
  __shared__ u16 As[32768];  // [4 ring][256][32] bf16
  __shared__ u16 Bs[32768];
  const int tid = threadIdx.x;
  const int w = tid >> 6;
  const int lane = tid & 63;
  const int wm = w >> 2, wn = w & 3;

  const int gx = gridDim.x;  // N/256
  const int bid = blockIdx.y * gx + blockIdx.x;
  const int nwg = gx * gridDim.y;
  const int logical = (bid & 7) * (nwg >> 3) + (bid >> 3);
  const int bm = (logical / gx) << 8;
  const int bn = (logical % gx) << 8;

  // ---- A reg-staging: thread t covers row t>>1, f32 cols (t&1)*16..+15 ----
  const int arow = tid >> 1;
  const float* Ap = A + (size_t)(bm + arow) * K + ((tid & 1) << 4);
  // write offsets (u16 units), chunk c placed at c^swz within row
  const int ac0 = (tid & 1) << 1;            // global 16B-chunk idx (0 or 2)
  const int aswz = (arow >> 1) & 3;
  const int woff0 = (arow << 5) + (((ac0 + 0) ^ aswz) << 3);
  const int woff1 = (arow << 5) + (((ac0 + 1) ^ aswz) << 3);

  // ---- B staging via global_load_lds (source swizzled) ----
  const int rowS0 = (w << 5) + (lane >> 2);
  const int rowS1 = rowS0 + 16;
  const int gac = (((lane & 3) ^ ((lane >> 3) & 3)) << 3);
  const u16* BgS0 = B + (size_t)(bn + rowS0) * K + gac;
  const u16* BgS1 = B + (size_t)(bn + rowS1) * K + gac;
  const int ldsS0 = (w << 10) + 0;
  const int ldsS1 = (w << 10) + 512;

  float4 sreg[2][4];  // two reg sets, parity = step&1; all indices constant

#define LOADA(P, step)                                        \
  sreg[P][0] = *(const float4*)(Ap + ((step) << 5));          \
  sreg[P][1] = *(const float4*)(Ap + ((step) << 5) + 4);      \
  sreg[P][2] = *(const float4*)(Ap + ((step) << 5) + 8);      \
  sreg[P][3] = *(const float4*)(Ap + ((step) << 5) + 12);
#define WRITEA(P, step)                                       \
  {                                                           \
    uint4 q0, q1;                                             \
    q0.x = cvtpk(sreg[P][0].x, sreg[P][0].y);                 \
    q0.y = cvtpk(sreg[P][0].z, sreg[P][0].w);                 \
    q0.z = cvtpk(sreg[P][1].x, sreg[P][1].y);                 \
    q0.w = cvtpk(sreg[P][1].z, sreg[P][1].w);                 \
    q1.x = cvtpk(sreg[P][2].x, sreg[P][2].y);                 \
    q1.y = cvtpk(sreg[P][2].z, sreg[P][2].w);                 \
    q1.z = cvtpk(sreg[P][3].x, sreg[P][3].y);                 \
    q1.w = cvtpk(sreg[P][3].z, sreg[P][3].w);                 \
    u16* ab = As + (((step) & 3) << 13);                      \
    *(uint4*)(ab + woff0) = q0;                               \
    *(uint4*)(ab + woff1) = q1;                               \
  }
#define STAGEB(step)                                                          \
  {                                                                           \
    const int bufo_ = ((step) & 3) << 13;                                     \
    const int ks_ = (step) << 5;                                              \
    __builtin_amdgcn_global_load_lds(                                         \
        (const __attribute__((address_space(1))) void*)(BgS0 + ks_),          \
        (__attribute__((address_space(3))) void*)(Bs + bufo_ + ldsS0), 16, 0, 0); \
    __builtin_amdgcn_global_load_lds(                                         \
        (const __attribute__((address_space(1))) void*)(BgS1 + ks_),          \
        (__attribute__((address_space(3))) void*)(Bs + bufo_ + ldsS1), 16, 0, 0); \
  }

  // frag read offsets (u16 units), swizzled read
  const int kg = lane >> 4;
  int aoff[8], boff[4];
#pragma unroll
  for (int m = 0; m < 8; ++m) {
    const int r = (wm << 7) + (m << 4) + (lane & 15);
    aoff[m] = (r << 5) + ((kg ^ ((r >> 1) & 3)) << 3);
  }
#pragma unroll
  for (int n = 0; n < 4; ++n) {
    const int r = (wn << 6) + (n << 4) + (lane & 15);
    boff[n] = (r << 5) + ((kg ^ ((r >> 1) & 3)) << 3);
  }

  f32x4 acc[8][4];
#pragma unroll
  for (int m = 0; m < 8; ++m)
#pragma unroll
    for (int n = 0; n < 4; ++n) acc[m][n] = (f32x4){0.f, 0.f, 0.f, 0.f};

#define GROUP_BODY(sbuf)                                                      \
  {                                                                           \
    const u16* Ab = As + ((sbuf) << 13);                                      \
    const u16* Bb = Bs + ((sbuf) << 13);                                      \
    bf16x8 af[8], bfr[4];                                                     \
    _Pragma("unroll")                                                         \
    for (int m = 0; m < 8; ++m) af[m] = *(const bf16x8*)(Ab + aoff[m]);       \
    _Pragma("unroll")                                                         \
    for (int n = 0; n < 4; ++n) bfr[n] = *(const bf16x8*)(Bb + boff[n]);      \
    asm volatile("s_waitcnt lgkmcnt(0)" ::: "memory");                        \
    __builtin_amdgcn_sched_barrier(0);                                        \
    __builtin_amdgcn_s_setprio(1);                                            \
    _Pragma("unroll")                                                         \
    for (int m = 0; m < 8; ++m)                                               \
      _Pragma("unroll")                                                       \
      for (int n = 0; n < 4; ++n)                                             \
        acc[m][n] = __builtin_amdgcn_mfma_f32_16x16x32_bf16(                  \
            af[m], bfr[n], acc[m][n], 0, 0, 0);                               \
    __builtin_amdgcn_s_setprio(0);                                            \
  }

  // nt == 16. Prologue: steps 0,1 to regs+write; step 2 issued.
  LOADA(0, 0)
  STAGEB(0)
  LOADA(1, 1)
  STAGEB(1)
  asm volatile("s_waitcnt vmcnt(2)" ::: "memory");  // A0,B0,A1 done; B1 flight
  __builtin_amdgcn_sched_barrier(0);
  WRITEA(0, 0)
  WRITEA(1, 1)
  LOADA(0, 2)
  STAGEB(2)
  asm volatile("s_waitcnt lgkmcnt(0)" ::: "memory");

  // groups 0..12: uniform vmcnt(8)
  for (int s = 0; s <= 12; ++s) {
    __builtin_amdgcn_s_barrier();      // prev group reads done
    LOADA((s + 3) & 1, s + 3)
    STAGEB(s + 3)
    B1_WAIT(8)                         // step s ready; A(s+2) regs landed
    WRITEA((s + 2) & 1, s + 2)
    GROUP_BODY(s & 3)
  }
  // group 13
  __builtin_amdgcn_s_barrier();
  B1_WAIT(2)                           // drains B(14), A(15); leaves B(15)
  WRITEA(1, 15)                        // 15&1 == 1
  GROUP_BODY(1)                        // 13&3
  // group 14
  __builtin_amdgcn_s_barrier();
  B1_WAIT(2)
  GROUP_BODY(2)
  // group 15
  __builtin_amdgcn_s_barrier();
  B1_WAIT(0)
  GROUP_BODY(3)
#undef GROUP_BODY
#undef STAGEB
#undef WRITEA
#undef LOADA

  const int rb = bm + (wm << 7) + ((lane >> 4) << 2);
  const int cb = bn + (wn << 6) + (lane & 15);
#pragma unroll
  for (int m = 0; m < 8; ++m)
#pragma unroll
    for (int n = 0; n < 4; ++n) {
      const int col = cb + (n << 4);
#pragma unroll
      for (int j = 0; j < 4; ++j) {
        size_t idx = (size_t)(rb + (m << 4) + j) * N + col;
        Cb[idx] = f2bf(acc[m][n][j]);
      }
    }
}

// ---------------------------------------------------------------------------
// bf16 MFMA GEMM, 128x128 tile (cls), counted-vmcnt pipeline (4 loads/STAGE).
// ---------------------------------------------------------------------------
template <bool ACC, bool WF32, bool WBF16>
__global__ __launch_bounds__(256) void gemm_mfma(
    const u16* __restrict__ A, const u16* __restrict__ B,
    float* __restrict__ C, u16* __restrict__ Cb, int M, int N, int K) {
  __shared__ u16 As[8192];
  __shared__ u16 Bs[8192];
  const int tid = threadIdx.x;
  const int w = tid >> 6;
  const int lane = tid & 63;

  const int gx = gridDim.x;
  const int bid = blockIdx.y * gx + blockIdx.x;
  const int nwg = gx * gridDim.y;
  const int logical = (bid & 7) * (nwg >> 3) + (bid >> 3);
  const int bm = (logical / gx) << 7;
  const int bn = (logical % gx) << 7;
  const int wr = w >> 1, wc = w & 1;

  const int r0 = (w << 4) + (lane >> 2);
  const int kc = (lane & 3) << 3;
  const u16* Ag0 = A + (size_t)(bm + r0) * K + kc;
  const u16* Ag1 = Ag0 + (size_t)64 * K;
  const u16* Bg0 = B + (size_t)(bn + r0) * K + kc;
  const u16* Bg1 = Bg0 + (size_t)64 * K;

  int aoff[4], boff[4];
#pragma unroll
  for (int m = 0; m < 4; ++m)
    aoff[m] = (((wr << 6) + (m << 4) + (lane & 15)) << 5) + ((lane >> 4) << 3);
#pragma unroll
  for (int n = 0; n < 4; ++n)
    boff[n] = (((wc << 6) + (n << 4) + (lane & 15)) << 5) + ((lane >> 4) << 3);

  f32x4 acc[4][4];
#pragma unroll
  for (int m = 0; m < 4; ++m)
#pragma unroll
    for (int n = 0; n < 4; ++n) acc[m][n] = (f32x4){0.f, 0.f, 0.f, 0.f};

#define STAGE(buf, kt)                                                        \
  {                                                                           \
    u16* as_ = As + (buf) * 4096 + (w << 9);                                  \
    u16* bs_ = Bs + (buf) * 4096 + (w << 9);                                  \
    __builtin_amdgcn_global_load_lds(                                         \
        (const __attribute__((address_space(1))) void*)(Ag0 + (kt)),          \
        (__attribute__((address_space(3))) void*)as_, 16, 0, 0);              \
    __builtin_amdgcn_global_load_lds(                                         \
        (const __attribute__((address_space(1))) void*)(Ag1 + (kt)),          \
        (__attribute__((address_space(3))) void*)(as_ + 2048), 16, 0, 0);     \
    __builtin_amdgcn_global_load_lds(                                         \
        (const __attribute__((address_space(1))) void*)(Bg0 + (kt)),          \
        (__attribute__((address_space(3))) void*)bs_, 16, 0, 0);              \
    __builtin_amdgcn_global_load_lds(                                         \
        (const __attribute__((address_space(1))) void*)(Bg1 + (kt)),          \
        (__attribute__((address_space(3))) void*)(bs_ + 2048), 16, 0, 0);     \
  }

  const int nt = K >> 5;
  STAGE(0, 0);
  int cur = 0;
  for (int t = 0; t < nt; ++t) {
    if (t + 1 < nt) {
      STAGE(cur ^ 1, (t + 1) << 5);
      B1_WAIT(4)
    } else {
      B1_WAIT(0)
    }
    const u16* Ab = As + cur * 4096;
    const u16* Bb = Bs + cur * 4096;
    bf16x8 af[4], bfr[4];
#pragma unroll
    for (int m = 0; m < 4; ++m) af[m] = *(const bf16x8*)(Ab + aoff[m]);
#pragma unroll
    for (int n = 0; n < 4; ++n) bfr[n] = *(const bf16x8*)(Bb + boff[n]);
#pragma unroll
    for (int m = 0; m < 4; ++m)
#pragma unroll
      for (int n = 0; n < 4; ++n)
        acc[m][n] = __builtin_amdgcn_mfma_f32_16x16x32_bf16(
            af[m], bfr[n], acc[m][n], 0, 0, 0);
    B2_BAR()
    cur ^= 1;
  }
#undef STAGE

  const int rb = bm + (wr << 6) + ((lane >> 4) << 2);
  const int cb = bn + (wc << 6) + (lane & 15);
#pragma unroll
  for (int m = 0; m < 4; ++m)
#pragma unroll
    for (int n = 0; n < 4; ++n) {
      int col = cb + (n << 4);
#pragma unroll
      for (int j = 0; j < 4; ++j) {
        size_t idx = (size_t)(rb + (m << 4) + j) * N + col;
        float v = acc[m][n][j];
        if (ACC) v += C[idx];
        if (WF32) C[idx] = v;
        if (WBF16) Cb[idx] = f2bf(v);
      }
    }
}

// ---------------------------------------------------------------------------
// bf16 MFMA GEMM, 128x64 tile for N=512 GEMMs, counted-vmcnt (3 loads/STAGE).
// ---------------------------------------------------------------------------
template <bool ACC, bool WF32, bool WBF16>
__global__ __launch_bounds__(256) void gemm_n64(
    const u16* __restrict__ A, const u16* __restrict__ B,
    float* __restrict__ C, u16* __restrict__ Cb, int M, int N, int K) {
  __shared__ u16 As[8192];  // [2][128][32]
  __shared__ u16 Bs[4096];  // [2][64][32]
  const int tid = threadIdx.x;
  const int w = tid >> 6;
  const int lane = tid & 63;

  const int gx = gridDim.x;  // N/64
  const int bid = blockIdx.y * gx + blockIdx.x;
  const int nwg = gx * gridDim.y;
  const int logical = (bid & 7) * (nwg >> 3) + (bid >> 3);
  const int bm = (logical / gx) << 7;
  const int bn = (logical % gx) << 6;

  const int r0 = (w << 4) + (lane >> 2);
  const int kc = (lane & 3) << 3;
  const u16* Ag0 = A + (size_t)(bm + r0) * K + kc;
  const u16* Ag1 = Ag0 + (size_t)64 * K;
  const u16* Bg0 = B + (size_t)(bn + r0) * K + kc;

  int aoff[2], boff[4];
#pragma unroll
  for (int m = 0; m < 2; ++m)
    aoff[m] = (((w << 5) + (m << 4) + (lane & 15)) << 5) + ((lane >> 4) << 3);
#pragma unroll
  for (int n = 0; n < 4; ++n)
    boff[n] = (((n << 4) + (lane & 15)) << 5) + ((lane >> 4) << 3);

  f32x4 acc[2][4];
#pragma unroll
  for (int m = 0; m < 2; ++m)
#pragma unroll
    for (int n = 0; n < 4; ++n) acc[m][n] = (f32x4){0.f, 0.f, 0.f, 0.f};

#define STAGE(buf, kt)                                                        \
  {                                                                           \
    u16* as_ = As + (buf) * 4096 + (w << 9);                                  \
    u16* bs_ = Bs + (buf) * 2048 + (w << 9);                                  \
    __builtin_amdgcn_global_load_lds(                                         \
        (const __attribute__((address_space(1))) void*)(Ag0 + (kt)),          \
        (__attribute__((address_space(3))) void*)as_, 16, 0, 0);              \
    __builtin_amdgcn_global_load_lds(                                         \
        (const __attribute__((address_space(1))) void*)(Ag1 + (kt)),          \
        (__attribute__((address_space(3))) void*)(as_ + 2048), 16, 0, 0);     \
    __builtin_amdgcn_global_load_lds(                                         \
        (const __attribute__((address_space(1))) void*)(Bg0 + (kt)),          \
        (__attribute__((address_space(3))) void*)bs_, 16, 0, 0);              \
  }

  const int nt = K >> 5;
  STAGE(0, 0);
  int cur = 0;
  for (int t = 0; t < nt; ++t) {
    if (t + 1 < nt) {
      STAGE(cur ^ 1, (t + 1) << 5);
      B1_WAIT(3)
    } else {
      B1_WAIT(0)
    }
    const u16* Ab = As + cur * 4096;
    const u16* Bb = Bs + cur * 2048;
    bf16x8 af[2], bfr[4];
#pragma unroll
    for (int m = 0; m < 2; ++m) af[m] = *(const bf16x8*)(Ab + aoff[m]);
#pragma unroll
    for (int n = 0; n < 4; ++n) bfr[n] = *(const bf16x8*)(Bb + boff[n]);
#pragma unroll
    for (int m = 0; m < 2; ++m)
#pragma unroll
      for (int n = 0; n < 4; ++n)
        acc[m][n] = __builtin_amdgcn_mfma_f32_16x16x32_bf16(
            af[m], bfr[n], acc[m][n], 0, 0, 0);
    B2_BAR()
    cur ^= 1;
  }
#undef STAGE

  const int rb = bm + (w << 5) + ((lane >> 4) << 2);
  const int cb = bn + (lane & 15);
#pragma unroll
  for (int m = 0; m < 2; ++m)
#pragma unroll
    for (int n = 0; n < 4; ++n) {
      int col = cb + (n << 4);
#pragma unroll
      for (int j = 0; j < 4; ++j) {
        size_t idx = (size_t)(rb + (m << 4) + j) * N + col;
        float v = acc[m][n][j];
        if (ACC) v += C[idx];
        if (WF32) C[idx] = v;
        if (WBF16) Cb[idx] = f2bf(v);
      }
    }
}

// ---------------------------------------------------------------------------
// LayerNorm over DT=512 per row; writes bf16 q_txt
// ---------------------------------------------------------------------------
__global__ __launch_bounds__(256) void ln_kernel(
    const float* __restrict__ m, const float* __restrict__ g,
    const float* __restrict__ bta, u16* __restrict__ q) {
  int row = blockIdx.x;
  int tid = threadIdx.x;
  float v0 = m[(size_t)row * 512 + tid];
  float v1 = m[(size_t)row * 512 + 256 + tid];
  __shared__ float red[4], red2[4];
  float s = v0 + v1;
#pragma unroll
  for (int d = 32; d; d >>= 1) s += __shfl_xor(s, d);
  if ((tid & 63) == 0) red[tid >> 6] = s;
  __syncthreads();
  float mu = (red[0] + red[1] + red[2] + red[3]) * (1.0f / 512.0f);
  float d0 = v0 - mu, d1 = v1 - mu;
  float s2 = d0 * d0 + d1 * d1;
#pragma unroll
  for (int d = 32; d; d >>= 1) s2 += __shfl_xor(s2, d);
  if ((tid & 63) == 0) red2[tid >> 6] = s2;
  __syncthreads();
  float var = (red2[0] + red2[1] + red2[2] + red2[3]) * (1.0f / 512.0f);
  float r = rsqrtf(var + 1e-5f);
  q[(size_t)row * 512 + tid] = f2bf(d0 * r * g[tid] + bta[tid]);
  q[(size_t)row * 512 + 256 + tid] = f2bf(d1 * r * g[tid + 256] + bta[tid + 256]);
}

// ---------------------------------------------------------------------------
// MFMA banded attention. Block = (b, 16 l), 512 threads = 8 waves.
// ---------------------------------------------------------------------------
__global__ __launch_bounds__(512) void attn_kernel(
    const u16* __restrict__ Qb, const u16* __restrict__ KV,
    const float* __restrict__ alpha_p, float* __restrict__ A,
    u16* __restrict__ Fv) {
  __shared__ u16 KV_s[96 * 512];   // 96 KB, K then reused for V
  __shared__ u16 Q_s[16 * 520];    // padded stride 520 u16
  __shared__ float S_s[16 * 100];  // logits then attention weights

  const int bid = blockIdx.x;
  const int logical = (bid & 7) * 64 + (bid >> 3);
  const int b = logical >> 4, lg = logical & 15;
  const int l0 = lg * 16;
  const int tid = threadIdx.x;
  const int w = tid >> 6, lane = tid & 63;
  const float al = *alpha_p;

  const int c_min = (1023 * l0) / 255;
  const int kb0 = min(max(c_min - BAND_, 0), N_ - 96);

  {
    const size_t rowb = (size_t)(b * N_ + kb0);
    for (int rr = 0; rr < 12; ++rr) {
      const int r = w * 12 + rr;
      const u16* src = KV + (rowb + r) * 1024 + ((lane * 8) ^ ((r & 7) << 3));
      u16* dst = KV_s + r * 512;
      __builtin_amdgcn_global_load_lds(
          (const __attribute__((address_space(1))) void*)src,
          (__attribute__((address_space(3))) void*)dst, 16, 0, 0);
    }
  }
  {
    const int r = tid >> 5;
    const u16* qrow = Qb + (size_t)(b * L_ + l0 + r) * 512;
#pragma unroll
    for (int h = 0; h < 2; ++h) {
      const int ch = (tid & 31) + h * 32;
      u16x8 v = *(const u16x8*)(qrow + ch * 8);
      *(u16x8*)(Q_s + r * 520 + ch * 8) = v;
    }
  }
  __syncthreads();

  if (w < 6) {
    f32x4 acc = {0.f, 0.f, 0.f, 0.f};
    const int arow = (lane & 15) * 520 + ((lane >> 4) << 3);
    const int key = w * 16 + (lane & 15);
    const int swz = (key & 7) << 3;
    for (int ks = 0; ks < 16; ++ks) {
      bf16x8 aq = *(const bf16x8*)(Q_s + arow + ks * 32);
      bf16x8 bk =
          *(const bf16x8*)(KV_s + key * 512 + ((ks * 32 + ((lane >> 4) << 3)) ^ swz));
      acc = __builtin_amdgcn_mfma_f32_16x16x32_bf16(aq, bk, acc, 0, 0, 0);
    }
#pragma unroll
    for (int j = 0; j < 4; ++j)
      S_s[((lane >> 4) * 4 + j) * 100 + w * 16 + (lane & 15)] = acc[j];
  }
  __syncthreads();

  {
    const size_t rowb = (size_t)(b * N_ + kb0);
    for (int rr = 0; rr < 12; ++rr) {
      const int r = w * 12 + rr;
      const u16* src =
          KV + (rowb + r) * 1024 + 512 + ((lane * 8) ^ ((r & 7) << 3));
      u16* dst = KV_s + r * 512;
      __builtin_amdgcn_global_load_lds(
          (const __attribute__((address_space(1))) void*)src,
          (__attribute__((address_space(3))) void*)dst, 16, 0, 0);
    }
  }

#pragma unroll
  for (int rr = 0; rr < 2; ++rr) {
    const int l = 2 * w + rr;
    const int c = (1023 * (l0 + l)) / 255;
    const int g0 = kb0 + lane, g1 = kb0 + 64 + lane;
    const bool v0 = (g0 >= c - BAND_) && (g0 <= c + BAND_);
    const bool v1 = (lane < 32) && (g1 >= c - BAND_) && (g1 <= c + BAND_);
    const float sc = 0.044194173824159216f;
    float x0 = v0 ? S_s[l * 100 + lane] * sc +
                        al * ((float)(c - g0) * (1.0f / 16.000001f))
                  : -INFINITY;
    float x1 = v1 ? S_s[l * 100 + 64 + lane] * sc +
                        al * ((float)(c - g1) * (1.0f / 16.000001f))
                  : -INFINITY;
    float mx = fmaxf(x0, x1);
#pragma unroll
    for (int d = 32; d; d >>= 1) mx = fmaxf(mx, __shfl_xor(mx, d));
    float e0 = v0 ? expf(x0 - mx) : 0.0f;
    float e1 = v1 ? expf(x1 - mx) : 0.0f;
    float sm = e0 + e1;
#pragma unroll
    for (int d = 32; d; d >>= 1) sm += __shfl_xor(sm, d);
    const float inv = 1.0f / sm;
    S_s[l * 100 + lane] = e0 * inv;
    if (lane < 32) S_s[l * 100 + 64 + lane] = e1 * inv;
    const int lo = max(0, c - BAND_), hi = min(N_ - 1, c + BAND_);
    float* Arow = A + (size_t)(b * L_ + l0 + l) * N_;
#pragma unroll
    for (int p4 = 0; p4 < 4; ++p4) {
      const int p = (p4 * 64 + lane) * 4;
      float4 v;
      v.x = (p + 0 >= lo && p + 0 <= hi) ? S_s[l * 100 + p + 0 - kb0] : 0.0f;
      v.y = (p + 1 >= lo && p + 1 <= hi) ? S_s[l * 100 + p + 1 - kb0] : 0.0f;
      v.z = (p + 2 >= lo && p + 2 <= hi) ? S_s[l * 100 + p + 2 - kb0] : 0.0f;
      v.w = (p + 3 >= lo && p + 3 <= hi) ? S_s[l * 100 + p + 3 - kb0] : 0.0f;
      ((float4*)Arow)[p4 * 64 + lane] = v;
    }
  }
  __syncthreads();

#pragma unroll
  for (int rr = 0; rr < 2; ++rr) {
    const int l = 2 * w + rr;
    const int c = (1023 * (l0 + l)) / 255;
    const int jlo = max(0, c - BAND_) - kb0, jhi = min(N_ - 1, c + BAND_) - kb0;
    float acc[8] = {};
    for (int j = jlo; j <= jhi; ++j) {
      const float avj = S_s[l * 100 + j];
      const u16x8 v =
          *(const u16x8*)(KV_s + j * 512 + ((lane * 8) ^ ((j & 7) << 3)));
#pragma unroll
      for (int t = 0; t < 8; ++t) acc[t] += avj * bf2f(v[t]);
    }
    u16x8 fo;
#pragma unroll
    for (int t = 0; t < 8; ++t) fo[t] = f2bf(acc[t]);
    *(u16x8*)(Fv + (size_t)(b * L_ + l0 + l) * 512 + lane * 8) = fo;
  }
}

// ---------------------------------------------------------------------------
extern "C" void kernel_launch(void* const* d_in, const int* in_sizes, int n_in,
                              void* d_out, int out_size, void* d_ws,
                              size_t ws_size, hipStream_t stream) {
  const float* vis = (const float*)d_in[0];    // [32,1024,512]
  const int* ids = (const int*)d_in[1];        // [32,256,8]
  const float* emb = (const float*)d_in[2];    // [1024,512]
  const float* wq = (const float*)d_in[3];     // [512,512]
  const float* wk = (const float*)d_in[4];     // [512,512]
  const float* wvp = (const float*)d_in[5];    // [512,512]
  const float* wv2t = (const float*)d_in[6];   // [512,512]
  const float* dwk = (const float*)d_in[7];    // [512,1,3]
  const float* pwk = (const float*)d_in[8];    // [512,512,1]
  const float* lng = (const float*)d_in[9];    // [512]
  const float* lnb = (const float*)d_in[10];   // [512]
  const float* alpha = (const float*)d_in[11]; // scalar

  float* out_cls = (float*)d_out;                // [8192,1024]
  float* out_H = out_cls + (size_t)8192 * 1024;  // [8192,512]
  float* out_A = out_H + (size_t)8192 * 512;     // [8192,1024]

  // workspace layout
  char* p = (char*)d_ws;
  u16* KVb  = (u16*)p;              p += (size_t)32768 * 1024 * 2;
  u16* embb = (u16*)p;              p += (size_t)1024 * 512 * 2;
  u16* wqb  = (u16*)p;              p += (size_t)512 * 512 * 2;
  u16* wkvb = (u16*)p;              p += (size_t)1024 * 512 * 2;
  u16* wv2tb= (u16*)p;              p += (size_t)512 * 512 * 2;
  u16* pwkb = (u16*)p;              p += (size_t)512 * 512 * 2;
  u16* shmb = (u16*)p;              p += (size_t)8192 * 512 * 2;
  float* mbuf = (float*)p;          p += (size_t)8192 * 512 * 4;
  u16* qbuf = (u16*)p;              p += (size_t)8192 * 512 * 2;
  u16* Qbf  = (u16*)p;              p += (size_t)8192 * 512 * 2;
  u16* Fvb  = (u16*)p;              p += (size_t)8192 * 512 * 2;
  u16* Hb   = (u16*)p;              p += (size_t)8192 * 512 * 2;

  // small weights -> bf16
  cvt_weights<<<1792, 256, 0, stream>>>(emb, wq, wk, wvp, wv2t, pwk,
                                        embb, wqb, wkvb, wv2tb, pwkb);

  // KV = vis_f32 @ [wk;wv]^T -> bf16 [32768][1024]  (8ph ring, fused cvt)
  gemm_kv_8ph<<<dim3(4, 128), 512, 0, stream>>>(
      vis, wkvb, KVb, 32768, 1024, 512);

  // text front: gather + dwconv + silu + means
  text_front<<<8192, 256, 0, stream>>>(ids, emb, dwk, shmb, mbuf);
  // m += shm_mean @ pw^T  (pointwise conv folded through mean)
  gemm_n64<true, true, false><<<dim3(8, 64), 256, 0, stream>>>(
      shmb, pwkb, mbuf, nullptr, 8192, 512, 512);
  // LayerNorm -> q_txt (bf16)
  ln_kernel<<<8192, 256, 0, stream>>>(mbuf, lng, lnb, qbuf);
  // Q = q_txt @ wq^T (bf16 out)
  gemm_n64<false, false, true><<<dim3(8, 64), 256, 0, stream>>>(
      qbuf, wqb, nullptr, Qbf, 8192, 512, 512);
  // banded attention (MFMA) -> A (full rows, f32), Fv (bf16)
  attn_kernel<<<512, 512, 0, stream>>>(Qbf, KVb, alpha, out_A, Fvb);
  // H = Fv @ wv2t^T (f32 out + bf16 copy)
  gemm_n64<false, true, true><<<dim3(8, 64), 256, 0, stream>>>(
      Fvb, wv2tb, out_H, Hb, 8192, 512, 512);
  // cls = H @ emb^T (f32 out)
  gemm_mfma<false, true, false><<<dim3(8, 64), 256, 0, stream>>>(
      Hb, embb, out_cls, nullptr, 8192, 1024, 512);
}

// Round 16
// 212.800 us; speedup vs baseline: 1.0005x; 1.0005x over previous
//
#include <hip/hip_runtime.h>
#include <cmath>

typedef unsigned short u16;
typedef __attribute__((ext_vector_type(8))) short bf16x8;
typedef __attribute__((ext_vector_type(4))) float f32x4;
typedef __attribute__((ext_vector_type(8))) unsigned short u16x8;

#define B_  32
#define N_  1024
#define L_  256
#define S_  8
#define DT_ 512
#define BAND_ 16

__device__ __forceinline__ u16 f2bf(float f) {
  union { float f; unsigned u; } x; x.f = f;
  unsigned r = (x.u + 0x7fffu + ((x.u >> 16) & 1u)) >> 16;
  return (u16)r;
}
__device__ __forceinline__ float bf2f(u16 h) {
  union { unsigned u; float f; } x; x.u = ((unsigned)h) << 16;
  return x.f;
}

#define B1_WAIT(N)                                       \
  asm volatile("s_waitcnt vmcnt(" #N ")" ::: "memory");  \
  __builtin_amdgcn_s_barrier();                          \
  __builtin_amdgcn_sched_barrier(0);
#define B2_BAR()                                         \
  __builtin_amdgcn_sched_barrier(0);                     \
  __builtin_amdgcn_s_barrier();

// ---------------------------------------------------------------------------
// f32 -> bf16 conversion (vectorized x4)
// ---------------------------------------------------------------------------
__global__ __launch_bounds__(256) void cvt_bf16(
    const float* __restrict__ in, u16* __restrict__ out, int n4) {
  int i = blockIdx.x * 256 + threadIdx.x;
  if (i < n4) {
    float4 v = ((const float4*)in)[i];
    ushort4 o;
    o.x = f2bf(v.x); o.y = f2bf(v.y); o.z = f2bf(v.z); o.w = f2bf(v.w);
    ((ushort4*)out)[i] = o;
  }
}

// ---------------------------------------------------------------------------
// All small weights in one launch.
// ---------------------------------------------------------------------------
__global__ __launch_bounds__(256) void cvt_weights(
    const float* __restrict__ e, const float* __restrict__ q,
    const float* __restrict__ k, const float* __restrict__ v,
    const float* __restrict__ t, const float* __restrict__ pw,
    u16* __restrict__ eo, u16* __restrict__ qo, u16* __restrict__ kvo,
    u16* __restrict__ to, u16* __restrict__ po) {
  int i = blockIdx.x * 256 + threadIdx.x;
  const float* src; u16* dst; int soff, doff;
  if (i < 131072)      { src = e;  dst = eo;  soff = i;          doff = soff; }
  else if (i < 196608) { src = q;  dst = qo;  soff = i - 131072; doff = soff; }
  else if (i < 262144) { src = k;  dst = kvo; soff = i - 196608; doff = soff; }
  else if (i < 327680) { src = v;  dst = kvo; soff = i - 262144; doff = soff + 65536; }
  else if (i < 393216) { src = t;  dst = to;  soff = i - 327680; doff = soff; }
  else                 { src = pw; dst = po;  soff = i - 393216; doff = soff; }
  float4 vv = ((const float4*)src)[soff];
  ushort4 o;
  o.x = f2bf(vv.x); o.y = f2bf(vv.y); o.z = f2bf(vv.z); o.w = f2bf(vv.w);
  ((ushort4*)dst)[doff] = o;
}

// ---------------------------------------------------------------------------
// K1: gather emb rows, depthwise conv, silu, means
// ---------------------------------------------------------------------------
__global__ __launch_bounds__(256) void text_front(
    const int* __restrict__ ids, const float* __restrict__ emb,
    const float* __restrict__ dwk, u16* __restrict__ shm,
    float* __restrict__ mbuf) {
  int bl = blockIdx.x;
  int tid = threadIdx.x;
  __shared__ int sid[S_];
  if (tid < S_) sid[tid] = ids[bl * S_ + tid];
  __syncthreads();
  for (int c = tid; c < DT_; c += 256) {
    float x[S_];
#pragma unroll
    for (int s = 0; s < S_; ++s) x[s] = emb[(size_t)sid[s] * DT_ + c];
    float k0 = dwk[c * 3 + 0], k1 = dwk[c * 3 + 1], k2 = dwk[c * 3 + 2];
    float me = 0.f, sh = 0.f;
#pragma unroll
    for (int s = 0; s < S_; ++s) {
      float xm = (s > 0) ? x[s - 1] : 0.0f;
      float xp = (s < S_ - 1) ? x[s + 1] : 0.0f;
      float h = k0 * xm + k1 * x[s] + k2 * xp;
      float si = h / (1.0f + expf(-h));  // silu
      me += x[s];
      sh += si;
    }
    shm[(size_t)bl * DT_ + c] = f2bf(sh * (1.0f / S_));
    mbuf[(size_t)bl * DT_ + c] = me * (1.0f / S_);
  }
}

// ---------------------------------------------------------------------------
// KV GEMM, 256x256 tile, BK=32, 8 waves, ring-2 LDS (64KB -> 2 blocks/CU),
// counted vmcnt(4), T2 source-swizzle (conflict-free, verified r14), setprio.
// C_bf16[m][n] = sum_k A[m][k]*B[n][k]; A:[M,K], B:[N,K] bf16.
// Grid: (N/256, M/256).
// ---------------------------------------------------------------------------
__global__ __launch_bounds__(512) void gemm_kv_8ph(
    const u16* __restrict__ A, const u16* __restrict__ B,
    u16* __restrict__ Cb, int M, int N, int K) {
  __shared__ u16 As[16384];  // [2 ring][256][32]
  __shared__ u16 Bs[16384];
  const int tid = threadIdx.x;
  const int w = tid >> 6;
  const int lane = tid & 63;
  const int wm = w >> 2, wn = w & 3;

  const int gx = gridDim.x;  // N/256
  const int bid = blockIdx.y * gx + blockIdx.x;
  const int nwg = gx * gridDim.y;
  const int logical = (bid & 7) * (nwg >> 3) + (bid >> 3);
  const int bm = (logical / gx) << 8;
  const int bn = (logical % gx) << 8;

  // staging: wave w covers rows [w*32, w*32+32); source chunk swizzled
  const int rowS0 = (w << 5) + (lane >> 2);
  const int rowS1 = rowS0 + 16;
  const int gac = (((lane & 3) ^ ((lane >> 3) & 3)) << 3);  // u16 offset
  const u16* AgS0 = A + (size_t)(bm + rowS0) * K + gac;
  const u16* AgS1 = A + (size_t)(bm + rowS1) * K + gac;
  const u16* BgS0 = B + (size_t)(bn + rowS0) * K + gac;
  const u16* BgS1 = B + (size_t)(bn + rowS1) * K + gac;
  const int ldsS0 = (w << 10) + 0;
  const int ldsS1 = (w << 10) + 512;

#define STAGE(step)                                                           \
  {                                                                           \
    const int bufo_ = ((step) & 1) << 13;                                     \
    const int ks_ = (step) << 5;                                              \
    __builtin_amdgcn_global_load_lds(                                         \
        (const __attribute__((address_space(1))) void*)(AgS0 + ks_),          \
        (__attribute__((address_space(3))) void*)(As + bufo_ + ldsS0), 16, 0, 0); \
    __builtin_amdgcn_global_load_lds(                                         \
        (const __attribute__((address_space(1))) void*)(AgS1 + ks_),          \
        (__attribute__((address_space(3))) void*)(As + bufo_ + ldsS1), 16, 0, 0); \
    __builtin_amdgcn_global_load_lds(                                         \
        (const __attribute__((address_space(1))) void*)(BgS0 + ks_),          \
        (__attribute__((address_space(3))) void*)(Bs + bufo_ + ldsS0), 16, 0, 0); \
    __builtin_amdgcn_global_load_lds(                                         \
        (const __attribute__((address_space(1))) void*)(BgS1 + ks_),          \
        (__attribute__((address_space(3))) void*)(Bs + bufo_ + ldsS1), 16, 0, 0); \
  }

  // frag read offsets (u16 units, within one ring buffer), swizzled read
  const int kg = lane >> 4;
  int aoff[8], boff[4];
#pragma unroll
  for (int m = 0; m < 8; ++m) {
    const int r = (wm << 7) + (m << 4) + (lane & 15);
    aoff[m] = (r << 5) + ((kg ^ ((r >> 1) & 3)) << 3);
  }
#pragma unroll
  for (int n = 0; n < 4; ++n) {
    const int r = (wn << 6) + (n << 4) + (lane & 15);
    boff[n] = (r << 5) + ((kg ^ ((r >> 1) & 3)) << 3);
  }

  f32x4 acc[8][4];
#pragma unroll
  for (int m = 0; m < 8; ++m)
#pragma unroll
    for (int n = 0; n < 4; ++n) acc[m][n] = (f32x4){0.f, 0.f, 0.f, 0.f};

#define GROUP_BODY(sbuf)                                                      \
  {                                                                           \
    const u16* Ab = As + ((sbuf) << 13);                                      \
    const u16* Bb = Bs + ((sbuf) << 13);                                      \
    bf16x8 af[8], bfr[4];                                                     \
    _Pragma("unroll")                                                         \
    for (int m = 0; m < 8; ++m) af[m] = *(const bf16x8*)(Ab + aoff[m]);       \
    _Pragma("unroll")                                                         \
    for (int n = 0; n < 4; ++n) bfr[n] = *(const bf16x8*)(Bb + boff[n]);      \
    asm volatile("s_waitcnt lgkmcnt(0)" ::: "memory");                        \
    __builtin_amdgcn_sched_barrier(0);                                        \
    __builtin_amdgcn_s_setprio(1);                                            \
    _Pragma("unroll")                                                         \
    for (int m = 0; m < 8; ++m)                                               \
      _Pragma("unroll")                                                       \
      for (int n = 0; n < 4; ++n)                                             \
        acc[m][n] = __builtin_amdgcn_mfma_f32_16x16x32_bf16(                  \
            af[m], bfr[n], acc[m][n], 0, 0, 0);                               \
    __builtin_amdgcn_s_setprio(0);                                            \
  }

  const int nt = K >> 5;  // 16
  STAGE(0)
  for (int s = 0; s < nt; ++s) {
    __builtin_amdgcn_s_barrier();  // group s-1 reads done (regs landed pre-MFMA)
    if (s + 1 < nt) {
      STAGE(s + 1)
      B1_WAIT(4)                   // step s landed; s+1 stays in flight
    } else {
      B1_WAIT(0)
    }
    GROUP_BODY(s & 1)
  }
#undef GROUP_BODY
#undef STAGE

  // epilogue: C/D layout col=lane&15, row=(lane>>4)*4+j
  const int rb = bm + (wm << 7) + ((lane >> 4) << 2);
  const int cb = bn + (wn << 6) + (lane & 15);
#pragma unroll
  for (int m = 0; m < 8; ++m)
#pragma unroll
    for (int n = 0; n < 4; ++n) {
      const int col = cb + (n << 4);
#pragma unroll
      for (int j = 0; j < 4; ++j) {
        size_t idx = (size_t)(rb + (m << 4) + j) * N + col;
        Cb[idx] = f2bf(acc[m][n][j]);
      }
    }
}

// ---------------------------------------------------------------------------
// bf16 MFMA GEMM, 128x128 tile (cls), counted-vmcnt pipeline (4 loads/STAGE).
// ---------------------------------------------------------------------------
template <bool ACC, bool WF32, bool WBF16>
__global__ __launch_bounds__(256) void gemm_mfma(
    const u16* __restrict__ A, const u16* __restrict__ B,
    float* __restrict__ C, u16* __restrict__ Cb, int M, int N, int K) {
  __shared__ u16 As[8192];
  __shared__ u16 Bs[8192];
  const int tid = threadIdx.x;
  const int w = tid >> 6;
  const int lane = tid & 63;

  const int gx = gridDim.x;
  const int bid = blockIdx.y * gx + blockIdx.x;
  const int nwg = gx * gridDim.y;
  const int logical = (bid & 7) * (nwg >> 3) + (bid >> 3);
  const int bm = (logical / gx) << 7;
  const int bn = (logical % gx) << 7;
  const int wr = w >> 1, wc = w & 1;

  const int r0 = (w << 4) + (lane >> 2);
  const int kc = (lane & 3) << 3;
  const u16* Ag0 = A + (size_t)(bm + r0) * K + kc;
  const u16* Ag1 = Ag0 + (size_t)64 * K;
  const u16* Bg0 = B + (size_t)(bn + r0) * K + kc;
  const u16* Bg1 = Bg0 + (size_t)64 * K;

  int aoff[4], boff[4];
#pragma unroll
  for (int m = 0; m < 4; ++m)
    aoff[m] = (((wr << 6) + (m << 4) + (lane & 15)) << 5) + ((lane >> 4) << 3);
#pragma unroll
  for (int n = 0; n < 4; ++n)
    boff[n] = (((wc << 6) + (n << 4) + (lane & 15)) << 5) + ((lane >> 4) << 3);

  f32x4 acc[4][4];
#pragma unroll
  for (int m = 0; m < 4; ++m)
#pragma unroll
    for (int n = 0; n < 4; ++n) acc[m][n] = (f32x4){0.f, 0.f, 0.f, 0.f};

#define STAGE(buf, kt)                                                        \
  {                                                                           \
    u16* as_ = As + (buf) * 4096 + (w << 9);                                  \
    u16* bs_ = Bs + (buf) * 4096 + (w << 9);                                  \
    __builtin_amdgcn_global_load_lds(                                         \
        (const __attribute__((address_space(1))) void*)(Ag0 + (kt)),          \
        (__attribute__((address_space(3))) void*)as_, 16, 0, 0);              \
    __builtin_amdgcn_global_load_lds(                                         \
        (const __attribute__((address_space(1))) void*)(Ag1 + (kt)),          \
        (__attribute__((address_space(3))) void*)(as_ + 2048), 16, 0, 0);     \
    __builtin_amdgcn_global_load_lds(                                         \
        (const __attribute__((address_space(1))) void*)(Bg0 + (kt)),          \
        (__attribute__((address_space(3))) void*)bs_, 16, 0, 0);              \
    __builtin_amdgcn_global_load_lds(                                         \
        (const __attribute__((address_space(1))) void*)(Bg1 + (kt)),          \
        (__attribute__((address_space(3))) void*)(bs_ + 2048), 16, 0, 0);     \
  }

  const int nt = K >> 5;
  STAGE(0, 0);
  int cur = 0;
  for (int t = 0; t < nt; ++t) {
    if (t + 1 < nt) {
      STAGE(cur ^ 1, (t + 1) << 5);
      B1_WAIT(4)
    } else {
      B1_WAIT(0)
    }
    const u16* Ab = As + cur * 4096;
    const u16* Bb = Bs + cur * 4096;
    bf16x8 af[4], bfr[4];
#pragma unroll
    for (int m = 0; m < 4; ++m) af[m] = *(const bf16x8*)(Ab + aoff[m]);
#pragma unroll
    for (int n = 0; n < 4; ++n) bfr[n] = *(const bf16x8*)(Bb + boff[n]);
#pragma unroll
    for (int m = 0; m < 4; ++m)
#pragma unroll
      for (int n = 0; n < 4; ++n)
        acc[m][n] = __builtin_amdgcn_mfma_f32_16x16x32_bf16(
            af[m], bfr[n], acc[m][n], 0, 0, 0);
    B2_BAR()
    cur ^= 1;
  }
#undef STAGE

  const int rb = bm + (wr << 6) + ((lane >> 4) << 2);
  const int cb = bn + (wc << 6) + (lane & 15);
#pragma unroll
  for (int m = 0; m < 4; ++m)
#pragma unroll
    for (int n = 0; n < 4; ++n) {
      int col = cb + (n << 4);
#pragma unroll
      for (int j = 0; j < 4; ++j) {
        size_t idx = (size_t)(rb + (m << 4) + j) * N + col;
        float v = acc[m][n][j];
        if (ACC) v += C[idx];
        if (WF32) C[idx] = v;
        if (WBF16) Cb[idx] = f2bf(v);
      }
    }
}

// ---------------------------------------------------------------------------
// bf16 MFMA GEMM, 128x64 tile for N=512 GEMMs, counted-vmcnt (3 loads/STAGE).
// ---------------------------------------------------------------------------
template <bool ACC, bool WF32, bool WBF16>
__global__ __launch_bounds__(256) void gemm_n64(
    const u16* __restrict__ A, const u16* __restrict__ B,
    float* __restrict__ C, u16* __restrict__ Cb, int M, int N, int K) {
  __shared__ u16 As[8192];  // [2][128][32]
  __shared__ u16 Bs[4096];  // [2][64][32]
  const int tid = threadIdx.x;
  const int w = tid >> 6;
  const int lane = tid & 63;

  const int gx = gridDim.x;  // N/64
  const int bid = blockIdx.y * gx + blockIdx.x;
  const int nwg = gx * gridDim.y;
  const int logical = (bid & 7) * (nwg >> 3) + (bid >> 3);
  const int bm = (logical / gx) << 7;
  const int bn = (logical % gx) << 6;

  const int r0 = (w << 4) + (lane >> 2);
  const int kc = (lane & 3) << 3;
  const u16* Ag0 = A + (size_t)(bm + r0) * K + kc;
  const u16* Ag1 = Ag0 + (size_t)64 * K;
  const u16* Bg0 = B + (size_t)(bn + r0) * K + kc;

  int aoff[2], boff[4];
#pragma unroll
  for (int m = 0; m < 2; ++m)
    aoff[m] = (((w << 5) + (m << 4) + (lane & 15)) << 5) + ((lane >> 4) << 3);
#pragma unroll
  for (int n = 0; n < 4; ++n)
    boff[n] = (((n << 4) + (lane & 15)) << 5) + ((lane >> 4) << 3);

  f32x4 acc[2][4];
#pragma unroll
  for (int m = 0; m < 2; ++m)
#pragma unroll
    for (int n = 0; n < 4; ++n) acc[m][n] = (f32x4){0.f, 0.f, 0.f, 0.f};

#define STAGE(buf, kt)                                                        \
  {                                                                           \
    u16* as_ = As + (buf) * 4096 + (w << 9);                                  \
    u16* bs_ = Bs + (buf) * 2048 + (w << 9);                                  \
    __builtin_amdgcn_global_load_lds(                                         \
        (const __attribute__((address_space(1))) void*)(Ag0 + (kt)),          \
        (__attribute__((address_space(3))) void*)as_, 16, 0, 0);              \
    __builtin_amdgcn_global_load_lds(                                         \
        (const __attribute__((address_space(1))) void*)(Ag1 + (kt)),          \
        (__attribute__((address_space(3))) void*)(as_ + 2048), 16, 0, 0);     \
    __builtin_amdgcn_global_load_lds(                                         \
        (const __attribute__((address_space(1))) void*)(Bg0 + (kt)),          \
        (__attribute__((address_space(3))) void*)bs_, 16, 0, 0);              \
  }

  const int nt = K >> 5;
  STAGE(0, 0);
  int cur = 0;
  for (int t = 0; t < nt; ++t) {
    if (t + 1 < nt) {
      STAGE(cur ^ 1, (t + 1) << 5);
      B1_WAIT(3)
    } else {
      B1_WAIT(0)
    }
    const u16* Ab = As + cur * 4096;
    const u16* Bb = Bs + cur * 2048;
    bf16x8 af[2], bfr[4];
#pragma unroll
    for (int m = 0; m < 2; ++m) af[m] = *(const bf16x8*)(Ab + aoff[m]);
#pragma unroll
    for (int n = 0; n < 4; ++n) bfr[n] = *(const bf16x8*)(Bb + boff[n]);
#pragma unroll
    for (int m = 0; m < 2; ++m)
#pragma unroll
      for (int n = 0; n < 4; ++n)
        acc[m][n] = __builtin_amdgcn_mfma_f32_16x16x32_bf16(
            af[m], bfr[n], acc[m][n], 0, 0, 0);
    B2_BAR()
    cur ^= 1;
  }
#undef STAGE

  const int rb = bm + (w << 5) + ((lane >> 4) << 2);
  const int cb = bn + (lane & 15);
#pragma unroll
  for (int m = 0; m < 2; ++m)
#pragma unroll
    for (int n = 0; n < 4; ++n) {
      int col = cb + (n << 4);
#pragma unroll
      for (int j = 0; j < 4; ++j) {
        size_t idx = (size_t)(rb + (m << 4) + j) * N + col;
        float v = acc[m][n][j];
        if (ACC) v += C[idx];
        if (WF32) C[idx] = v;
        if (WBF16) Cb[idx] = f2bf(v);
      }
    }
}

// ---------------------------------------------------------------------------
// LayerNorm over DT=512 per row; writes bf16 q_txt
// ---------------------------------------------------------------------------
__global__ __launch_bounds__(256) void ln_kernel(
    const float* __restrict__ m, const float* __restrict__ g,
    const float* __restrict__ bta, u16* __restrict__ q) {
  int row = blockIdx.x;
  int tid = threadIdx.x;
  float v0 = m[(size_t)row * 512 + tid];
  float v1 = m[(size_t)row * 512 + 256 + tid];
  __shared__ float red[4], red2[4];
  float s = v0 + v1;
#pragma unroll
  for (int d = 32; d; d >>= 1) s += __shfl_xor(s, d);
  if ((tid & 63) == 0) red[tid >> 6] = s;
  __syncthreads();
  float mu = (red[0] + red[1] + red[2] + red[3]) * (1.0f / 512.0f);
  float d0 = v0 - mu, d1 = v1 - mu;
  float s2 = d0 * d0 + d1 * d1;
#pragma unroll
  for (int d = 32; d; d >>= 1) s2 += __shfl_xor(s2, d);
  if ((tid & 63) == 0) red2[tid >> 6] = s2;
  __syncthreads();
  float var = (red2[0] + red2[1] + red2[2] + red2[3]) * (1.0f / 512.0f);
  float r = rsqrtf(var + 1e-5f);
  q[(size_t)row * 512 + tid] = f2bf(d0 * r * g[tid] + bta[tid]);
  q[(size_t)row * 512 + 256 + tid] = f2bf(d1 * r * g[tid + 256] + bta[tid + 256]);
}

// ---------------------------------------------------------------------------
// MFMA banded attention. Block = (b, 16 l), 512 threads = 8 waves.
// ---------------------------------------------------------------------------
__global__ __launch_bounds__(512) void attn_kernel(
    const u16* __restrict__ Qb, const u16* __restrict__ KV,
    const float* __restrict__ alpha_p, float* __restrict__ A,
    u16* __restrict__ Fv) {
  __shared__ u16 KV_s[96 * 512];   // 96 KB, K then reused for V
  __shared__ u16 Q_s[16 * 520];    // padded stride 520 u16
  __shared__ float S_s[16 * 100];  // logits then attention weights

  const int bid = blockIdx.x;
  const int logical = (bid & 7) * 64 + (bid >> 3);
  const int b = logical >> 4, lg = logical & 15;
  const int l0 = lg * 16;
  const int tid = threadIdx.x;
  const int w = tid >> 6, lane = tid & 63;
  const float al = *alpha_p;

  const int c_min = (1023 * l0) / 255;
  const int kb0 = min(max(c_min - BAND_, 0), N_ - 96);

  {
    const size_t rowb = (size_t)(b * N_ + kb0);
    for (int rr = 0; rr < 12; ++rr) {
      const int r = w * 12 + rr;
      const u16* src = KV + (rowb + r) * 1024 + ((lane * 8) ^ ((r & 7) << 3));
      u16* dst = KV_s + r * 512;
      __builtin_amdgcn_global_load_lds(
          (const __attribute__((address_space(1))) void*)src,
          (__attribute__((address_space(3))) void*)dst, 16, 0, 0);
    }
  }
  {
    const int r = tid >> 5;
    const u16* qrow = Qb + (size_t)(b * L_ + l0 + r) * 512;
#pragma unroll
    for (int h = 0; h < 2; ++h) {
      const int ch = (tid & 31) + h * 32;
      u16x8 v = *(const u16x8*)(qrow + ch * 8);
      *(u16x8*)(Q_s + r * 520 + ch * 8) = v;
    }
  }
  __syncthreads();

  if (w < 6) {
    f32x4 acc = {0.f, 0.f, 0.f, 0.f};
    const int arow = (lane & 15) * 520 + ((lane >> 4) << 3);
    const int key = w * 16 + (lane & 15);
    const int swz = (key & 7) << 3;
    for (int ks = 0; ks < 16; ++ks) {
      bf16x8 aq = *(const bf16x8*)(Q_s + arow + ks * 32);
      bf16x8 bk =
          *(const bf16x8*)(KV_s + key * 512 + ((ks * 32 + ((lane >> 4) << 3)) ^ swz));
      acc = __builtin_amdgcn_mfma_f32_16x16x32_bf16(aq, bk, acc, 0, 0, 0);
    }
#pragma unroll
    for (int j = 0; j < 4; ++j)
      S_s[((lane >> 4) * 4 + j) * 100 + w * 16 + (lane & 15)] = acc[j];
  }
  __syncthreads();

  {
    const size_t rowb = (size_t)(b * N_ + kb0);
    for (int rr = 0; rr < 12; ++rr) {
      const int r = w * 12 + rr;
      const u16* src =
          KV + (rowb + r) * 1024 + 512 + ((lane * 8) ^ ((r & 7) << 3));
      u16* dst = KV_s + r * 512;
      __builtin_amdgcn_global_load_lds(
          (const __attribute__((address_space(1))) void*)src,
          (__attribute__((address_space(3))) void*)dst, 16, 0, 0);
    }
  }

#pragma unroll
  for (int rr = 0; rr < 2; ++rr) {
    const int l = 2 * w + rr;
    const int c = (1023 * (l0 + l)) / 255;
    const int g0 = kb0 + lane, g1 = kb0 + 64 + lane;
    const bool v0 = (g0 >= c - BAND_) && (g0 <= c + BAND_);
    const bool v1 = (lane < 32) && (g1 >= c - BAND_) && (g1 <= c + BAND_);
    const float sc = 0.044194173824159216f;
    float x0 = v0 ? S_s[l * 100 + lane] * sc +
                        al * ((float)(c - g0) * (1.0f / 16.000001f))
                  : -INFINITY;
    float x1 = v1 ? S_s[l * 100 + 64 + lane] * sc +
                        al * ((float)(c - g1) * (1.0f / 16.000001f))
                  : -INFINITY;
    float mx = fmaxf(x0, x1);
#pragma unroll
    for (int d = 32; d; d >>= 1) mx = fmaxf(mx, __shfl_xor(mx, d));
    float e0 = v0 ? expf(x0 - mx) : 0.0f;
    float e1 = v1 ? expf(x1 - mx) : 0.0f;
    float sm = e0 + e1;
#pragma unroll
    for (int d = 32; d; d >>= 1) sm += __shfl_xor(sm, d);
    const float inv = 1.0f / sm;
    S_s[l * 100 + lane] = e0 * inv;
    if (lane < 32) S_s[l * 100 + 64 + lane] = e1 * inv;
    const int lo = max(0, c - BAND_), hi = min(N_ - 1, c + BAND_);
    float* Arow = A + (size_t)(b * L_ + l0 + l) * N_;
#pragma unroll
    for (int p4 = 0; p4 < 4; ++p4) {
      const int p = (p4 * 64 + lane) * 4;
      float4 v;
      v.x = (p + 0 >= lo && p + 0 <= hi) ? S_s[l * 100 + p + 0 - kb0] : 0.0f;
      v.y = (p + 1 >= lo && p + 1 <= hi) ? S_s[l * 100 + p + 1 - kb0] : 0.0f;
      v.z = (p + 2 >= lo && p + 2 <= hi) ? S_s[l * 100 + p + 2 - kb0] : 0.0f;
      v.w = (p + 3 >= lo && p + 3 <= hi) ? S_s[l * 100 + p + 3 - kb0] : 0.0f;
      ((float4*)Arow)[p4 * 64 + lane] = v;
    }
  }
  __syncthreads();

#pragma unroll
  for (int rr = 0; rr < 2; ++rr) {
    const int l = 2 * w + rr;
    const int c = (1023 * (l0 + l)) / 255;
    const int jlo = max(0, c - BAND_) - kb0, jhi = min(N_ - 1, c + BAND_) - kb0;
    float acc[8] = {};
    for (int j = jlo; j <= jhi; ++j) {
      const float avj = S_s[l * 100 + j];
      const u16x8 v =
          *(const u16x8*)(KV_s + j * 512 + ((lane * 8) ^ ((j & 7) << 3)));
#pragma unroll
      for (int t = 0; t < 8; ++t) acc[t] += avj * bf2f(v[t]);
    }
    u16x8 fo;
#pragma unroll
    for (int t = 0; t < 8; ++t) fo[t] = f2bf(acc[t]);
    *(u16x8*)(Fv + (size_t)(b * L_ + l0 + l) * 512 + lane * 8) = fo;
  }
}

// ---------------------------------------------------------------------------
extern "C" void kernel_launch(void* const* d_in, const int* in_sizes, int n_in,
                              void* d_out, int out_size, void* d_ws,
                              size_t ws_size, hipStream_t stream) {
  const float* vis = (const float*)d_in[0];    // [32,1024,512]
  const int* ids = (const int*)d_in[1];        // [32,256,8]
  const float* emb = (const float*)d_in[2];    // [1024,512]
  const float* wq = (const float*)d_in[3];     // [512,512]
  const float* wk = (const float*)d_in[4];     // [512,512]
  const float* wvp = (const float*)d_in[5];    // [512,512]
  const float* wv2t = (const float*)d_in[6];   // [512,512]
  const float* dwk = (const float*)d_in[7];    // [512,1,3]
  const float* pwk = (const float*)d_in[8];    // [512,512,1]
  const float* lng = (const float*)d_in[9];    // [512]
  const float* lnb = (const float*)d_in[10];   // [512]
  const float* alpha = (const float*)d_in[11]; // scalar

  float* out_cls = (float*)d_out;                // [8192,1024]
  float* out_H = out_cls + (size_t)8192 * 1024;  // [8192,512]
  float* out_A = out_H + (size_t)8192 * 512;     // [8192,1024]

  // workspace layout
  char* p = (char*)d_ws;
  u16* visb = (u16*)p;              p += (size_t)32768 * 512 * 2;
  u16* KVb  = (u16*)p;              p += (size_t)32768 * 1024 * 2;
  u16* embb = (u16*)p;              p += (size_t)1024 * 512 * 2;
  u16* wqb  = (u16*)p;              p += (size_t)512 * 512 * 2;
  u16* wkvb = (u16*)p;              p += (size_t)1024 * 512 * 2;
  u16* wv2tb= (u16*)p;              p += (size_t)512 * 512 * 2;
  u16* pwkb = (u16*)p;              p += (size_t)512 * 512 * 2;
  u16* shmb = (u16*)p;              p += (size_t)8192 * 512 * 2;
  float* mbuf = (float*)p;          p += (size_t)8192 * 512 * 4;
  u16* qbuf = (u16*)p;              p += (size_t)8192 * 512 * 2;
  u16* Qbf  = (u16*)p;              p += (size_t)8192 * 512 * 2;
  u16* Fvb  = (u16*)p;              p += (size_t)8192 * 512 * 2;
  u16* Hb   = (u16*)p;              p += (size_t)8192 * 512 * 2;

  // conversions to bf16
  cvt_bf16<<<16384, 256, 0, stream>>>(vis, visb, 32768 * 512 / 4);
  cvt_weights<<<1792, 256, 0, stream>>>(emb, wq, wk, wvp, wv2t, pwk,
                                        embb, wqb, wkvb, wv2tb, pwkb);

  // KV = visb @ [wk;wv]^T -> bf16 [32768][1024]  (256^2 ring-2, 2 blocks/CU)
  gemm_kv_8ph<<<dim3(4, 128), 512, 0, stream>>>(
      visb, wkvb, KVb, 32768, 1024, 512);

  // text front: gather + dwconv + silu + means
  text_front<<<8192, 256, 0, stream>>>(ids, emb, dwk, shmb, mbuf);
  // m += shm_mean @ pw^T  (pointwise conv folded through mean)
  gemm_n64<true, true, false><<<dim3(8, 64), 256, 0, stream>>>(
      shmb, pwkb, mbuf, nullptr, 8192, 512, 512);
  // LayerNorm -> q_txt (bf16)
  ln_kernel<<<8192, 256, 0, stream>>>(mbuf, lng, lnb, qbuf);
  // Q = q_txt @ wq^T (bf16 out)
  gemm_n64<false, false, true><<<dim3(8, 64), 256, 0, stream>>>(
      qbuf, wqb, nullptr, Qbf, 8192, 512, 512);
  // banded attention (MFMA) -> A (full rows, f32), Fv (bf16)
  attn_kernel<<<512, 512, 0, stream>>>(Qbf, KVb, alpha, out_A, Fvb);
  // H = Fv @ wv2t^T (f32 out + bf16 copy)
  gemm_n64<false, true, true><<<dim3(8, 64), 256, 0, stream>>>(
      Fvb, wv2tb, out_H, Hb, 8192, 512, 512);
  // cls = H @ emb^T (f32 out)
  gemm_mfma<false, true, false><<<dim3(8, 64), 256, 0, stream>>>(
      Hb, embb, out_cls, nullptr, 8192, 1024, 512);
}

// Round 17
// 199.124 us; speedup vs baseline: 1.0692x; 1.0687x over previous
//
#include <hip/hip_runtime.h>
#include <cmath>

typedef unsigned short u16;
typedef __attribute__((ext_vector_type(8))) short bf16x8;
typedef __attribute__((ext_vector_type(4))) float f32x4;
typedef __attribute__((ext_vector_type(8))) unsigned short u16x8;

#define B_  32
#define N_  1024
#define L_  256
#define S_  8
#define DT_ 512
#define BAND_ 16

__device__ __forceinline__ u16 f2bf(float f) {
  union { float f; unsigned u; } x; x.f = f;
  unsigned r = (x.u + 0x7fffu + ((x.u >> 16) & 1u)) >> 16;
  return (u16)r;
}
__device__ __forceinline__ float bf2f(u16 h) {
  union { unsigned u; float f; } x; x.u = ((unsigned)h) << 16;
  return x.f;
}

#define B1_WAIT(N)                                       \
  asm volatile("s_waitcnt vmcnt(" #N ")" ::: "memory");  \
  __builtin_amdgcn_s_barrier();                          \
  __builtin_amdgcn_sched_barrier(0);
#define B2_BAR()                                         \
  __builtin_amdgcn_sched_barrier(0);                     \
  __builtin_amdgcn_s_barrier();

// ---------------------------------------------------------------------------
// MEGA front: cvt_bf16(vis) [blocks 0..16383] + cvt_weights [16384..18175]
// + text_front [18176..26367]. All 256-thread; independent work items.
// ---------------------------------------------------------------------------
__global__ __launch_bounds__(256) void mega_front(
    const float* __restrict__ vis, u16* __restrict__ visb,
    const float* __restrict__ e, const float* __restrict__ q,
    const float* __restrict__ k, const float* __restrict__ v,
    const float* __restrict__ t, const float* __restrict__ pw,
    u16* __restrict__ eo, u16* __restrict__ qo, u16* __restrict__ kvo,
    u16* __restrict__ to, u16* __restrict__ po,
    const int* __restrict__ ids, const float* __restrict__ dwk,
    u16* __restrict__ shm, float* __restrict__ mbuf) {
  const int blk = blockIdx.x;
  const int tid = threadIdx.x;
  if (blk < 16384) {
    // vis f32 -> bf16 (float4 x 1 per thread)
    int i = blk * 256 + tid;
    float4 vv = ((const float4*)vis)[i];
    ushort4 o;
    o.x = f2bf(vv.x); o.y = f2bf(vv.y); o.z = f2bf(vv.z); o.w = f2bf(vv.w);
    ((ushort4*)visb)[i] = o;
  } else if (blk < 18176) {
    int i = (blk - 16384) * 256 + tid;
    const float* src; u16* dst; int soff, doff;
    if (i < 131072)      { src = e;  dst = eo;  soff = i;          doff = soff; }
    else if (i < 196608) { src = q;  dst = qo;  soff = i - 131072; doff = soff; }
    else if (i < 262144) { src = k;  dst = kvo; soff = i - 196608; doff = soff; }
    else if (i < 327680) { src = v;  dst = kvo; soff = i - 262144; doff = soff + 65536; }
    else if (i < 393216) { src = t;  dst = to;  soff = i - 327680; doff = soff; }
    else                 { src = pw; dst = po;  soff = i - 393216; doff = soff; }
    float4 vv = ((const float4*)src)[soff];
    ushort4 o;
    o.x = f2bf(vv.x); o.y = f2bf(vv.y); o.z = f2bf(vv.z); o.w = f2bf(vv.w);
    ((ushort4*)dst)[doff] = o;
  } else {
    // text front: gather + dwconv + silu + means
    const int bl = blk - 18176;
    __shared__ int sid[S_];
    if (tid < S_) sid[tid] = ids[bl * S_ + tid];
    __syncthreads();
    for (int c = tid; c < DT_; c += 256) {
      float x[S_];
#pragma unroll
      for (int s = 0; s < S_; ++s) x[s] = e[(size_t)sid[s] * DT_ + c];
      float k0 = dwk[c * 3 + 0], k1 = dwk[c * 3 + 1], k2 = dwk[c * 3 + 2];
      float me = 0.f, sh = 0.f;
#pragma unroll
      for (int s = 0; s < S_; ++s) {
        float xm = (s > 0) ? x[s - 1] : 0.0f;
        float xp = (s < S_ - 1) ? x[s + 1] : 0.0f;
        float h = k0 * xm + k1 * x[s] + k2 * xp;
        float si = h / (1.0f + expf(-h));  // silu
        me += x[s];
        sh += si;
      }
      shm[(size_t)bl * DT_ + c] = f2bf(sh * (1.0f / S_));
      mbuf[(size_t)bl * DT_ + c] = me * (1.0f / S_);
    }
  }
}

// ---------------------------------------------------------------------------
// KV GEMM v2: 256x128 tile, BK=32, 8 waves (4M x 2N), ring-2 LDS 48KB
// (-> 3 blocks/CU), counted vmcnt(3), T2 source-swizzle (conflict-free
// layout family verified r14), setprio. C_bf16 = A @ B^T, bf16 inputs.
// Grid (N/128, M/256) = (8, 128).
// ---------------------------------------------------------------------------
__global__ __launch_bounds__(512) void gemm_kv_v2(
    const u16* __restrict__ A, const u16* __restrict__ B,
    u16* __restrict__ Cb, int M, int N, int K) {
  __shared__ u16 As[16384];  // [2][256][32]
  __shared__ u16 Bs[8192];   // [2][128][32]
  const int tid = threadIdx.x;
  const int w = tid >> 6;
  const int lane = tid & 63;
  const int wm = w >> 1, wn = w & 1;

  const int gx = gridDim.x;  // 8
  const int bid = blockIdx.y * gx + blockIdx.x;
  const int nwg = gx * gridDim.y;
  const int logical = (bid & 7) * (nwg >> 3) + (bid >> 3);
  const int bm = (logical / gx) << 8;
  const int bn = (logical % gx) << 7;

  // staging (source chunk swizzled: chunk ^= (row>>1)&3)
  const int rowA0 = (w << 5) + (lane >> 2);
  const int rowA1 = rowA0 + 16;
  const int rowB = (w << 4) + (lane >> 2);
  const int gac = (((lane & 3) ^ ((lane >> 3) & 3)) << 3);  // u16 offset
  const u16* AgS0 = A + (size_t)(bm + rowA0) * K + gac;
  const u16* AgS1 = A + (size_t)(bm + rowA1) * K + gac;
  const u16* BgS = B + (size_t)(bn + rowB) * K + gac;
  const int ldsA0 = (w << 10);
  const int ldsA1 = (w << 10) + 512;
  const int ldsB = (w << 9);

#define STAGE(step)                                                           \
  {                                                                           \
    const int bufA_ = ((step) & 1) << 13;                                     \
    const int bufB_ = ((step) & 1) << 12;                                     \
    const int ks_ = (step) << 5;                                              \
    __builtin_amdgcn_global_load_lds(                                         \
        (const __attribute__((address_space(1))) void*)(AgS0 + ks_),          \
        (__attribute__((address_space(3))) void*)(As + bufA_ + ldsA0), 16, 0, 0); \
    __builtin_amdgcn_global_load_lds(                                         \
        (const __attribute__((address_space(1))) void*)(AgS1 + ks_),          \
        (__attribute__((address_space(3))) void*)(As + bufA_ + ldsA1), 16, 0, 0); \
    __builtin_amdgcn_global_load_lds(                                         \
        (const __attribute__((address_space(1))) void*)(BgS + ks_),           \
        (__attribute__((address_space(3))) void*)(Bs + bufB_ + ldsB), 16, 0, 0); \
  }

  const int kg = lane >> 4;
  int aoff[4], boff[4];
#pragma unroll
  for (int m = 0; m < 4; ++m) {
    const int r = (wm << 6) + (m << 4) + (lane & 15);
    aoff[m] = (r << 5) + ((kg ^ ((r >> 1) & 3)) << 3);
  }
#pragma unroll
  for (int n = 0; n < 4; ++n) {
    const int r = (wn << 6) + (n << 4) + (lane & 15);
    boff[n] = (r << 5) + ((kg ^ ((r >> 1) & 3)) << 3);
  }

  f32x4 acc[4][4];
#pragma unroll
  for (int m = 0; m < 4; ++m)
#pragma unroll
    for (int n = 0; n < 4; ++n) acc[m][n] = (f32x4){0.f, 0.f, 0.f, 0.f};

#define GROUP_BODY(sbuf)                                                      \
  {                                                                           \
    const u16* Ab = As + ((sbuf) << 13);                                      \
    const u16* Bb = Bs + ((sbuf) << 12);                                      \
    bf16x8 af[4], bfr[4];                                                     \
    _Pragma("unroll")                                                         \
    for (int m = 0; m < 4; ++m) af[m] = *(const bf16x8*)(Ab + aoff[m]);       \
    _Pragma("unroll")                                                         \
    for (int n = 0; n < 4; ++n) bfr[n] = *(const bf16x8*)(Bb + boff[n]);      \
    asm volatile("s_waitcnt lgkmcnt(0)" ::: "memory");                        \
    __builtin_amdgcn_sched_barrier(0);                                        \
    __builtin_amdgcn_s_setprio(1);                                            \
    _Pragma("unroll")                                                         \
    for (int m = 0; m < 4; ++m)                                               \
      _Pragma("unroll")                                                       \
      for (int n = 0; n < 4; ++n)                                             \
        acc[m][n] = __builtin_amdgcn_mfma_f32_16x16x32_bf16(                  \
            af[m], bfr[n], acc[m][n], 0, 0, 0);                               \
    __builtin_amdgcn_s_setprio(0);                                            \
  }

  const int nt = K >> 5;  // 16
  STAGE(0)
  for (int s = 0; s < nt; ++s) {
    __builtin_amdgcn_s_barrier();  // prev group's reads done -> safe overwrite
    if (s + 1 < nt) {
      STAGE(s + 1)
      B1_WAIT(3)                   // step s landed; s+1's 3 loads in flight
    } else {
      B1_WAIT(0)
    }
    GROUP_BODY(s & 1)
  }
#undef GROUP_BODY
#undef STAGE

  const int rb = bm + (wm << 6) + ((lane >> 4) << 2);
  const int cb = bn + (wn << 6) + (lane & 15);
#pragma unroll
  for (int m = 0; m < 4; ++m)
#pragma unroll
    for (int n = 0; n < 4; ++n) {
      const int col = cb + (n << 4);
#pragma unroll
      for (int j = 0; j < 4; ++j) {
        size_t idx = (size_t)(rb + (m << 4) + j) * N + col;
        Cb[idx] = f2bf(acc[m][n][j]);
      }
    }
}

// ---------------------------------------------------------------------------
// bf16 MFMA GEMM, 128x128 tile (cls), counted-vmcnt pipeline (4 loads/STAGE).
// ---------------------------------------------------------------------------
template <bool ACC, bool WF32, bool WBF16>
__global__ __launch_bounds__(256) void gemm_mfma(
    const u16* __restrict__ A, const u16* __restrict__ B,
    float* __restrict__ C, u16* __restrict__ Cb, int M, int N, int K) {
  __shared__ u16 As[8192];
  __shared__ u16 Bs[8192];
  const int tid = threadIdx.x;
  const int w = tid >> 6;
  const int lane = tid & 63;

  const int gx = gridDim.x;
  const int bid = blockIdx.y * gx + blockIdx.x;
  const int nwg = gx * gridDim.y;
  const int logical = (bid & 7) * (nwg >> 3) + (bid >> 3);
  const int bm = (logical / gx) << 7;
  const int bn = (logical % gx) << 7;
  const int wr = w >> 1, wc = w & 1;

  const int r0 = (w << 4) + (lane >> 2);
  const int kc = (lane & 3) << 3;
  const u16* Ag0 = A + (size_t)(bm + r0) * K + kc;
  const u16* Ag1 = Ag0 + (size_t)64 * K;
  const u16* Bg0 = B + (size_t)(bn + r0) * K + kc;
  const u16* Bg1 = Bg0 + (size_t)64 * K;

  int aoff[4], boff[4];
#pragma unroll
  for (int m = 0; m < 4; ++m)
    aoff[m] = (((wr << 6) + (m << 4) + (lane & 15)) << 5) + ((lane >> 4) << 3);
#pragma unroll
  for (int n = 0; n < 4; ++n)
    boff[n] = (((wc << 6) + (n << 4) + (lane & 15)) << 5) + ((lane >> 4) << 3);

  f32x4 acc[4][4];
#pragma unroll
  for (int m = 0; m < 4; ++m)
#pragma unroll
    for (int n = 0; n < 4; ++n) acc[m][n] = (f32x4){0.f, 0.f, 0.f, 0.f};

#define STAGE(buf, kt)                                                        \
  {                                                                           \
    u16* as_ = As + (buf) * 4096 + (w << 9);                                  \
    u16* bs_ = Bs + (buf) * 4096 + (w << 9);                                  \
    __builtin_amdgcn_global_load_lds(                                         \
        (const __attribute__((address_space(1))) void*)(Ag0 + (kt)),          \
        (__attribute__((address_space(3))) void*)as_, 16, 0, 0);              \
    __builtin_amdgcn_global_load_lds(                                         \
        (const __attribute__((address_space(1))) void*)(Ag1 + (kt)),          \
        (__attribute__((address_space(3))) void*)(as_ + 2048), 16, 0, 0);     \
    __builtin_amdgcn_global_load_lds(                                         \
        (const __attribute__((address_space(1))) void*)(Bg0 + (kt)),          \
        (__attribute__((address_space(3))) void*)bs_, 16, 0, 0);              \
    __builtin_amdgcn_global_load_lds(                                         \
        (const __attribute__((address_space(1))) void*)(Bg1 + (kt)),          \
        (__attribute__((address_space(3))) void*)(bs_ + 2048), 16, 0, 0);     \
  }

  const int nt = K >> 5;
  STAGE(0, 0);
  int cur = 0;
  for (int t = 0; t < nt; ++t) {
    if (t + 1 < nt) {
      STAGE(cur ^ 1, (t + 1) << 5);
      B1_WAIT(4)
    } else {
      B1_WAIT(0)
    }
    const u16* Ab = As + cur * 4096;
    const u16* Bb = Bs + cur * 4096;
    bf16x8 af[4], bfr[4];
#pragma unroll
    for (int m = 0; m < 4; ++m) af[m] = *(const bf16x8*)(Ab + aoff[m]);
#pragma unroll
    for (int n = 0; n < 4; ++n) bfr[n] = *(const bf16x8*)(Bb + boff[n]);
#pragma unroll
    for (int m = 0; m < 4; ++m)
#pragma unroll
      for (int n = 0; n < 4; ++n)
        acc[m][n] = __builtin_amdgcn_mfma_f32_16x16x32_bf16(
            af[m], bfr[n], acc[m][n], 0, 0, 0);
    B2_BAR()
    cur ^= 1;
  }
#undef STAGE

  const int rb = bm + (wr << 6) + ((lane >> 4) << 2);
  const int cb = bn + (wc << 6) + (lane & 15);
#pragma unroll
  for (int m = 0; m < 4; ++m)
#pragma unroll
    for (int n = 0; n < 4; ++n) {
      int col = cb + (n << 4);
#pragma unroll
      for (int j = 0; j < 4; ++j) {
        size_t idx = (size_t)(rb + (m << 4) + j) * N + col;
        float v = acc[m][n][j];
        if (ACC) v += C[idx];
        if (WF32) C[idx] = v;
        if (WBF16) Cb[idx] = f2bf(v);
      }
    }
}

// ---------------------------------------------------------------------------
// bf16 MFMA GEMM, 128x64 tile for N=512 GEMMs, counted-vmcnt (3 loads/STAGE).
// ---------------------------------------------------------------------------
template <bool ACC, bool WF32, bool WBF16>
__global__ __launch_bounds__(256) void gemm_n64(
    const u16* __restrict__ A, const u16* __restrict__ B,
    float* __restrict__ C, u16* __restrict__ Cb, int M, int N, int K) {
  __shared__ u16 As[8192];  // [2][128][32]
  __shared__ u16 Bs[4096];  // [2][64][32]
  const int tid = threadIdx.x;
  const int w = tid >> 6;
  const int lane = tid & 63;

  const int gx = gridDim.x;  // N/64
  const int bid = blockIdx.y * gx + blockIdx.x;
  const int nwg = gx * gridDim.y;
  const int logical = (bid & 7) * (nwg >> 3) + (bid >> 3);
  const int bm = (logical / gx) << 7;
  const int bn = (logical % gx) << 6;

  const int r0 = (w << 4) + (lane >> 2);
  const int kc = (lane & 3) << 3;
  const u16* Ag0 = A + (size_t)(bm + r0) * K + kc;
  const u16* Ag1 = Ag0 + (size_t)64 * K;
  const u16* Bg0 = B + (size_t)(bn + r0) * K + kc;

  int aoff[2], boff[4];
#pragma unroll
  for (int m = 0; m < 2; ++m)
    aoff[m] = (((w << 5) + (m << 4) + (lane & 15)) << 5) + ((lane >> 4) << 3);
#pragma unroll
  for (int n = 0; n < 4; ++n)
    boff[n] = (((n << 4) + (lane & 15)) << 5) + ((lane >> 4) << 3);

  f32x4 acc[2][4];
#pragma unroll
  for (int m = 0; m < 2; ++m)
#pragma unroll
    for (int n = 0; n < 4; ++n) acc[m][n] = (f32x4){0.f, 0.f, 0.f, 0.f};

#define STAGE(buf, kt)                                                        \
  {                                                                           \
    u16* as_ = As + (buf) * 4096 + (w << 9);                                  \
    u16* bs_ = Bs + (buf) * 2048 + (w << 9);                                  \
    __builtin_amdgcn_global_load_lds(                                         \
        (const __attribute__((address_space(1))) void*)(Ag0 + (kt)),          \
        (__attribute__((address_space(3))) void*)as_, 16, 0, 0);              \
    __builtin_amdgcn_global_load_lds(                                         \
        (const __attribute__((address_space(1))) void*)(Ag1 + (kt)),          \
        (__attribute__((address_space(3))) void*)(as_ + 2048), 16, 0, 0);     \
    __builtin_amdgcn_global_load_lds(                                         \
        (const __attribute__((address_space(1))) void*)(Bg0 + (kt)),          \
        (__attribute__((address_space(3))) void*)bs_, 16, 0, 0);              \
  }

  const int nt = K >> 5;
  STAGE(0, 0);
  int cur = 0;
  for (int t = 0; t < nt; ++t) {
    if (t + 1 < nt) {
      STAGE(cur ^ 1, (t + 1) << 5);
      B1_WAIT(3)
    } else {
      B1_WAIT(0)
    }
    const u16* Ab = As + cur * 4096;
    const u16* Bb = Bs + cur * 2048;
    bf16x8 af[2], bfr[4];
#pragma unroll
    for (int m = 0; m < 2; ++m) af[m] = *(const bf16x8*)(Ab + aoff[m]);
#pragma unroll
    for (int n = 0; n < 4; ++n) bfr[n] = *(const bf16x8*)(Bb + boff[n]);
#pragma unroll
    for (int m = 0; m < 2; ++m)
#pragma unroll
      for (int n = 0; n < 4; ++n)
        acc[m][n] = __builtin_amdgcn_mfma_f32_16x16x32_bf16(
            af[m], bfr[n], acc[m][n], 0, 0, 0);
    B2_BAR()
    cur ^= 1;
  }
#undef STAGE

  const int rb = bm + (w << 5) + ((lane >> 4) << 2);
  const int cb = bn + (lane & 15);
#pragma unroll
  for (int m = 0; m < 2; ++m)
#pragma unroll
    for (int n = 0; n < 4; ++n) {
      int col = cb + (n << 4);
#pragma unroll
      for (int j = 0; j < 4; ++j) {
        size_t idx = (size_t)(rb + (m << 4) + j) * N + col;
        float v = acc[m][n][j];
        if (ACC) v += C[idx];
        if (WF32) C[idx] = v;
        if (WBF16) Cb[idx] = f2bf(v);
      }
    }
}

// ---------------------------------------------------------------------------
// LayerNorm over DT=512 per row; writes bf16 q_txt
// ---------------------------------------------------------------------------
__global__ __launch_bounds__(256) void ln_kernel(
    const float* __restrict__ m, const float* __restrict__ g,
    const float* __restrict__ bta, u16* __restrict__ q) {
  int row = blockIdx.x;
  int tid = threadIdx.x;
  float v0 = m[(size_t)row * 512 + tid];
  float v1 = m[(size_t)row * 512 + 256 + tid];
  __shared__ float red[4], red2[4];
  float s = v0 + v1;
#pragma unroll
  for (int d = 32; d; d >>= 1) s += __shfl_xor(s, d);
  if ((tid & 63) == 0) red[tid >> 6] = s;
  __syncthreads();
  float mu = (red[0] + red[1] + red[2] + red[3]) * (1.0f / 512.0f);
  float d0 = v0 - mu, d1 = v1 - mu;
  float s2 = d0 * d0 + d1 * d1;
#pragma unroll
  for (int d = 32; d; d >>= 1) s2 += __shfl_xor(s2, d);
  if ((tid & 63) == 0) red2[tid >> 6] = s2;
  __syncthreads();
  float var = (red2[0] + red2[1] + red2[2] + red2[3]) * (1.0f / 512.0f);
  float r = rsqrtf(var + 1e-5f);
  q[(size_t)row * 512 + tid] = f2bf(d0 * r * g[tid] + bta[tid]);
  q[(size_t)row * 512 + 256 + tid] = f2bf(d1 * r * g[tid + 256] + bta[tid + 256]);
}

// ---------------------------------------------------------------------------
// MFMA banded attention. Block = (b, 16 l), 512 threads = 8 waves.
// ---------------------------------------------------------------------------
__global__ __launch_bounds__(512) void attn_kernel(
    const u16* __restrict__ Qb, const u16* __restrict__ KV,
    const float* __restrict__ alpha_p, float* __restrict__ A,
    u16* __restrict__ Fv) {
  __shared__ u16 KV_s[96 * 512];   // 96 KB, K then reused for V
  __shared__ u16 Q_s[16 * 520];    // padded stride 520 u16
  __shared__ float S_s[16 * 100];  // logits then attention weights

  const int bid = blockIdx.x;
  const int logical = (bid & 7) * 64 + (bid >> 3);
  const int b = logical >> 4, lg = logical & 15;
  const int l0 = lg * 16;
  const int tid = threadIdx.x;
  const int w = tid >> 6, lane = tid & 63;
  const float al = *alpha_p;

  const int c_min = (1023 * l0) / 255;
  const int kb0 = min(max(c_min - BAND_, 0), N_ - 96);

  {
    const size_t rowb = (size_t)(b * N_ + kb0);
    for (int rr = 0; rr < 12; ++rr) {
      const int r = w * 12 + rr;
      const u16* src = KV + (rowb + r) * 1024 + ((lane * 8) ^ ((r & 7) << 3));
      u16* dst = KV_s + r * 512;
      __builtin_amdgcn_global_load_lds(
          (const __attribute__((address_space(1))) void*)src,
          (__attribute__((address_space(3))) void*)dst, 16, 0, 0);
    }
  }
  {
    const int r = tid >> 5;
    const u16* qrow = Qb + (size_t)(b * L_ + l0 + r) * 512;
#pragma unroll
    for (int h = 0; h < 2; ++h) {
      const int ch = (tid & 31) + h * 32;
      u16x8 v = *(const u16x8*)(qrow + ch * 8);
      *(u16x8*)(Q_s + r * 520 + ch * 8) = v;
    }
  }
  __syncthreads();

  if (w < 6) {
    f32x4 acc = {0.f, 0.f, 0.f, 0.f};
    const int arow = (lane & 15) * 520 + ((lane >> 4) << 3);
    const int key = w * 16 + (lane & 15);
    const int swz = (key & 7) << 3;
    for (int ks = 0; ks < 16; ++ks) {
      bf16x8 aq = *(const bf16x8*)(Q_s + arow + ks * 32);
      bf16x8 bk =
          *(const bf16x8*)(KV_s + key * 512 + ((ks * 32 + ((lane >> 4) << 3)) ^ swz));
      acc = __builtin_amdgcn_mfma_f32_16x16x32_bf16(aq, bk, acc, 0, 0, 0);
    }
#pragma unroll
    for (int j = 0; j < 4; ++j)
      S_s[((lane >> 4) * 4 + j) * 100 + w * 16 + (lane & 15)] = acc[j];
  }
  __syncthreads();

  {
    const size_t rowb = (size_t)(b * N_ + kb0);
    for (int rr = 0; rr < 12; ++rr) {
      const int r = w * 12 + rr;
      const u16* src =
          KV + (rowb + r) * 1024 + 512 + ((lane * 8) ^ ((r & 7) << 3));
      u16* dst = KV_s + r * 512;
      __builtin_amdgcn_global_load_lds(
          (const __attribute__((address_space(1))) void*)src,
          (__attribute__((address_space(3))) void*)dst, 16, 0, 0);
    }
  }

#pragma unroll
  for (int rr = 0; rr < 2; ++rr) {
    const int l = 2 * w + rr;
    const int c = (1023 * (l0 + l)) / 255;
    const int g0 = kb0 + lane, g1 = kb0 + 64 + lane;
    const bool v0 = (g0 >= c - BAND_) && (g0 <= c + BAND_);
    const bool v1 = (lane < 32) && (g1 >= c - BAND_) && (g1 <= c + BAND_);
    const float sc = 0.044194173824159216f;
    float x0 = v0 ? S_s[l * 100 + lane] * sc +
                        al * ((float)(c - g0) * (1.0f / 16.000001f))
                  : -INFINITY;
    float x1 = v1 ? S_s[l * 100 + 64 + lane] * sc +
                        al * ((float)(c - g1) * (1.0f / 16.000001f))
                  : -INFINITY;
    float mx = fmaxf(x0, x1);
#pragma unroll
    for (int d = 32; d; d >>= 1) mx = fmaxf(mx, __shfl_xor(mx, d));
    float e0 = v0 ? expf(x0 - mx) : 0.0f;
    float e1 = v1 ? expf(x1 - mx) : 0.0f;
    float sm = e0 + e1;
#pragma unroll
    for (int d = 32; d; d >>= 1) sm += __shfl_xor(sm, d);
    const float inv = 1.0f / sm;
    S_s[l * 100 + lane] = e0 * inv;
    if (lane < 32) S_s[l * 100 + 64 + lane] = e1 * inv;
    const int lo = max(0, c - BAND_), hi = min(N_ - 1, c + BAND_);
    float* Arow = A + (size_t)(b * L_ + l0 + l) * N_;
#pragma unroll
    for (int p4 = 0; p4 < 4; ++p4) {
      const int p = (p4 * 64 + lane) * 4;
      float4 v;
      v.x = (p + 0 >= lo && p + 0 <= hi) ? S_s[l * 100 + p + 0 - kb0] : 0.0f;
      v.y = (p + 1 >= lo && p + 1 <= hi) ? S_s[l * 100 + p + 1 - kb0] : 0.0f;
      v.z = (p + 2 >= lo && p + 2 <= hi) ? S_s[l * 100 + p + 2 - kb0] : 0.0f;
      v.w = (p + 3 >= lo && p + 3 <= hi) ? S_s[l * 100 + p + 3 - kb0] : 0.0f;
      ((float4*)Arow)[p4 * 64 + lane] = v;
    }
  }
  __syncthreads();

#pragma unroll
  for (int rr = 0; rr < 2; ++rr) {
    const int l = 2 * w + rr;
    const int c = (1023 * (l0 + l)) / 255;
    const int jlo = max(0, c - BAND_) - kb0, jhi = min(N_ - 1, c + BAND_) - kb0;
    float acc[8] = {};
    for (int j = jlo; j <= jhi; ++j) {
      const float avj = S_s[l * 100 + j];
      const u16x8 v =
          *(const u16x8*)(KV_s + j * 512 + ((lane * 8) ^ ((j & 7) << 3)));
#pragma unroll
      for (int t = 0; t < 8; ++t) acc[t] += avj * bf2f(v[t]);
    }
    u16x8 fo;
#pragma unroll
    for (int t = 0; t < 8; ++t) fo[t] = f2bf(acc[t]);
    *(u16x8*)(Fv + (size_t)(b * L_ + l0 + l) * 512 + lane * 8) = fo;
  }
}

// ---------------------------------------------------------------------------
extern "C" void kernel_launch(void* const* d_in, const int* in_sizes, int n_in,
                              void* d_out, int out_size, void* d_ws,
                              size_t ws_size, hipStream_t stream) {
  const float* vis = (const float*)d_in[0];    // [32,1024,512]
  const int* ids = (const int*)d_in[1];        // [32,256,8]
  const float* emb = (const float*)d_in[2];    // [1024,512]
  const float* wq = (const float*)d_in[3];     // [512,512]
  const float* wk = (const float*)d_in[4];     // [512,512]
  const float* wvp = (const float*)d_in[5];    // [512,512]
  const float* wv2t = (const float*)d_in[6];   // [512,512]
  const float* dwk = (const float*)d_in[7];    // [512,1,3]
  const float* pwk = (const float*)d_in[8];    // [512,512,1]
  const float* lng = (const float*)d_in[9];    // [512]
  const float* lnb = (const float*)d_in[10];   // [512]
  const float* alpha = (const float*)d_in[11]; // scalar

  float* out_cls = (float*)d_out;                // [8192,1024]
  float* out_H = out_cls + (size_t)8192 * 1024;  // [8192,512]
  float* out_A = out_H + (size_t)8192 * 512;     // [8192,1024]

  // workspace layout
  char* p = (char*)d_ws;
  u16* visb = (u16*)p;              p += (size_t)32768 * 512 * 2;
  u16* KVb  = (u16*)p;              p += (size_t)32768 * 1024 * 2;
  u16* embb = (u16*)p;              p += (size_t)1024 * 512 * 2;
  u16* wqb  = (u16*)p;              p += (size_t)512 * 512 * 2;
  u16* wkvb = (u16*)p;              p += (size_t)1024 * 512 * 2;
  u16* wv2tb= (u16*)p;              p += (size_t)512 * 512 * 2;
  u16* pwkb = (u16*)p;              p += (size_t)512 * 512 * 2;
  u16* shmb = (u16*)p;              p += (size_t)8192 * 512 * 2;
  float* mbuf = (float*)p;          p += (size_t)8192 * 512 * 4;
  u16* qbuf = (u16*)p;              p += (size_t)8192 * 512 * 2;
  u16* Qbf  = (u16*)p;              p += (size_t)8192 * 512 * 2;
  u16* Fvb  = (u16*)p;              p += (size_t)8192 * 512 * 2;
  u16* Hb   = (u16*)p;              p += (size_t)8192 * 512 * 2;

  // fused front: vis->bf16 + weights->bf16 + text_front (independent)
  mega_front<<<26368, 256, 0, stream>>>(
      vis, visb, emb, wq, wk, wvp, wv2t, pwk,
      embb, wqb, wkvb, wv2tb, pwkb, ids, dwk, shmb, mbuf);

  // KV = visb @ [wk;wv]^T -> bf16 [32768][1024]  (256x128 ring-2, 3 blk/CU)
  gemm_kv_v2<<<dim3(8, 128), 512, 0, stream>>>(
      visb, wkvb, KVb, 32768, 1024, 512);

  // m += shm_mean @ pw^T  (pointwise conv folded through mean)
  gemm_n64<true, true, false><<<dim3(8, 64), 256, 0, stream>>>(
      shmb, pwkb, mbuf, nullptr, 8192, 512, 512);
  // LayerNorm -> q_txt (bf16)
  ln_kernel<<<8192, 256, 0, stream>>>(mbuf, lng, lnb, qbuf);
  // Q = q_txt @ wq^T (bf16 out)
  gemm_n64<false, false, true><<<dim3(8, 64), 256, 0, stream>>>(
      qbuf, wqb, nullptr, Qbf, 8192, 512, 512);
  // banded attention (MFMA) -> A (full rows, f32), Fv (bf16)
  attn_kernel<<<512, 512, 0, stream>>>(Qbf, KVb, alpha, out_A, Fvb);
  // H = Fv @ wv2t^T (f32 out + bf16 copy)
  gemm_n64<false, true, true><<<dim3(8, 64), 256, 0, stream>>>(
      Fvb, wv2tb, out_H, Hb, 8192, 512, 512);
  // cls = H @ emb^T (f32 out)
  gemm_mfma<false, true, false><<<dim3(8, 64), 256, 0, stream>>>(
      Hb, embb, out_cls, nullptr, 8192, 1024, 512);
}

// Round 18
// 195.568 us; speedup vs baseline: 1.0886x; 1.0182x over previous
//
#include <hip/hip_runtime.h>
#include <cmath>

typedef unsigned short u16;
typedef __attribute__((ext_vector_type(8))) short bf16x8;
typedef __attribute__((ext_vector_type(4))) float f32x4;
typedef __attribute__((ext_vector_type(8))) unsigned short u16x8;

#define B_  32
#define N_  1024
#define L_  256
#define S_  8
#define DT_ 512
#define BAND_ 16

__device__ __forceinline__ u16 f2bf(float f) {
  union { float f; unsigned u; } x; x.f = f;
  unsigned r = (x.u + 0x7fffu + ((x.u >> 16) & 1u)) >> 16;
  return (u16)r;
}
__device__ __forceinline__ float bf2f(u16 h) {
  union { unsigned u; float f; } x; x.u = ((unsigned)h) << 16;
  return x.f;
}

#define B1_WAIT(N)                                       \
  asm volatile("s_waitcnt vmcnt(" #N ")" ::: "memory");  \
  __builtin_amdgcn_s_barrier();                          \
  __builtin_amdgcn_sched_barrier(0);
#define B2_BAR()                                         \
  __builtin_amdgcn_sched_barrier(0);                     \
  __builtin_amdgcn_s_barrier();

// ---------------------------------------------------------------------------
// MEGA front v2. Grid 12288 x 256.
// Blocks 0..4095: text_front, 2 (b,l) items each (dispatched FIRST).
// Blocks 4096..12287: grid-stride over 18176 cvt chunks (vis + weights).
// ---------------------------------------------------------------------------
__global__ __launch_bounds__(256) void mega_front(
    const float* __restrict__ vis, u16* __restrict__ visb,
    const float* __restrict__ e, const float* __restrict__ q,
    const float* __restrict__ k, const float* __restrict__ v,
    const float* __restrict__ t, const float* __restrict__ pw,
    u16* __restrict__ eo, u16* __restrict__ qo, u16* __restrict__ kvo,
    u16* __restrict__ to, u16* __restrict__ po,
    const int* __restrict__ ids, const float* __restrict__ dwk,
    u16* __restrict__ shm, float* __restrict__ mbuf) {
  const int blk = blockIdx.x;
  const int tid = threadIdx.x;
  if (blk < 4096) {
    // text front: gather + dwconv + silu + means; 2 bl per block
#pragma unroll
    for (int ii = 0; ii < 2; ++ii) {
      const int bl = blk * 2 + ii;
      int sid[S_];
#pragma unroll
      for (int s = 0; s < S_; ++s) sid[s] = ids[bl * S_ + s];  // wave-broadcast
#pragma unroll
      for (int ci = 0; ci < 2; ++ci) {
        const int c = tid + ci * 256;
        float x[S_];
#pragma unroll
        for (int s = 0; s < S_; ++s) x[s] = e[(size_t)sid[s] * DT_ + c];
        float k0 = dwk[c * 3 + 0], k1 = dwk[c * 3 + 1], k2 = dwk[c * 3 + 2];
        float me = 0.f, sh = 0.f;
#pragma unroll
        for (int s = 0; s < S_; ++s) {
          float xm = (s > 0) ? x[s - 1] : 0.0f;
          float xp = (s < S_ - 1) ? x[s + 1] : 0.0f;
          float h = k0 * xm + k1 * x[s] + k2 * xp;
          float si = h / (1.0f + expf(-h));  // silu
          me += x[s];
          sh += si;
        }
        shm[(size_t)bl * DT_ + c] = f2bf(sh * (1.0f / S_));
        mbuf[(size_t)bl * DT_ + c] = me * (1.0f / S_);
      }
    }
  } else {
    // cvt: grid-stride over chunk ids [0, 18176): 0..16383 vis, rest weights
    for (int ch = blk - 4096; ch < 18176; ch += 8192) {
      if (ch < 16384) {
        int i = ch * 256 + tid;
        float4 vv = ((const float4*)vis)[i];
        ushort4 o;
        o.x = f2bf(vv.x); o.y = f2bf(vv.y); o.z = f2bf(vv.z); o.w = f2bf(vv.w);
        ((ushort4*)visb)[i] = o;
      } else {
        int i = (ch - 16384) * 256 + tid;
        const float* src; u16* dst; int soff, doff;
        if (i < 131072)      { src = e;  dst = eo;  soff = i;          doff = soff; }
        else if (i < 196608) { src = q;  dst = qo;  soff = i - 131072; doff = soff; }
        else if (i < 262144) { src = k;  dst = kvo; soff = i - 196608; doff = soff; }
        else if (i < 327680) { src = v;  dst = kvo; soff = i - 262144; doff = soff + 65536; }
        else if (i < 393216) { src = t;  dst = to;  soff = i - 327680; doff = soff; }
        else                 { src = pw; dst = po;  soff = i - 393216; doff = soff; }
        float4 vv = ((const float4*)src)[soff];
        ushort4 o;
        o.x = f2bf(vv.x); o.y = f2bf(vv.y); o.z = f2bf(vv.z); o.w = f2bf(vv.w);
        ((ushort4*)dst)[doff] = o;
      }
    }
  }
}

// ---------------------------------------------------------------------------
// KV GEMM v2: 256x128 tile, BK=32, 8 waves (4M x 2N), ring-2 LDS 48KB
// (-> 3 blocks/CU), counted vmcnt(3), T2 source-swizzle, setprio.
// ---------------------------------------------------------------------------
__global__ __launch_bounds__(512) void gemm_kv_v2(
    const u16* __restrict__ A, const u16* __restrict__ B,
    u16* __restrict__ Cb, int M, int N, int K) {
  __shared__ u16 As[16384];  // [2][256][32]
  __shared__ u16 Bs[8192];   // [2][128][32]
  const int tid = threadIdx.x;
  const int w = tid >> 6;
  const int lane = tid & 63;
  const int wm = w >> 1, wn = w & 1;

  const int gx = gridDim.x;  // 8
  const int bid = blockIdx.y * gx + blockIdx.x;
  const int nwg = gx * gridDim.y;
  const int logical = (bid & 7) * (nwg >> 3) + (bid >> 3);
  const int bm = (logical / gx) << 8;
  const int bn = (logical % gx) << 7;

  const int rowA0 = (w << 5) + (lane >> 2);
  const int rowA1 = rowA0 + 16;
  const int rowB = (w << 4) + (lane >> 2);
  const int gac = (((lane & 3) ^ ((lane >> 3) & 3)) << 3);  // u16 offset
  const u16* AgS0 = A + (size_t)(bm + rowA0) * K + gac;
  const u16* AgS1 = A + (size_t)(bm + rowA1) * K + gac;
  const u16* BgS = B + (size_t)(bn + rowB) * K + gac;
  const int ldsA0 = (w << 10);
  const int ldsA1 = (w << 10) + 512;
  const int ldsB = (w << 9);

#define STAGE(step)                                                           \
  {                                                                           \
    const int bufA_ = ((step) & 1) << 13;                                     \
    const int bufB_ = ((step) & 1) << 12;                                     \
    const int ks_ = (step) << 5;                                              \
    __builtin_amdgcn_global_load_lds(                                         \
        (const __attribute__((address_space(1))) void*)(AgS0 + ks_),          \
        (__attribute__((address_space(3))) void*)(As + bufA_ + ldsA0), 16, 0, 0); \
    __builtin_amdgcn_global_load_lds(                                         \
        (const __attribute__((address_space(1))) void*)(AgS1 + ks_),          \
        (__attribute__((address_space(3))) void*)(As + bufA_ + ldsA1), 16, 0, 0); \
    __builtin_amdgcn_global_load_lds(                                         \
        (const __attribute__((address_space(1))) void*)(BgS + ks_),           \
        (__attribute__((address_space(3))) void*)(Bs + bufB_ + ldsB), 16, 0, 0); \
  }

  const int kg = lane >> 4;
  int aoff[4], boff[4];
#pragma unroll
  for (int m = 0; m < 4; ++m) {
    const int r = (wm << 6) + (m << 4) + (lane & 15);
    aoff[m] = (r << 5) + ((kg ^ ((r >> 1) & 3)) << 3);
  }
#pragma unroll
  for (int n = 0; n < 4; ++n) {
    const int r = (wn << 6) + (n << 4) + (lane & 15);
    boff[n] = (r << 5) + ((kg ^ ((r >> 1) & 3)) << 3);
  }

  f32x4 acc[4][4];
#pragma unroll
  for (int m = 0; m < 4; ++m)
#pragma unroll
    for (int n = 0; n < 4; ++n) acc[m][n] = (f32x4){0.f, 0.f, 0.f, 0.f};

#define GROUP_BODY(sbuf)                                                      \
  {                                                                           \
    const u16* Ab = As + ((sbuf) << 13);                                      \
    const u16* Bb = Bs + ((sbuf) << 12);                                      \
    bf16x8 af[4], bfr[4];                                                     \
    _Pragma("unroll")                                                         \
    for (int m = 0; m < 4; ++m) af[m] = *(const bf16x8*)(Ab + aoff[m]);       \
    _Pragma("unroll")                                                         \
    for (int n = 0; n < 4; ++n) bfr[n] = *(const bf16x8*)(Bb + boff[n]);      \
    asm volatile("s_waitcnt lgkmcnt(0)" ::: "memory");                        \
    __builtin_amdgcn_sched_barrier(0);                                        \
    __builtin_amdgcn_s_setprio(1);                                            \
    _Pragma("unroll")                                                         \
    for (int m = 0; m < 4; ++m)                                               \
      _Pragma("unroll")                                                       \
      for (int n = 0; n < 4; ++n)                                             \
        acc[m][n] = __builtin_amdgcn_mfma_f32_16x16x32_bf16(                  \
            af[m], bfr[n], acc[m][n], 0, 0, 0);                               \
    __builtin_amdgcn_s_setprio(0);                                            \
  }

  const int nt = K >> 5;  // 16
  STAGE(0)
  for (int s = 0; s < nt; ++s) {
    __builtin_amdgcn_s_barrier();
    if (s + 1 < nt) {
      STAGE(s + 1)
      B1_WAIT(3)
    } else {
      B1_WAIT(0)
    }
    GROUP_BODY(s & 1)
  }
#undef GROUP_BODY
#undef STAGE

  const int rb = bm + (wm << 6) + ((lane >> 4) << 2);
  const int cb = bn + (wn << 6) + (lane & 15);
#pragma unroll
  for (int m = 0; m < 4; ++m)
#pragma unroll
    for (int n = 0; n < 4; ++n) {
      const int col = cb + (n << 4);
#pragma unroll
      for (int j = 0; j < 4; ++j) {
        size_t idx = (size_t)(rb + (m << 4) + j) * N + col;
        Cb[idx] = f2bf(acc[m][n][j]);
      }
    }
}

// ---------------------------------------------------------------------------
// bf16 MFMA GEMM, 128x128 tile (cls), counted-vmcnt pipeline (4 loads/STAGE).
// ---------------------------------------------------------------------------
template <bool ACC, bool WF32, bool WBF16>
__global__ __launch_bounds__(256) void gemm_mfma(
    const u16* __restrict__ A, const u16* __restrict__ B,
    float* __restrict__ C, u16* __restrict__ Cb, int M, int N, int K) {
  __shared__ u16 As[8192];
  __shared__ u16 Bs[8192];
  const int tid = threadIdx.x;
  const int w = tid >> 6;
  const int lane = tid & 63;

  const int gx = gridDim.x;
  const int bid = blockIdx.y * gx + blockIdx.x;
  const int nwg = gx * gridDim.y;
  const int logical = (bid & 7) * (nwg >> 3) + (bid >> 3);
  const int bm = (logical / gx) << 7;
  const int bn = (logical % gx) << 7;
  const int wr = w >> 1, wc = w & 1;

  const int r0 = (w << 4) + (lane >> 2);
  const int kc = (lane & 3) << 3;
  const u16* Ag0 = A + (size_t)(bm + r0) * K + kc;
  const u16* Ag1 = Ag0 + (size_t)64 * K;
  const u16* Bg0 = B + (size_t)(bn + r0) * K + kc;
  const u16* Bg1 = Bg0 + (size_t)64 * K;

  int aoff[4], boff[4];
#pragma unroll
  for (int m = 0; m < 4; ++m)
    aoff[m] = (((wr << 6) + (m << 4) + (lane & 15)) << 5) + ((lane >> 4) << 3);
#pragma unroll
  for (int n = 0; n < 4; ++n)
    boff[n] = (((wc << 6) + (n << 4) + (lane & 15)) << 5) + ((lane >> 4) << 3);

  f32x4 acc[4][4];
#pragma unroll
  for (int m = 0; m < 4; ++m)
#pragma unroll
    for (int n = 0; n < 4; ++n) acc[m][n] = (f32x4){0.f, 0.f, 0.f, 0.f};

#define STAGE(buf, kt)                                                        \
  {                                                                           \
    u16* as_ = As + (buf) * 4096 + (w << 9);                                  \
    u16* bs_ = Bs + (buf) * 4096 + (w << 9);                                  \
    __builtin_amdgcn_global_load_lds(                                         \
        (const __attribute__((address_space(1))) void*)(Ag0 + (kt)),          \
        (__attribute__((address_space(3))) void*)as_, 16, 0, 0);              \
    __builtin_amdgcn_global_load_lds(                                         \
        (const __attribute__((address_space(1))) void*)(Ag1 + (kt)),          \
        (__attribute__((address_space(3))) void*)(as_ + 2048), 16, 0, 0);     \
    __builtin_amdgcn_global_load_lds(                                         \
        (const __attribute__((address_space(1))) void*)(Bg0 + (kt)),          \
        (__attribute__((address_space(3))) void*)bs_, 16, 0, 0);              \
    __builtin_amdgcn_global_load_lds(                                         \
        (const __attribute__((address_space(1))) void*)(Bg1 + (kt)),          \
        (__attribute__((address_space(3))) void*)(bs_ + 2048), 16, 0, 0);     \
  }

  const int nt = K >> 5;
  STAGE(0, 0);
  int cur = 0;
  for (int t = 0; t < nt; ++t) {
    if (t + 1 < nt) {
      STAGE(cur ^ 1, (t + 1) << 5);
      B1_WAIT(4)
    } else {
      B1_WAIT(0)
    }
    const u16* Ab = As + cur * 4096;
    const u16* Bb = Bs + cur * 4096;
    bf16x8 af[4], bfr[4];
#pragma unroll
    for (int m = 0; m < 4; ++m) af[m] = *(const bf16x8*)(Ab + aoff[m]);
#pragma unroll
    for (int n = 0; n < 4; ++n) bfr[n] = *(const bf16x8*)(Bb + boff[n]);
#pragma unroll
    for (int m = 0; m < 4; ++m)
#pragma unroll
      for (int n = 0; n < 4; ++n)
        acc[m][n] = __builtin_amdgcn_mfma_f32_16x16x32_bf16(
            af[m], bfr[n], acc[m][n], 0, 0, 0);
    B2_BAR()
    cur ^= 1;
  }
#undef STAGE

  const int rb = bm + (wr << 6) + ((lane >> 4) << 2);
  const int cb = bn + (wc << 6) + (lane & 15);
#pragma unroll
  for (int m = 0; m < 4; ++m)
#pragma unroll
    for (int n = 0; n < 4; ++n) {
      int col = cb + (n << 4);
#pragma unroll
      for (int j = 0; j < 4; ++j) {
        size_t idx = (size_t)(rb + (m << 4) + j) * N + col;
        float v = acc[m][n][j];
        if (ACC) v += C[idx];
        if (WF32) C[idx] = v;
        if (WBF16) Cb[idx] = f2bf(v);
      }
    }
}

// ---------------------------------------------------------------------------
// bf16 MFMA GEMM, 128x64 tile for N=512 GEMMs, counted-vmcnt (3 loads/STAGE).
// ---------------------------------------------------------------------------
template <bool ACC, bool WF32, bool WBF16>
__global__ __launch_bounds__(256) void gemm_n64(
    const u16* __restrict__ A, const u16* __restrict__ B,
    float* __restrict__ C, u16* __restrict__ Cb, int M, int N, int K) {
  __shared__ u16 As[8192];  // [2][128][32]
  __shared__ u16 Bs[4096];  // [2][64][32]
  const int tid = threadIdx.x;
  const int w = tid >> 6;
  const int lane = tid & 63;

  const int gx = gridDim.x;  // N/64
  const int bid = blockIdx.y * gx + blockIdx.x;
  const int nwg = gx * gridDim.y;
  const int logical = (bid & 7) * (nwg >> 3) + (bid >> 3);
  const int bm = (logical / gx) << 7;
  const int bn = (logical % gx) << 6;

  const int r0 = (w << 4) + (lane >> 2);
  const int kc = (lane & 3) << 3;
  const u16* Ag0 = A + (size_t)(bm + r0) * K + kc;
  const u16* Ag1 = Ag0 + (size_t)64 * K;
  const u16* Bg0 = B + (size_t)(bn + r0) * K + kc;

  int aoff[2], boff[4];
#pragma unroll
  for (int m = 0; m < 2; ++m)
    aoff[m] = (((w << 5) + (m << 4) + (lane & 15)) << 5) + ((lane >> 4) << 3);
#pragma unroll
  for (int n = 0; n < 4; ++n)
    boff[n] = (((n << 4) + (lane & 15)) << 5) + ((lane >> 4) << 3);

  f32x4 acc[2][4];
#pragma unroll
  for (int m = 0; m < 2; ++m)
#pragma unroll
    for (int n = 0; n < 4; ++n) acc[m][n] = (f32x4){0.f, 0.f, 0.f, 0.f};

#define STAGE(buf, kt)                                                        \
  {                                                                           \
    u16* as_ = As + (buf) * 4096 + (w << 9);                                  \
    u16* bs_ = Bs + (buf) * 2048 + (w << 9);                                  \
    __builtin_amdgcn_global_load_lds(                                         \
        (const __attribute__((address_space(1))) void*)(Ag0 + (kt)),          \
        (__attribute__((address_space(3))) void*)as_, 16, 0, 0);              \
    __builtin_amdgcn_global_load_lds(                                         \
        (const __attribute__((address_space(1))) void*)(Ag1 + (kt)),          \
        (__attribute__((address_space(3))) void*)(as_ + 2048), 16, 0, 0);     \
    __builtin_amdgcn_global_load_lds(                                         \
        (const __attribute__((address_space(1))) void*)(Bg0 + (kt)),          \
        (__attribute__((address_space(3))) void*)bs_, 16, 0, 0);              \
  }

  const int nt = K >> 5;
  STAGE(0, 0);
  int cur = 0;
  for (int t = 0; t < nt; ++t) {
    if (t + 1 < nt) {
      STAGE(cur ^ 1, (t + 1) << 5);
      B1_WAIT(3)
    } else {
      B1_WAIT(0)
    }
    const u16* Ab = As + cur * 4096;
    const u16* Bb = Bs + cur * 2048;
    bf16x8 af[2], bfr[4];
#pragma unroll
    for (int m = 0; m < 2; ++m) af[m] = *(const bf16x8*)(Ab + aoff[m]);
#pragma unroll
    for (int n = 0; n < 4; ++n) bfr[n] = *(const bf16x8*)(Bb + boff[n]);
#pragma unroll
    for (int m = 0; m < 2; ++m)
#pragma unroll
      for (int n = 0; n < 4; ++n)
        acc[m][n] = __builtin_amdgcn_mfma_f32_16x16x32_bf16(
            af[m], bfr[n], acc[m][n], 0, 0, 0);
    B2_BAR()
    cur ^= 1;
  }
#undef STAGE

  const int rb = bm + (w << 5) + ((lane >> 4) << 2);
  const int cb = bn + (lane & 15);
#pragma unroll
  for (int m = 0; m < 2; ++m)
#pragma unroll
    for (int n = 0; n < 4; ++n) {
      int col = cb + (n << 4);
#pragma unroll
      for (int j = 0; j < 4; ++j) {
        size_t idx = (size_t)(rb + (m << 4) + j) * N + col;
        float v = acc[m][n][j];
        if (ACC) v += C[idx];
        if (WF32) C[idx] = v;
        if (WBF16) Cb[idx] = f2bf(v);
      }
    }
}

// ---------------------------------------------------------------------------
// LayerNorm over DT=512 per row; writes bf16 q_txt
// ---------------------------------------------------------------------------
__global__ __launch_bounds__(256) void ln_kernel(
    const float* __restrict__ m, const float* __restrict__ g,
    const float* __restrict__ bta, u16* __restrict__ q) {
  int row = blockIdx.x;
  int tid = threadIdx.x;
  float v0 = m[(size_t)row * 512 + tid];
  float v1 = m[(size_t)row * 512 + 256 + tid];
  __shared__ float red[4], red2[4];
  float s = v0 + v1;
#pragma unroll
  for (int d = 32; d; d >>= 1) s += __shfl_xor(s, d);
  if ((tid & 63) == 0) red[tid >> 6] = s;
  __syncthreads();
  float mu = (red[0] + red[1] + red[2] + red[3]) * (1.0f / 512.0f);
  float d0 = v0 - mu, d1 = v1 - mu;
  float s2 = d0 * d0 + d1 * d1;
#pragma unroll
  for (int d = 32; d; d >>= 1) s2 += __shfl_xor(s2, d);
  if ((tid & 63) == 0) red2[tid >> 6] = s2;
  __syncthreads();
  float var = (red2[0] + red2[1] + red2[2] + red2[3]) * (1.0f / 512.0f);
  float r = rsqrtf(var + 1e-5f);
  q[(size_t)row * 512 + tid] = f2bf(d0 * r * g[tid] + bta[tid]);
  q[(size_t)row * 512 + 256 + tid] = f2bf(d1 * r * g[tid + 256] + bta[tid + 256]);
}

// ---------------------------------------------------------------------------
// MFMA banded attention. Block = (b, 16 l), 512 threads = 8 waves.
// ---------------------------------------------------------------------------
__global__ __launch_bounds__(512) void attn_kernel(
    const u16* __restrict__ Qb, const u16* __restrict__ KV,
    const float* __restrict__ alpha_p, float* __restrict__ A,
    u16* __restrict__ Fv) {
  __shared__ u16 KV_s[96 * 512];   // 96 KB, K then reused for V
  __shared__ u16 Q_s[16 * 520];    // padded stride 520 u16
  __shared__ float S_s[16 * 100];  // logits then attention weights

  const int bid = blockIdx.x;
  const int logical = (bid & 7) * 64 + (bid >> 3);
  const int b = logical >> 4, lg = logical & 15;
  const int l0 = lg * 16;
  const int tid = threadIdx.x;
  const int w = tid >> 6, lane = tid & 63;
  const float al = *alpha_p;

  const int c_min = (1023 * l0) / 255;
  const int kb0 = min(max(c_min - BAND_, 0), N_ - 96);

  {
    const size_t rowb = (size_t)(b * N_ + kb0);
    for (int rr = 0; rr < 12; ++rr) {
      const int r = w * 12 + rr;
      const u16* src = KV + (rowb + r) * 1024 + ((lane * 8) ^ ((r & 7) << 3));
      u16* dst = KV_s + r * 512;
      __builtin_amdgcn_global_load_lds(
          (const __attribute__((address_space(1))) void*)src,
          (__attribute__((address_space(3))) void*)dst, 16, 0, 0);
    }
  }
  {
    const int r = tid >> 5;
    const u16* qrow = Qb + (size_t)(b * L_ + l0 + r) * 512;
#pragma unroll
    for (int h = 0; h < 2; ++h) {
      const int ch = (tid & 31) + h * 32;
      u16x8 v = *(const u16x8*)(qrow + ch * 8);
      *(u16x8*)(Q_s + r * 520 + ch * 8) = v;
    }
  }
  __syncthreads();

  if (w < 6) {
    f32x4 acc = {0.f, 0.f, 0.f, 0.f};
    const int arow = (lane & 15) * 520 + ((lane >> 4) << 3);
    const int key = w * 16 + (lane & 15);
    const int swz = (key & 7) << 3;
    for (int ks = 0; ks < 16; ++ks) {
      bf16x8 aq = *(const bf16x8*)(Q_s + arow + ks * 32);
      bf16x8 bk =
          *(const bf16x8*)(KV_s + key * 512 + ((ks * 32 + ((lane >> 4) << 3)) ^ swz));
      acc = __builtin_amdgcn_mfma_f32_16x16x32_bf16(aq, bk, acc, 0, 0, 0);
    }
#pragma unroll
    for (int j = 0; j < 4; ++j)
      S_s[((lane >> 4) * 4 + j) * 100 + w * 16 + (lane & 15)] = acc[j];
  }
  __syncthreads();

  {
    const size_t rowb = (size_t)(b * N_ + kb0);
    for (int rr = 0; rr < 12; ++rr) {
      const int r = w * 12 + rr;
      const u16* src =
          KV + (rowb + r) * 1024 + 512 + ((lane * 8) ^ ((r & 7) << 3));
      u16* dst = KV_s + r * 512;
      __builtin_amdgcn_global_load_lds(
          (const __attribute__((address_space(1))) void*)src,
          (__attribute__((address_space(3))) void*)dst, 16, 0, 0);
    }
  }

#pragma unroll
  for (int rr = 0; rr < 2; ++rr) {
    const int l = 2 * w + rr;
    const int c = (1023 * (l0 + l)) / 255;
    const int g0 = kb0 + lane, g1 = kb0 + 64 + lane;
    const bool v0 = (g0 >= c - BAND_) && (g0 <= c + BAND_);
    const bool v1 = (lane < 32) && (g1 >= c - BAND_) && (g1 <= c + BAND_);
    const float sc = 0.044194173824159216f;
    float x0 = v0 ? S_s[l * 100 + lane] * sc +
                        al * ((float)(c - g0) * (1.0f / 16.000001f))
                  : -INFINITY;
    float x1 = v1 ? S_s[l * 100 + 64 + lane] * sc +
                        al * ((float)(c - g1) * (1.0f / 16.000001f))
                  : -INFINITY;
    float mx = fmaxf(x0, x1);
#pragma unroll
    for (int d = 32; d; d >>= 1) mx = fmaxf(mx, __shfl_xor(mx, d));
    float e0 = v0 ? expf(x0 - mx) : 0.0f;
    float e1 = v1 ? expf(x1 - mx) : 0.0f;
    float sm = e0 + e1;
#pragma unroll
    for (int d = 32; d; d >>= 1) sm += __shfl_xor(sm, d);
    const float inv = 1.0f / sm;
    S_s[l * 100 + lane] = e0 * inv;
    if (lane < 32) S_s[l * 100 + 64 + lane] = e1 * inv;
    const int lo = max(0, c - BAND_), hi = min(N_ - 1, c + BAND_);
    float* Arow = A + (size_t)(b * L_ + l0 + l) * N_;
#pragma unroll
    for (int p4 = 0; p4 < 4; ++p4) {
      const int p = (p4 * 64 + lane) * 4;
      float4 v;
      v.x = (p + 0 >= lo && p + 0 <= hi) ? S_s[l * 100 + p + 0 - kb0] : 0.0f;
      v.y = (p + 1 >= lo && p + 1 <= hi) ? S_s[l * 100 + p + 1 - kb0] : 0.0f;
      v.z = (p + 2 >= lo && p + 2 <= hi) ? S_s[l * 100 + p + 2 - kb0] : 0.0f;
      v.w = (p + 3 >= lo && p + 3 <= hi) ? S_s[l * 100 + p + 3 - kb0] : 0.0f;
      ((float4*)Arow)[p4 * 64 + lane] = v;
    }
  }
  __syncthreads();

#pragma unroll
  for (int rr = 0; rr < 2; ++rr) {
    const int l = 2 * w + rr;
    const int c = (1023 * (l0 + l)) / 255;
    const int jlo = max(0, c - BAND_) - kb0, jhi = min(N_ - 1, c + BAND_) - kb0;
    float acc[8] = {};
    for (int j = jlo; j <= jhi; ++j) {
      const float avj = S_s[l * 100 + j];
      const u16x8 v =
          *(const u16x8*)(KV_s + j * 512 + ((lane * 8) ^ ((j & 7) << 3)));
#pragma unroll
      for (int t = 0; t < 8; ++t) acc[t] += avj * bf2f(v[t]);
    }
    u16x8 fo;
#pragma unroll
    for (int t = 0; t < 8; ++t) fo[t] = f2bf(acc[t]);
    *(u16x8*)(Fv + (size_t)(b * L_ + l0 + l) * 512 + lane * 8) = fo;
  }
}

// ---------------------------------------------------------------------------
extern "C" void kernel_launch(void* const* d_in, const int* in_sizes, int n_in,
                              void* d_out, int out_size, void* d_ws,
                              size_t ws_size, hipStream_t stream) {
  const float* vis = (const float*)d_in[0];    // [32,1024,512]
  const int* ids = (const int*)d_in[1];        // [32,256,8]
  const float* emb = (const float*)d_in[2];    // [1024,512]
  const float* wq = (const float*)d_in[3];     // [512,512]
  const float* wk = (const float*)d_in[4];     // [512,512]
  const float* wvp = (const float*)d_in[5];    // [512,512]
  const float* wv2t = (const float*)d_in[6];   // [512,512]
  const float* dwk = (const float*)d_in[7];    // [512,1,3]
  const float* pwk = (const float*)d_in[8];    // [512,512,1]
  const float* lng = (const float*)d_in[9];    // [512]
  const float* lnb = (const float*)d_in[10];   // [512]
  const float* alpha = (const float*)d_in[11]; // scalar

  float* out_cls = (float*)d_out;                // [8192,1024]
  float* out_H = out_cls + (size_t)8192 * 1024;  // [8192,512]
  float* out_A = out_H + (size_t)8192 * 512;     // [8192,1024]

  // workspace layout
  char* p = (char*)d_ws;
  u16* visb = (u16*)p;              p += (size_t)32768 * 512 * 2;
  u16* KVb  = (u16*)p;              p += (size_t)32768 * 1024 * 2;
  u16* embb = (u16*)p;              p += (size_t)1024 * 512 * 2;
  u16* wqb  = (u16*)p;              p += (size_t)512 * 512 * 2;
  u16* wkvb = (u16*)p;              p += (size_t)1024 * 512 * 2;
  u16* wv2tb= (u16*)p;              p += (size_t)512 * 512 * 2;
  u16* pwkb = (u16*)p;              p += (size_t)512 * 512 * 2;
  u16* shmb = (u16*)p;              p += (size_t)8192 * 512 * 2;
  float* mbuf = (float*)p;          p += (size_t)8192 * 512 * 4;
  u16* qbuf = (u16*)p;              p += (size_t)8192 * 512 * 2;
  u16* Qbf  = (u16*)p;              p += (size_t)8192 * 512 * 2;
  u16* Fvb  = (u16*)p;              p += (size_t)8192 * 512 * 2;
  u16* Hb   = (u16*)p;              p += (size_t)8192 * 512 * 2;

  // fused front: text_front (blocks 0..4095) + cvt grid-stride (4096..12287)
  mega_front<<<12288, 256, 0, stream>>>(
      vis, visb, emb, wq, wk, wvp, wv2t, pwk,
      embb, wqb, wkvb, wv2tb, pwkb, ids, dwk, shmb, mbuf);

  // KV = visb @ [wk;wv]^T -> bf16 [32768][1024]  (256x128 ring-2, 3 blk/CU)
  gemm_kv_v2<<<dim3(8, 128), 512, 0, stream>>>(
      visb, wkvb, KVb, 32768, 1024, 512);

  // m += shm_mean @ pw^T  (pointwise conv folded through mean)
  gemm_n64<true, true, false><<<dim3(8, 64), 256, 0, stream>>>(
      shmb, pwkb, mbuf, nullptr, 8192, 512, 512);
  // LayerNorm -> q_txt (bf16)
  ln_kernel<<<8192, 256, 0, stream>>>(mbuf, lng, lnb, qbuf);
  // Q = q_txt @ wq^T (bf16 out)
  gemm_n64<false, false, true><<<dim3(8, 64), 256, 0, stream>>>(
      qbuf, wqb, nullptr, Qbf, 8192, 512, 512);
  // banded attention (MFMA) -> A (full rows, f32), Fv (bf16)
  attn_kernel<<<512, 512, 0, stream>>>(Qbf, KVb, alpha, out_A, Fvb);
  // H = Fv @ wv2t^T (f32 out + bf16 copy)
  gemm_n64<false, true, true><<<dim3(8, 64), 256, 0, stream>>>(
      Fvb, wv2tb, out_H, Hb, 8192, 512, 512);
  // cls = H @ emb^T (f32 out)
  gemm_mfma<false, true, false><<<dim3(8, 64), 256, 0, stream>>>(
      Hb, embb, out_cls, nullptr, 8192, 1024, 512);
}

// Round 19
// 192.841 us; speedup vs baseline: 1.1040x; 1.0141x over previous
//
#include <hip/hip_runtime.h>
#include <cmath>

typedef unsigned short u16;
typedef __attribute__((ext_vector_type(8))) short bf16x8;
typedef __attribute__((ext_vector_type(4))) float f32x4;
typedef __attribute__((ext_vector_type(8))) unsigned short u16x8;

#define B_  32
#define N_  1024
#define L_  256
#define S_  8
#define DT_ 512
#define BAND_ 16

__device__ __forceinline__ u16 f2bf(float f) {
  union { float f; unsigned u; } x; x.f = f;
  unsigned r = (x.u + 0x7fffu + ((x.u >> 16) & 1u)) >> 16;
  return (u16)r;
}
__device__ __forceinline__ float bf2f(u16 h) {
  union { unsigned u; float f; } x; x.u = ((unsigned)h) << 16;
  return x.f;
}
// packed f32x2 -> bf16x2 (RNE), 1 instr
__device__ __forceinline__ unsigned cvtpk(float lo, float hi) {
  unsigned r;
  asm volatile("v_cvt_pk_bf16_f32 %0, %1, %2" : "=v"(r) : "v"(lo), "v"(hi));
  return r;
}

#define B1_WAIT(N)                                       \
  asm volatile("s_waitcnt vmcnt(" #N ")" ::: "memory");  \
  __builtin_amdgcn_s_barrier();                          \
  __builtin_amdgcn_sched_barrier(0);
#define B2_BAR()                                         \
  __builtin_amdgcn_sched_barrier(0);                     \
  __builtin_amdgcn_s_barrier();

// ---------------------------------------------------------------------------
// MEGA front v3. Grid 12288 x 256.
// Blocks 0..4095: text_front, 2 (b,l) items each, float2 channel pairs,
// fast __expf silu, cvt_pk bf16 packing.
// Blocks 4096..12287: grid-stride over 18176 cvt chunks (vis + weights),
// cvt_pk packing.
// ---------------------------------------------------------------------------
__global__ __launch_bounds__(256) void mega_front(
    const float* __restrict__ vis, u16* __restrict__ visb,
    const float* __restrict__ e, const float* __restrict__ q,
    const float* __restrict__ k, const float* __restrict__ v,
    const float* __restrict__ t, const float* __restrict__ pw,
    u16* __restrict__ eo, u16* __restrict__ qo, u16* __restrict__ kvo,
    u16* __restrict__ to, u16* __restrict__ po,
    const int* __restrict__ ids, const float* __restrict__ dwk,
    u16* __restrict__ shm, float* __restrict__ mbuf) {
  const int blk = blockIdx.x;
  const int tid = threadIdx.x;
  if (blk < 4096) {
    // text front: 2 bl per block; thread owns channels c0, c0+1
    const int c0 = tid * 2;
#pragma unroll
    for (int ii = 0; ii < 2; ++ii) {
      const int bl = blk * 2 + ii;
      int sid[S_];
#pragma unroll
      for (int s = 0; s < S_; ++s) sid[s] = ids[bl * S_ + s];
      float2 x2[S_];
#pragma unroll
      for (int s = 0; s < S_; ++s)
        x2[s] = *(const float2*)(e + (size_t)sid[s] * DT_ + c0);
      // dwk[c*3 + j]: 6 consecutive floats at 3*c0 (8B aligned)
      const float2 d01 = *(const float2*)(dwk + 3 * c0 + 0);
      const float2 d23 = *(const float2*)(dwk + 3 * c0 + 2);
      const float2 d45 = *(const float2*)(dwk + 3 * c0 + 4);
      float me0 = 0.f, sh0 = 0.f, me1 = 0.f, sh1 = 0.f;
#pragma unroll
      for (int s = 0; s < S_; ++s) {
        const float xm0 = (s > 0) ? x2[s - 1].x : 0.0f;
        const float xp0 = (s < S_ - 1) ? x2[s + 1].x : 0.0f;
        const float xm1 = (s > 0) ? x2[s - 1].y : 0.0f;
        const float xp1 = (s < S_ - 1) ? x2[s + 1].y : 0.0f;
        const float h0 = d01.x * xm0 + d01.y * x2[s].x + d23.x * xp0;
        const float h1 = d23.y * xm1 + d45.x * x2[s].y + d45.y * xp1;
        sh0 += h0 / (1.0f + __expf(-h0));
        sh1 += h1 / (1.0f + __expf(-h1));
        me0 += x2[s].x;
        me1 += x2[s].y;
      }
      ((unsigned*)shm)[((size_t)bl * DT_ + c0) >> 1] =
          cvtpk(sh0 * (1.0f / S_), sh1 * (1.0f / S_));
      *(float2*)(mbuf + (size_t)bl * DT_ + c0) =
          make_float2(me0 * (1.0f / S_), me1 * (1.0f / S_));
    }
  } else {
    // cvt: grid-stride over chunk ids [0, 18176): 0..16383 vis, rest weights
    for (int ch = blk - 4096; ch < 18176; ch += 8192) {
      if (ch < 16384) {
        int i = ch * 256 + tid;
        float4 vv = ((const float4*)vis)[i];
        uint2 o;
        o.x = cvtpk(vv.x, vv.y);
        o.y = cvtpk(vv.z, vv.w);
        ((uint2*)visb)[i] = o;
      } else {
        int i = (ch - 16384) * 256 + tid;
        const float* src; u16* dst; int soff, doff;
        if (i < 131072)      { src = e;  dst = eo;  soff = i;          doff = soff; }
        else if (i < 196608) { src = q;  dst = qo;  soff = i - 131072; doff = soff; }
        else if (i < 262144) { src = k;  dst = kvo; soff = i - 196608; doff = soff; }
        else if (i < 327680) { src = v;  dst = kvo; soff = i - 262144; doff = soff + 65536; }
        else if (i < 393216) { src = t;  dst = to;  soff = i - 327680; doff = soff; }
        else                 { src = pw; dst = po;  soff = i - 393216; doff = soff; }
        float4 vv = ((const float4*)src)[soff];
        uint2 o;
        o.x = cvtpk(vv.x, vv.y);
        o.y = cvtpk(vv.z, vv.w);
        ((uint2*)dst)[doff] = o;
      }
    }
  }
}

// ---------------------------------------------------------------------------
// KV GEMM v2: 256x128 tile, BK=32, 8 waves (4M x 2N), ring-2 LDS 48KB
// (-> 3 blocks/CU), counted vmcnt(3), T2 source-swizzle, setprio.
// ---------------------------------------------------------------------------
__global__ __launch_bounds__(512) void gemm_kv_v2(
    const u16* __restrict__ A, const u16* __restrict__ B,
    u16* __restrict__ Cb, int M, int N, int K) {
  __shared__ u16 As[16384];  // [2][256][32]
  __shared__ u16 Bs[8192];   // [2][128][32]
  const int tid = threadIdx.x;
  const int w = tid >> 6;
  const int lane = tid & 63;
  const int wm = w >> 1, wn = w & 1;

  const int gx = gridDim.x;  // 8
  const int bid = blockIdx.y * gx + blockIdx.x;
  const int nwg = gx * gridDim.y;
  const int logical = (bid & 7) * (nwg >> 3) + (bid >> 3);
  const int bm = (logical / gx) << 8;
  const int bn = (logical % gx) << 7;

  const int rowA0 = (w << 5) + (lane >> 2);
  const int rowA1 = rowA0 + 16;
  const int rowB = (w << 4) + (lane >> 2);
  const int gac = (((lane & 3) ^ ((lane >> 3) & 3)) << 3);  // u16 offset
  const u16* AgS0 = A + (size_t)(bm + rowA0) * K + gac;
  const u16* AgS1 = A + (size_t)(bm + rowA1) * K + gac;
  const u16* BgS = B + (size_t)(bn + rowB) * K + gac;
  const int ldsA0 = (w << 10);
  const int ldsA1 = (w << 10) + 512;
  const int ldsB = (w << 9);

#define STAGE(step)                                                           \
  {                                                                           \
    const int bufA_ = ((step) & 1) << 13;                                     \
    const int bufB_ = ((step) & 1) << 12;                                     \
    const int ks_ = (step) << 5;                                              \
    __builtin_amdgcn_global_load_lds(                                         \
        (const __attribute__((address_space(1))) void*)(AgS0 + ks_),          \
        (__attribute__((address_space(3))) void*)(As + bufA_ + ldsA0), 16, 0, 0); \
    __builtin_amdgcn_global_load_lds(                                         \
        (const __attribute__((address_space(1))) void*)(AgS1 + ks_),          \
        (__attribute__((address_space(3))) void*)(As + bufA_ + ldsA1), 16, 0, 0); \
    __builtin_amdgcn_global_load_lds(                                         \
        (const __attribute__((address_space(1))) void*)(BgS + ks_),           \
        (__attribute__((address_space(3))) void*)(Bs + bufB_ + ldsB), 16, 0, 0); \
  }

  const int kg = lane >> 4;
  int aoff[4], boff[4];
#pragma unroll
  for (int m = 0; m < 4; ++m) {
    const int r = (wm << 6) + (m << 4) + (lane & 15);
    aoff[m] = (r << 5) + ((kg ^ ((r >> 1) & 3)) << 3);
  }
#pragma unroll
  for (int n = 0; n < 4; ++n) {
    const int r = (wn << 6) + (n << 4) + (lane & 15);
    boff[n] = (r << 5) + ((kg ^ ((r >> 1) & 3)) << 3);
  }

  f32x4 acc[4][4];
#pragma unroll
  for (int m = 0; m < 4; ++m)
#pragma unroll
    for (int n = 0; n < 4; ++n) acc[m][n] = (f32x4){0.f, 0.f, 0.f, 0.f};

#define GROUP_BODY(sbuf)                                                      \
  {                                                                           \
    const u16* Ab = As + ((sbuf) << 13);                                      \
    const u16* Bb = Bs + ((sbuf) << 12);                                      \
    bf16x8 af[4], bfr[4];                                                     \
    _Pragma("unroll")                                                         \
    for (int m = 0; m < 4; ++m) af[m] = *(const bf16x8*)(Ab + aoff[m]);       \
    _Pragma("unroll")                                                         \
    for (int n = 0; n < 4; ++n) bfr[n] = *(const bf16x8*)(Bb + boff[n]);      \
    asm volatile("s_waitcnt lgkmcnt(0)" ::: "memory");                        \
    __builtin_amdgcn_sched_barrier(0);                                        \
    __builtin_amdgcn_s_setprio(1);                                            \
    _Pragma("unroll")                                                         \
    for (int m = 0; m < 4; ++m)                                               \
      _Pragma("unroll")                                                       \
      for (int n = 0; n < 4; ++n)                                             \
        acc[m][n] = __builtin_amdgcn_mfma_f32_16x16x32_bf16(                  \
            af[m], bfr[n], acc[m][n], 0, 0, 0);                               \
    __builtin_amdgcn_s_setprio(0);                                            \
  }

  const int nt = K >> 5;  // 16
  STAGE(0)
  for (int s = 0; s < nt; ++s) {
    __builtin_amdgcn_s_barrier();
    if (s + 1 < nt) {
      STAGE(s + 1)
      B1_WAIT(3)
    } else {
      B1_WAIT(0)
    }
    GROUP_BODY(s & 1)
  }
#undef GROUP_BODY
#undef STAGE

  const int rb = bm + (wm << 6) + ((lane >> 4) << 2);
  const int cb = bn + (wn << 6) + (lane & 15);
#pragma unroll
  for (int m = 0; m < 4; ++m)
#pragma unroll
    for (int n = 0; n < 4; ++n) {
      const int col = cb + (n << 4);
#pragma unroll
      for (int j = 0; j < 4; ++j) {
        size_t idx = (size_t)(rb + (m << 4) + j) * N + col;
        Cb[idx] = f2bf(acc[m][n][j]);
      }
    }
}

// ---------------------------------------------------------------------------
// bf16 MFMA GEMM, 128x128 tile (cls), counted-vmcnt pipeline (4 loads/STAGE).
// ---------------------------------------------------------------------------
template <bool ACC, bool WF32, bool WBF16>
__global__ __launch_bounds__(256) void gemm_mfma(
    const u16* __restrict__ A, const u16* __restrict__ B,
    float* __restrict__ C, u16* __restrict__ Cb, int M, int N, int K) {
  __shared__ u16 As[8192];
  __shared__ u16 Bs[8192];
  const int tid = threadIdx.x;
  const int w = tid >> 6;
  const int lane = tid & 63;

  const int gx = gridDim.x;
  const int bid = blockIdx.y * gx + blockIdx.x;
  const int nwg = gx * gridDim.y;
  const int logical = (bid & 7) * (nwg >> 3) + (bid >> 3);
  const int bm = (logical / gx) << 7;
  const int bn = (logical % gx) << 7;
  const int wr = w >> 1, wc = w & 1;

  const int r0 = (w << 4) + (lane >> 2);
  const int kc = (lane & 3) << 3;
  const u16* Ag0 = A + (size_t)(bm + r0) * K + kc;
  const u16* Ag1 = Ag0 + (size_t)64 * K;
  const u16* Bg0 = B + (size_t)(bn + r0) * K + kc;
  const u16* Bg1 = Bg0 + (size_t)64 * K;

  int aoff[4], boff[4];
#pragma unroll
  for (int m = 0; m < 4; ++m)
    aoff[m] = (((wr << 6) + (m << 4) + (lane & 15)) << 5) + ((lane >> 4) << 3);
#pragma unroll
  for (int n = 0; n < 4; ++n)
    boff[n] = (((wc << 6) + (n << 4) + (lane & 15)) << 5) + ((lane >> 4) << 3);

  f32x4 acc[4][4];
#pragma unroll
  for (int m = 0; m < 4; ++m)
#pragma unroll
    for (int n = 0; n < 4; ++n) acc[m][n] = (f32x4){0.f, 0.f, 0.f, 0.f};

#define STAGE(buf, kt)                                                        \
  {                                                                           \
    u16* as_ = As + (buf) * 4096 + (w << 9);                                  \
    u16* bs_ = Bs + (buf) * 4096 + (w << 9);                                  \
    __builtin_amdgcn_global_load_lds(                                         \
        (const __attribute__((address_space(1))) void*)(Ag0 + (kt)),          \
        (__attribute__((address_space(3))) void*)as_, 16, 0, 0);              \
    __builtin_amdgcn_global_load_lds(                                         \
        (const __attribute__((address_space(1))) void*)(Ag1 + (kt)),          \
        (__attribute__((address_space(3))) void*)(as_ + 2048), 16, 0, 0);     \
    __builtin_amdgcn_global_load_lds(                                         \
        (const __attribute__((address_space(1))) void*)(Bg0 + (kt)),          \
        (__attribute__((address_space(3))) void*)bs_, 16, 0, 0);              \
    __builtin_amdgcn_global_load_lds(                                         \
        (const __attribute__((address_space(1))) void*)(Bg1 + (kt)),          \
        (__attribute__((address_space(3))) void*)(bs_ + 2048), 16, 0, 0);     \
  }

  const int nt = K >> 5;
  STAGE(0, 0);
  int cur = 0;
  for (int t = 0; t < nt; ++t) {
    if (t + 1 < nt) {
      STAGE(cur ^ 1, (t + 1) << 5);
      B1_WAIT(4)
    } else {
      B1_WAIT(0)
    }
    const u16* Ab = As + cur * 4096;
    const u16* Bb = Bs + cur * 4096;
    bf16x8 af[4], bfr[4];
#pragma unroll
    for (int m = 0; m < 4; ++m) af[m] = *(const bf16x8*)(Ab + aoff[m]);
#pragma unroll
    for (int n = 0; n < 4; ++n) bfr[n] = *(const bf16x8*)(Bb + boff[n]);
#pragma unroll
    for (int m = 0; m < 4; ++m)
#pragma unroll
      for (int n = 0; n < 4; ++n)
        acc[m][n] = __builtin_amdgcn_mfma_f32_16x16x32_bf16(
            af[m], bfr[n], acc[m][n], 0, 0, 0);
    B2_BAR()
    cur ^= 1;
  }
#undef STAGE

  const int rb = bm + (wr << 6) + ((lane >> 4) << 2);
  const int cb = bn + (wc << 6) + (lane & 15);
#pragma unroll
  for (int m = 0; m < 4; ++m)
#pragma unroll
    for (int n = 0; n < 4; ++n) {
      int col = cb + (n << 4);
#pragma unroll
      for (int j = 0; j < 4; ++j) {
        size_t idx = (size_t)(rb + (m << 4) + j) * N + col;
        float v = acc[m][n][j];
        if (ACC) v += C[idx];
        if (WF32) C[idx] = v;
        if (WBF16) Cb[idx] = f2bf(v);
      }
    }
}

// ---------------------------------------------------------------------------
// bf16 MFMA GEMM, 128x64 tile for N=512 GEMMs, counted-vmcnt (3 loads/STAGE).
// ---------------------------------------------------------------------------
template <bool ACC, bool WF32, bool WBF16>
__global__ __launch_bounds__(256) void gemm_n64(
    const u16* __restrict__ A, const u16* __restrict__ B,
    float* __restrict__ C, u16* __restrict__ Cb, int M, int N, int K) {
  __shared__ u16 As[8192];  // [2][128][32]
  __shared__ u16 Bs[4096];  // [2][64][32]
  const int tid = threadIdx.x;
  const int w = tid >> 6;
  const int lane = tid & 63;

  const int gx = gridDim.x;  // N/64
  const int bid = blockIdx.y * gx + blockIdx.x;
  const int nwg = gx * gridDim.y;
  const int logical = (bid & 7) * (nwg >> 3) + (bid >> 3);
  const int bm = (logical / gx) << 7;
  const int bn = (logical % gx) << 6;

  const int r0 = (w << 4) + (lane >> 2);
  const int kc = (lane & 3) << 3;
  const u16* Ag0 = A + (size_t)(bm + r0) * K + kc;
  const u16* Ag1 = Ag0 + (size_t)64 * K;
  const u16* Bg0 = B + (size_t)(bn + r0) * K + kc;

  int aoff[2], boff[4];
#pragma unroll
  for (int m = 0; m < 2; ++m)
    aoff[m] = (((w << 5) + (m << 4) + (lane & 15)) << 5) + ((lane >> 4) << 3);
#pragma unroll
  for (int n = 0; n < 4; ++n)
    boff[n] = (((n << 4) + (lane & 15)) << 5) + ((lane >> 4) << 3);

  f32x4 acc[2][4];
#pragma unroll
  for (int m = 0; m < 2; ++m)
#pragma unroll
    for (int n = 0; n < 4; ++n) acc[m][n] = (f32x4){0.f, 0.f, 0.f, 0.f};

#define STAGE(buf, kt)                                                        \
  {                                                                           \
    u16* as_ = As + (buf) * 4096 + (w << 9);                                  \
    u16* bs_ = Bs + (buf) * 2048 + (w << 9);                                  \
    __builtin_amdgcn_global_load_lds(                                         \
        (const __attribute__((address_space(1))) void*)(Ag0 + (kt)),          \
        (__attribute__((address_space(3))) void*)as_, 16, 0, 0);              \
    __builtin_amdgcn_global_load_lds(                                         \
        (const __attribute__((address_space(1))) void*)(Ag1 + (kt)),          \
        (__attribute__((address_space(3))) void*)(as_ + 2048), 16, 0, 0);     \
    __builtin_amdgcn_global_load_lds(                                         \
        (const __attribute__((address_space(1))) void*)(Bg0 + (kt)),          \
        (__attribute__((address_space(3))) void*)bs_, 16, 0, 0);              \
  }

  const int nt = K >> 5;
  STAGE(0, 0);
  int cur = 0;
  for (int t = 0; t < nt; ++t) {
    if (t + 1 < nt) {
      STAGE(cur ^ 1, (t + 1) << 5);
      B1_WAIT(3)
    } else {
      B1_WAIT(0)
    }
    const u16* Ab = As + cur * 4096;
    const u16* Bb = Bs + cur * 2048;
    bf16x8 af[2], bfr[4];
#pragma unroll
    for (int m = 0; m < 2; ++m) af[m] = *(const bf16x8*)(Ab + aoff[m]);
#pragma unroll
    for (int n = 0; n < 4; ++n) bfr[n] = *(const bf16x8*)(Bb + boff[n]);
#pragma unroll
    for (int m = 0; m < 2; ++m)
#pragma unroll
      for (int n = 0; n < 4; ++n)
        acc[m][n] = __builtin_amdgcn_mfma_f32_16x16x32_bf16(
            af[m], bfr[n], acc[m][n], 0, 0, 0);
    B2_BAR()
    cur ^= 1;
  }
#undef STAGE

  const int rb = bm + (w << 5) + ((lane >> 4) << 2);
  const int cb = bn + (lane & 15);
#pragma unroll
  for (int m = 0; m < 2; ++m)
#pragma unroll
    for (int n = 0; n < 4; ++n) {
      int col = cb + (n << 4);
#pragma unroll
      for (int j = 0; j < 4; ++j) {
        size_t idx = (size_t)(rb + (m << 4) + j) * N + col;
        float v = acc[m][n][j];
        if (ACC) v += C[idx];
        if (WF32) C[idx] = v;
        if (WBF16) Cb[idx] = f2bf(v);
      }
    }
}

// ---------------------------------------------------------------------------
// LayerNorm over DT=512 per row; writes bf16 q_txt
// ---------------------------------------------------------------------------
__global__ __launch_bounds__(256) void ln_kernel(
    const float* __restrict__ m, const float* __restrict__ g,
    const float* __restrict__ bta, u16* __restrict__ q) {
  int row = blockIdx.x;
  int tid = threadIdx.x;
  float v0 = m[(size_t)row * 512 + tid];
  float v1 = m[(size_t)row * 512 + 256 + tid];
  __shared__ float red[4], red2[4];
  float s = v0 + v1;
#pragma unroll
  for (int d = 32; d; d >>= 1) s += __shfl_xor(s, d);
  if ((tid & 63) == 0) red[tid >> 6] = s;
  __syncthreads();
  float mu = (red[0] + red[1] + red[2] + red[3]) * (1.0f / 512.0f);
  float d0 = v0 - mu, d1 = v1 - mu;
  float s2 = d0 * d0 + d1 * d1;
#pragma unroll
  for (int d = 32; d; d >>= 1) s2 += __shfl_xor(s2, d);
  if ((tid & 63) == 0) red2[tid >> 6] = s2;
  __syncthreads();
  float var = (red2[0] + red2[1] + red2[2] + red2[3]) * (1.0f / 512.0f);
  float r = rsqrtf(var + 1e-5f);
  q[(size_t)row * 512 + tid] = f2bf(d0 * r * g[tid] + bta[tid]);
  q[(size_t)row * 512 + 256 + tid] = f2bf(d1 * r * g[tid + 256] + bta[tid + 256]);
}

// ---------------------------------------------------------------------------
// MFMA banded attention. Block = (b, 16 l), 512 threads = 8 waves.
// ---------------------------------------------------------------------------
__global__ __launch_bounds__(512) void attn_kernel(
    const u16* __restrict__ Qb, const u16* __restrict__ KV,
    const float* __restrict__ alpha_p, float* __restrict__ A,
    u16* __restrict__ Fv) {
  __shared__ u16 KV_s[96 * 512];   // 96 KB, K then reused for V
  __shared__ u16 Q_s[16 * 520];    // padded stride 520 u16
  __shared__ float S_s[16 * 100];  // logits then attention weights

  const int bid = blockIdx.x;
  const int logical = (bid & 7) * 64 + (bid >> 3);
  const int b = logical >> 4, lg = logical & 15;
  const int l0 = lg * 16;
  const int tid = threadIdx.x;
  const int w = tid >> 6, lane = tid & 63;
  const float al = *alpha_p;

  const int c_min = (1023 * l0) / 255;
  const int kb0 = min(max(c_min - BAND_, 0), N_ - 96);

  {
    const size_t rowb = (size_t)(b * N_ + kb0);
    for (int rr = 0; rr < 12; ++rr) {
      const int r = w * 12 + rr;
      const u16* src = KV + (rowb + r) * 1024 + ((lane * 8) ^ ((r & 7) << 3));
      u16* dst = KV_s + r * 512;
      __builtin_amdgcn_global_load_lds(
          (const __attribute__((address_space(1))) void*)src,
          (__attribute__((address_space(3))) void*)dst, 16, 0, 0);
    }
  }
  {
    const int r = tid >> 5;
    const u16* qrow = Qb + (size_t)(b * L_ + l0 + r) * 512;
#pragma unroll
    for (int h = 0; h < 2; ++h) {
      const int ch = (tid & 31) + h * 32;
      u16x8 v = *(const u16x8*)(qrow + ch * 8);
      *(u16x8*)(Q_s + r * 520 + ch * 8) = v;
    }
  }
  __syncthreads();

  if (w < 6) {
    f32x4 acc = {0.f, 0.f, 0.f, 0.f};
    const int arow = (lane & 15) * 520 + ((lane >> 4) << 3);
    const int key = w * 16 + (lane & 15);
    const int swz = (key & 7) << 3;
    for (int ks = 0; ks < 16; ++ks) {
      bf16x8 aq = *(const bf16x8*)(Q_s + arow + ks * 32);
      bf16x8 bk =
          *(const bf16x8*)(KV_s + key * 512 + ((ks * 32 + ((lane >> 4) << 3)) ^ swz));
      acc = __builtin_amdgcn_mfma_f32_16x16x32_bf16(aq, bk, acc, 0, 0, 0);
    }
#pragma unroll
    for (int j = 0; j < 4; ++j)
      S_s[((lane >> 4) * 4 + j) * 100 + w * 16 + (lane & 15)] = acc[j];
  }
  __syncthreads();

  {
    const size_t rowb = (size_t)(b * N_ + kb0);
    for (int rr = 0; rr < 12; ++rr) {
      const int r = w * 12 + rr;
      const u16* src =
          KV + (rowb + r) * 1024 + 512 + ((lane * 8) ^ ((r & 7) << 3));
      u16* dst = KV_s + r * 512;
      __builtin_amdgcn_global_load_lds(
          (const __attribute__((address_space(1))) void*)src,
          (__attribute__((address_space(3))) void*)dst, 16, 0, 0);
    }
  }

#pragma unroll
  for (int rr = 0; rr < 2; ++rr) {
    const int l = 2 * w + rr;
    const int c = (1023 * (l0 + l)) / 255;
    const int g0 = kb0 + lane, g1 = kb0 + 64 + lane;
    const bool v0 = (g0 >= c - BAND_) && (g0 <= c + BAND_);
    const bool v1 = (lane < 32) && (g1 >= c - BAND_) && (g1 <= c + BAND_);
    const float sc = 0.044194173824159216f;
    float x0 = v0 ? S_s[l * 100 + lane] * sc +
                        al * ((float)(c - g0) * (1.0f / 16.000001f))
                  : -INFINITY;
    float x1 = v1 ? S_s[l * 100 + 64 + lane] * sc +
                        al * ((float)(c - g1) * (1.0f / 16.000001f))
                  : -INFINITY;
    float mx = fmaxf(x0, x1);
#pragma unroll
    for (int d = 32; d; d >>= 1) mx = fmaxf(mx, __shfl_xor(mx, d));
    float e0 = v0 ? expf(x0 - mx) : 0.0f;
    float e1 = v1 ? expf(x1 - mx) : 0.0f;
    float sm = e0 + e1;
#pragma unroll
    for (int d = 32; d; d >>= 1) sm += __shfl_xor(sm, d);
    const float inv = 1.0f / sm;
    S_s[l * 100 + lane] = e0 * inv;
    if (lane < 32) S_s[l * 100 + 64 + lane] = e1 * inv;
    const int lo = max(0, c - BAND_), hi = min(N_ - 1, c + BAND_);
    float* Arow = A + (size_t)(b * L_ + l0 + l) * N_;
#pragma unroll
    for (int p4 = 0; p4 < 4; ++p4) {
      const int p = (p4 * 64 + lane) * 4;
      float4 v;
      v.x = (p + 0 >= lo && p + 0 <= hi) ? S_s[l * 100 + p + 0 - kb0] : 0.0f;
      v.y = (p + 1 >= lo && p + 1 <= hi) ? S_s[l * 100 + p + 1 - kb0] : 0.0f;
      v.z = (p + 2 >= lo && p + 2 <= hi) ? S_s[l * 100 + p + 2 - kb0] : 0.0f;
      v.w = (p + 3 >= lo && p + 3 <= hi) ? S_s[l * 100 + p + 3 - kb0] : 0.0f;
      ((float4*)Arow)[p4 * 64 + lane] = v;
    }
  }
  __syncthreads();

#pragma unroll
  for (int rr = 0; rr < 2; ++rr) {
    const int l = 2 * w + rr;
    const int c = (1023 * (l0 + l)) / 255;
    const int jlo = max(0, c - BAND_) - kb0, jhi = min(N_ - 1, c + BAND_) - kb0;
    float acc[8] = {};
    for (int j = jlo; j <= jhi; ++j) {
      const float avj = S_s[l * 100 + j];
      const u16x8 v =
          *(const u16x8*)(KV_s + j * 512 + ((lane * 8) ^ ((j & 7) << 3)));
#pragma unroll
      for (int t = 0; t < 8; ++t) acc[t] += avj * bf2f(v[t]);
    }
    u16x8 fo;
#pragma unroll
    for (int t = 0; t < 8; ++t) fo[t] = f2bf(acc[t]);
    *(u16x8*)(Fv + (size_t)(b * L_ + l0 + l) * 512 + lane * 8) = fo;
  }
}

// ---------------------------------------------------------------------------
extern "C" void kernel_launch(void* const* d_in, const int* in_sizes, int n_in,
                              void* d_out, int out_size, void* d_ws,
                              size_t ws_size, hipStream_t stream) {
  const float* vis = (const float*)d_in[0];    // [32,1024,512]
  const int* ids = (const int*)d_in[1];        // [32,256,8]
  const float* emb = (const float*)d_in[2];    // [1024,512]
  const float* wq = (const float*)d_in[3];     // [512,512]
  const float* wk = (const float*)d_in[4];     // [512,512]
  const float* wvp = (const float*)d_in[5];    // [512,512]
  const float* wv2t = (const float*)d_in[6];   // [512,512]
  const float* dwk = (const float*)d_in[7];    // [512,1,3]
  const float* pwk = (const float*)d_in[8];    // [512,512,1]
  const float* lng = (const float*)d_in[9];    // [512]
  const float* lnb = (const float*)d_in[10];   // [512]
  const float* alpha = (const float*)d_in[11]; // scalar

  float* out_cls = (float*)d_out;                // [8192,1024]
  float* out_H = out_cls + (size_t)8192 * 1024;  // [8192,512]
  float* out_A = out_H + (size_t)8192 * 512;     // [8192,1024]

  // workspace layout
  char* p = (char*)d_ws;
  u16* visb = (u16*)p;              p += (size_t)32768 * 512 * 2;
  u16* KVb  = (u16*)p;              p += (size_t)32768 * 1024 * 2;
  u16* embb = (u16*)p;              p += (size_t)1024 * 512 * 2;
  u16* wqb  = (u16*)p;              p += (size_t)512 * 512 * 2;
  u16* wkvb = (u16*)p;              p += (size_t)1024 * 512 * 2;
  u16* wv2tb= (u16*)p;              p += (size_t)512 * 512 * 2;
  u16* pwkb = (u16*)p;              p += (size_t)512 * 512 * 2;
  u16* shmb = (u16*)p;              p += (size_t)8192 * 512 * 2;
  float* mbuf = (float*)p;          p += (size_t)8192 * 512 * 4;
  u16* qbuf = (u16*)p;              p += (size_t)8192 * 512 * 2;
  u16* Qbf  = (u16*)p;              p += (size_t)8192 * 512 * 2;
  u16* Fvb  = (u16*)p;              p += (size_t)8192 * 512 * 2;
  u16* Hb   = (u16*)p;              p += (size_t)8192 * 512 * 2;

  // fused front: text_front (blocks 0..4095) + cvt grid-stride (4096..12287)
  mega_front<<<12288, 256, 0, stream>>>(
      vis, visb, emb, wq, wk, wvp, wv2t, pwk,
      embb, wqb, wkvb, wv2tb, pwkb, ids, dwk, shmb, mbuf);

  // KV = visb @ [wk;wv]^T -> bf16 [32768][1024]  (256x128 ring-2, 3 blk/CU)
  gemm_kv_v2<<<dim3(8, 128), 512, 0, stream>>>(
      visb, wkvb, KVb, 32768, 1024, 512);

  // m += shm_mean @ pw^T  (pointwise conv folded through mean)
  gemm_n64<true, true, false><<<dim3(8, 64), 256, 0, stream>>>(
      shmb, pwkb, mbuf, nullptr, 8192, 512, 512);
  // LayerNorm -> q_txt (bf16)
  ln_kernel<<<8192, 256, 0, stream>>>(mbuf, lng, lnb, qbuf);
  // Q = q_txt @ wq^T (bf16 out)
  gemm_n64<false, false, true><<<dim3(8, 64), 256, 0, stream>>>(
      qbuf, wqb, nullptr, Qbf, 8192, 512, 512);
  // banded attention (MFMA) -> A (full rows, f32), Fv (bf16)
  attn_kernel<<<512, 512, 0, stream>>>(Qbf, KVb, alpha, out_A, Fvb);
  // H = Fv @ wv2t^T (f32 out + bf16 copy)
  gemm_n64<false, true, true><<<dim3(8, 64), 256, 0, stream>>>(
      Fvb, wv2tb, out_H, Hb, 8192, 512, 512);
  // cls = H @ emb^T (f32 out)
  gemm_mfma<false, true, false><<<dim3(8, 64), 256, 0, stream>>>(
      Hb, embb, out_cls, nullptr, 8192, 1024, 512);
}

// Round 20
// 188.276 us; speedup vs baseline: 1.1308x; 1.0243x over previous
//
#include <hip/hip_runtime.h>
#include <cmath>

typedef unsigned short u16;
typedef __attribute__((ext_vector_type(8))) short bf16x8;
typedef __attribute__((ext_vector_type(4))) float f32x4;
typedef __attribute__((ext_vector_type(8))) unsigned short u16x8;

#define B_  32
#define N_  1024
#define L_  256
#define S_  8
#define DT_ 512
#define BAND_ 16

__device__ __forceinline__ u16 f2bf(float f) {
  union { float f; unsigned u; } x; x.f = f;
  unsigned r = (x.u + 0x7fffu + ((x.u >> 16) & 1u)) >> 16;
  return (u16)r;
}
__device__ __forceinline__ float bf2f(u16 h) {
  union { unsigned u; float f; } x; x.u = ((unsigned)h) << 16;
  return x.f;
}
// packed f32x2 -> bf16x2 (RNE), 1 instr
__device__ __forceinline__ unsigned cvtpk(float lo, float hi) {
  unsigned r;
  asm volatile("v_cvt_pk_bf16_f32 %0, %1, %2" : "=v"(r) : "v"(lo), "v"(hi));
  return r;
}

#define B1_WAIT(N)                                       \
  asm volatile("s_waitcnt vmcnt(" #N ")" ::: "memory");  \
  __builtin_amdgcn_s_barrier();                          \
  __builtin_amdgcn_sched_barrier(0);
#define B2_BAR()                                         \
  __builtin_amdgcn_sched_barrier(0);                     \
  __builtin_amdgcn_s_barrier();

// ---------------------------------------------------------------------------
// MEGA front v4. Grid 13184 x 256, exact work mapping (no grid-stride).
// Blocks 0..4095: text_front, 2 (b,l) each; silu uses fast rcp.
// Blocks 4096..12287: vis cvt, 2 float4-chunks each (loads issued upfront).
// Blocks 12288..13183: weight cvt, 2 chunks each.
// ---------------------------------------------------------------------------
__global__ __launch_bounds__(256) void mega_front(
    const float* __restrict__ vis, u16* __restrict__ visb,
    const float* __restrict__ e, const float* __restrict__ q,
    const float* __restrict__ k, const float* __restrict__ v,
    const float* __restrict__ t, const float* __restrict__ pw,
    u16* __restrict__ eo, u16* __restrict__ qo, u16* __restrict__ kvo,
    u16* __restrict__ to, u16* __restrict__ po,
    const int* __restrict__ ids, const float* __restrict__ dwk,
    u16* __restrict__ shm, float* __restrict__ mbuf) {
  const int blk = blockIdx.x;
  const int tid = threadIdx.x;
  if (blk < 4096) {
    // text front: 2 bl per block; thread owns channels c0, c0+1
    const int c0 = tid * 2;
    const float2 d01 = *(const float2*)(dwk + 3 * c0 + 0);
    const float2 d23 = *(const float2*)(dwk + 3 * c0 + 2);
    const float2 d45 = *(const float2*)(dwk + 3 * c0 + 4);
#pragma unroll
    for (int ii = 0; ii < 2; ++ii) {
      const int bl = blk * 2 + ii;
      int sid[S_];
#pragma unroll
      for (int s = 0; s < S_; ++s) sid[s] = ids[bl * S_ + s];
      float2 x2[S_];
#pragma unroll
      for (int s = 0; s < S_; ++s)
        x2[s] = *(const float2*)(e + (size_t)sid[s] * DT_ + c0);
      float me0 = 0.f, sh0 = 0.f, me1 = 0.f, sh1 = 0.f;
#pragma unroll
      for (int s = 0; s < S_; ++s) {
        const float xm0 = (s > 0) ? x2[s - 1].x : 0.0f;
        const float xp0 = (s < S_ - 1) ? x2[s + 1].x : 0.0f;
        const float xm1 = (s > 0) ? x2[s - 1].y : 0.0f;
        const float xp1 = (s < S_ - 1) ? x2[s + 1].y : 0.0f;
        const float h0 = d01.x * xm0 + d01.y * x2[s].x + d23.x * xp0;
        const float h1 = d23.y * xm1 + d45.x * x2[s].y + d45.y * xp1;
        sh0 += h0 * __builtin_amdgcn_rcpf(1.0f + __expf(-h0));
        sh1 += h1 * __builtin_amdgcn_rcpf(1.0f + __expf(-h1));
        me0 += x2[s].x;
        me1 += x2[s].y;
      }
      ((unsigned*)shm)[((size_t)bl * DT_ + c0) >> 1] =
          cvtpk(sh0 * (1.0f / S_), sh1 * (1.0f / S_));
      *(float2*)(mbuf + (size_t)bl * DT_ + c0) =
          make_float2(me0 * (1.0f / S_), me1 * (1.0f / S_));
    }
  } else if (blk < 12288) {
    // vis cvt: 512 consecutive float4 per block, both loads upfront
    const int i0 = (blk - 4096) * 512 + tid;
    const float4 v0 = ((const float4*)vis)[i0];
    const float4 v1 = ((const float4*)vis)[i0 + 256];
    uint2 o0, o1;
    o0.x = cvtpk(v0.x, v0.y); o0.y = cvtpk(v0.z, v0.w);
    o1.x = cvtpk(v1.x, v1.y); o1.y = cvtpk(v1.z, v1.w);
    ((uint2*)visb)[i0] = o0;
    ((uint2*)visb)[i0 + 256] = o1;
  } else {
    // weight cvt: 2 chunks per block
    const int base = (blk - 12288) * 512 + tid;
#pragma unroll
    for (int jj = 0; jj < 2; ++jj) {
      const int i = base + jj * 256;
      const float* src; u16* dst; int soff, doff;
      if (i < 131072)      { src = e;  dst = eo;  soff = i;          doff = soff; }
      else if (i < 196608) { src = q;  dst = qo;  soff = i - 131072; doff = soff; }
      else if (i < 262144) { src = k;  dst = kvo; soff = i - 196608; doff = soff; }
      else if (i < 327680) { src = v;  dst = kvo; soff = i - 262144; doff = soff + 65536; }
      else if (i < 393216) { src = t;  dst = to;  soff = i - 327680; doff = soff; }
      else                 { src = pw; dst = po;  soff = i - 393216; doff = soff; }
      float4 vv = ((const float4*)src)[soff];
      uint2 o;
      o.x = cvtpk(vv.x, vv.y);
      o.y = cvtpk(vv.z, vv.w);
      ((uint2*)dst)[doff] = o;
    }
  }
}

// ---------------------------------------------------------------------------
// KV GEMM v3: 256x128 tile, BK=32, 8 waves (4M x 2N), ring-3 LDS 72KB
// (-> 2 blocks/CU), prefetch depth 2, counted vmcnt(6), T2 source-swizzle,
// setprio. C_bf16 = A @ B^T, bf16 inputs. Grid (8, 128).
// ---------------------------------------------------------------------------
__global__ __launch_bounds__(512) void gemm_kv_v2(
    const u16* __restrict__ A, const u16* __restrict__ B,
    u16* __restrict__ Cb, int M, int N, int K) {
  __shared__ u16 As[24576];  // [3][256][32]
  __shared__ u16 Bs[12288];  // [3][128][32]
  const int tid = threadIdx.x;
  const int w = tid >> 6;
  const int lane = tid & 63;
  const int wm = w >> 1, wn = w & 1;

  const int gx = gridDim.x;  // 8
  const int bid = blockIdx.y * gx + blockIdx.x;
  const int nwg = gx * gridDim.y;
  const int logical = (bid & 7) * (nwg >> 3) + (bid >> 3);
  const int bm = (logical / gx) << 8;
  const int bn = (logical % gx) << 7;

  const int rowA0 = (w << 5) + (lane >> 2);
  const int rowA1 = rowA0 + 16;
  const int rowB = (w << 4) + (lane >> 2);
  const int gac = (((lane & 3) ^ ((lane >> 3) & 3)) << 3);  // u16 offset
  const u16* AgS0 = A + (size_t)(bm + rowA0) * K + gac;
  const u16* AgS1 = A + (size_t)(bm + rowA1) * K + gac;
  const u16* BgS = B + (size_t)(bn + rowB) * K + gac;
  const int ldsA0 = (w << 10);
  const int ldsA1 = (w << 10) + 512;
  const int ldsB = (w << 9);

#define STAGE(step)                                                           \
  {                                                                           \
    const int rb_ = (step) % 3;                                               \
    const int bufA_ = rb_ * 8192;                                             \
    const int bufB_ = rb_ * 4096;                                             \
    const int ks_ = (step) << 5;                                              \
    __builtin_amdgcn_global_load_lds(                                         \
        (const __attribute__((address_space(1))) void*)(AgS0 + ks_),          \
        (__attribute__((address_space(3))) void*)(As + bufA_ + ldsA0), 16, 0, 0); \
    __builtin_amdgcn_global_load_lds(                                         \
        (const __attribute__((address_space(1))) void*)(AgS1 + ks_),          \
        (__attribute__((address_space(3))) void*)(As + bufA_ + ldsA1), 16, 0, 0); \
    __builtin_amdgcn_global_load_lds(                                         \
        (const __attribute__((address_space(1))) void*)(BgS + ks_),           \
        (__attribute__((address_space(3))) void*)(Bs + bufB_ + ldsB), 16, 0, 0); \
  }

  const int kg = lane >> 4;
  int aoff[4], boff[4];
#pragma unroll
  for (int m = 0; m < 4; ++m) {
    const int r = (wm << 6) + (m << 4) + (lane & 15);
    aoff[m] = (r << 5) + ((kg ^ ((r >> 1) & 3)) << 3);
  }
#pragma unroll
  for (int n = 0; n < 4; ++n) {
    const int r = (wn << 6) + (n << 4) + (lane & 15);
    boff[n] = (r << 5) + ((kg ^ ((r >> 1) & 3)) << 3);
  }

  f32x4 acc[4][4];
#pragma unroll
  for (int m = 0; m < 4; ++m)
#pragma unroll
    for (int n = 0; n < 4; ++n) acc[m][n] = (f32x4){0.f, 0.f, 0.f, 0.f};

#define GROUP_BODY(sbuf)                                                      \
  {                                                                           \
    const u16* Ab = As + (sbuf) * 8192;                                       \
    const u16* Bb = Bs + (sbuf) * 4096;                                       \
    bf16x8 af[4], bfr[4];                                                     \
    _Pragma("unroll")                                                         \
    for (int m = 0; m < 4; ++m) af[m] = *(const bf16x8*)(Ab + aoff[m]);       \
    _Pragma("unroll")                                                         \
    for (int n = 0; n < 4; ++n) bfr[n] = *(const bf16x8*)(Bb + boff[n]);      \
    asm volatile("s_waitcnt lgkmcnt(0)" ::: "memory");                        \
    __builtin_amdgcn_sched_barrier(0);                                        \
    __builtin_amdgcn_s_setprio(1);                                            \
    _Pragma("unroll")                                                         \
    for (int m = 0; m < 4; ++m)                                               \
      _Pragma("unroll")                                                       \
      for (int n = 0; n < 4; ++n)                                             \
        acc[m][n] = __builtin_amdgcn_mfma_f32_16x16x32_bf16(                  \
            af[m], bfr[n], acc[m][n], 0, 0, 0);                               \
    __builtin_amdgcn_s_setprio(0);                                            \
  }

  const int nt = K >> 5;  // 16
  STAGE(0)
  STAGE(1)
  for (int s = 0; s < nt; ++s) {
    __builtin_amdgcn_s_barrier();  // group s-1 reads done -> (s+2)%3 reusable
    if (s + 2 < nt) {
      STAGE(s + 2)
      B1_WAIT(6)                   // step s landed; s+1, s+2 in flight
    } else if (s + 1 < nt) {
      B1_WAIT(3)
    } else {
      B1_WAIT(0)
    }
    GROUP_BODY(s % 3)
  }
#undef GROUP_BODY
#undef STAGE

  const int rb = bm + (wm << 6) + ((lane >> 4) << 2);
  const int cb = bn + (wn << 6) + (lane & 15);
#pragma unroll
  for (int m = 0; m < 4; ++m)
#pragma unroll
    for (int n = 0; n < 4; ++n) {
      const int col = cb + (n << 4);
#pragma unroll
      for (int j = 0; j < 4; ++j) {
        size_t idx = (size_t)(rb + (m << 4) + j) * N + col;
        Cb[idx] = f2bf(acc[m][n][j]);
      }
    }
}

// ---------------------------------------------------------------------------
// bf16 MFMA GEMM, 128x128 tile (cls), counted-vmcnt pipeline (4 loads/STAGE).
// ---------------------------------------------------------------------------
template <bool ACC, bool WF32, bool WBF16>
__global__ __launch_bounds__(256) void gemm_mfma(
    const u16* __restrict__ A, const u16* __restrict__ B,
    float* __restrict__ C, u16* __restrict__ Cb, int M, int N, int K) {
  __shared__ u16 As[8192];
  __shared__ u16 Bs[8192];
  const int tid = threadIdx.x;
  const int w = tid >> 6;
  const int lane = tid & 63;

  const int gx = gridDim.x;
  const int bid = blockIdx.y * gx + blockIdx.x;
  const int nwg = gx * gridDim.y;
  const int logical = (bid & 7) * (nwg >> 3) + (bid >> 3);
  const int bm = (logical / gx) << 7;
  const int bn = (logical % gx) << 7;
  const int wr = w >> 1, wc = w & 1;

  const int r0 = (w << 4) + (lane >> 2);
  const int kc = (lane & 3) << 3;
  const u16* Ag0 = A + (size_t)(bm + r0) * K + kc;
  const u16* Ag1 = Ag0 + (size_t)64 * K;
  const u16* Bg0 = B + (size_t)(bn + r0) * K + kc;
  const u16* Bg1 = Bg0 + (size_t)64 * K;

  int aoff[4], boff[4];
#pragma unroll
  for (int m = 0; m < 4; ++m)
    aoff[m] = (((wr << 6) + (m << 4) + (lane & 15)) << 5) + ((lane >> 4) << 3);
#pragma unroll
  for (int n = 0; n < 4; ++n)
    boff[n] = (((wc << 6) + (n << 4) + (lane & 15)) << 5) + ((lane >> 4) << 3);

  f32x4 acc[4][4];
#pragma unroll
  for (int m = 0; m < 4; ++m)
#pragma unroll
    for (int n = 0; n < 4; ++n) acc[m][n] = (f32x4){0.f, 0.f, 0.f, 0.f};

#define STAGE(buf, kt)                                                        \
  {                                                                           \
    u16* as_ = As + (buf) * 4096 + (w << 9);                                  \
    u16* bs_ = Bs + (buf) * 4096 + (w << 9);                                  \
    __builtin_amdgcn_global_load_lds(                                         \
        (const __attribute__((address_space(1))) void*)(Ag0 + (kt)),          \
        (__attribute__((address_space(3))) void*)as_, 16, 0, 0);              \
    __builtin_amdgcn_global_load_lds(                                         \
        (const __attribute__((address_space(1))) void*)(Ag1 + (kt)),          \
        (__attribute__((address_space(3))) void*)(as_ + 2048), 16, 0, 0);     \
    __builtin_amdgcn_global_load_lds(                                         \
        (const __attribute__((address_space(1))) void*)(Bg0 + (kt)),          \
        (__attribute__((address_space(3))) void*)bs_, 16, 0, 0);              \
    __builtin_amdgcn_global_load_lds(                                         \
        (const __attribute__((address_space(1))) void*)(Bg1 + (kt)),          \
        (__attribute__((address_space(3))) void*)(bs_ + 2048), 16, 0, 0);     \
  }

  const int nt = K >> 5;
  STAGE(0, 0);
  int cur = 0;
  for (int t = 0; t < nt; ++t) {
    if (t + 1 < nt) {
      STAGE(cur ^ 1, (t + 1) << 5);
      B1_WAIT(4)
    } else {
      B1_WAIT(0)
    }
    const u16* Ab = As + cur * 4096;
    const u16* Bb = Bs + cur * 4096;
    bf16x8 af[4], bfr[4];
#pragma unroll
    for (int m = 0; m < 4; ++m) af[m] = *(const bf16x8*)(Ab + aoff[m]);
#pragma unroll
    for (int n = 0; n < 4; ++n) bfr[n] = *(const bf16x8*)(Bb + boff[n]);
#pragma unroll
    for (int m = 0; m < 4; ++m)
#pragma unroll
      for (int n = 0; n < 4; ++n)
        acc[m][n] = __builtin_amdgcn_mfma_f32_16x16x32_bf16(
            af[m], bfr[n], acc[m][n], 0, 0, 0);
    B2_BAR()
    cur ^= 1;
  }
#undef STAGE

  const int rb = bm + (wr << 6) + ((lane >> 4) << 2);
  const int cb = bn + (wc << 6) + (lane & 15);
#pragma unroll
  for (int m = 0; m < 4; ++m)
#pragma unroll
    for (int n = 0; n < 4; ++n) {
      int col = cb + (n << 4);
#pragma unroll
      for (int j = 0; j < 4; ++j) {
        size_t idx = (size_t)(rb + (m << 4) + j) * N + col;
        float v = acc[m][n][j];
        if (ACC) v += C[idx];
        if (WF32) C[idx] = v;
        if (WBF16) Cb[idx] = f2bf(v);
      }
    }
}

// ---------------------------------------------------------------------------
// bf16 MFMA GEMM, 128x64 tile for N=512 GEMMs, counted-vmcnt (3 loads/STAGE).
// ---------------------------------------------------------------------------
template <bool ACC, bool WF32, bool WBF16>
__global__ __launch_bounds__(256) void gemm_n64(
    const u16* __restrict__ A, const u16* __restrict__ B,
    float* __restrict__ C, u16* __restrict__ Cb, int M, int N, int K) {
  __shared__ u16 As[8192];  // [2][128][32]
  __shared__ u16 Bs[4096];  // [2][64][32]
  const int tid = threadIdx.x;
  const int w = tid >> 6;
  const int lane = tid & 63;

  const int gx = gridDim.x;  // N/64
  const int bid = blockIdx.y * gx + blockIdx.x;
  const int nwg = gx * gridDim.y;
  const int logical = (bid & 7) * (nwg >> 3) + (bid >> 3);
  const int bm = (logical / gx) << 7;
  const int bn = (logical % gx) << 6;

  const int r0 = (w << 4) + (lane >> 2);
  const int kc = (lane & 3) << 3;
  const u16* Ag0 = A + (size_t)(bm + r0) * K + kc;
  const u16* Ag1 = Ag0 + (size_t)64 * K;
  const u16* Bg0 = B + (size_t)(bn + r0) * K + kc;

  int aoff[2], boff[4];
#pragma unroll
  for (int m = 0; m < 2; ++m)
    aoff[m] = (((w << 5) + (m << 4) + (lane & 15)) << 5) + ((lane >> 4) << 3);
#pragma unroll
  for (int n = 0; n < 4; ++n)
    boff[n] = (((n << 4) + (lane & 15)) << 5) + ((lane >> 4) << 3);

  f32x4 acc[2][4];
#pragma unroll
  for (int m = 0; m < 2; ++m)
#pragma unroll
    for (int n = 0; n < 4; ++n) acc[m][n] = (f32x4){0.f, 0.f, 0.f, 0.f};

#define STAGE(buf, kt)                                                        \
  {                                                                           \
    u16* as_ = As + (buf) * 4096 + (w << 9);                                  \
    u16* bs_ = Bs + (buf) * 2048 + (w << 9);                                  \
    __builtin_amdgcn_global_load_lds(                                         \
        (const __attribute__((address_space(1))) void*)(Ag0 + (kt)),          \
        (__attribute__((address_space(3))) void*)as_, 16, 0, 0);              \
    __builtin_amdgcn_global_load_lds(                                         \
        (const __attribute__((address_space(1))) void*)(Ag1 + (kt)),          \
        (__attribute__((address_space(3))) void*)(as_ + 2048), 16, 0, 0);     \
    __builtin_amdgcn_global_load_lds(                                         \
        (const __attribute__((address_space(1))) void*)(Bg0 + (kt)),          \
        (__attribute__((address_space(3))) void*)bs_, 16, 0, 0);              \
  }

  const int nt = K >> 5;
  STAGE(0, 0);
  int cur = 0;
  for (int t = 0; t < nt; ++t) {
    if (t + 1 < nt) {
      STAGE(cur ^ 1, (t + 1) << 5);
      B1_WAIT(3)
    } else {
      B1_WAIT(0)
    }
    const u16* Ab = As + cur * 4096;
    const u16* Bb = Bs + cur * 2048;
    bf16x8 af[2], bfr[4];
#pragma unroll
    for (int m = 0; m < 2; ++m) af[m] = *(const bf16x8*)(Ab + aoff[m]);
#pragma unroll
    for (int n = 0; n < 4; ++n) bfr[n] = *(const bf16x8*)(Bb + boff[n]);
#pragma unroll
    for (int m = 0; m < 2; ++m)
#pragma unroll
      for (int n = 0; n < 4; ++n)
        acc[m][n] = __builtin_amdgcn_mfma_f32_16x16x32_bf16(
            af[m], bfr[n], acc[m][n], 0, 0, 0);
    B2_BAR()
    cur ^= 1;
  }
#undef STAGE

  const int rb = bm + (w << 5) + ((lane >> 4) << 2);
  const int cb = bn + (lane & 15);
#pragma unroll
  for (int m = 0; m < 2; ++m)
#pragma unroll
    for (int n = 0; n < 4; ++n) {
      int col = cb + (n << 4);
#pragma unroll
      for (int j = 0; j < 4; ++j) {
        size_t idx = (size_t)(rb + (m << 4) + j) * N + col;
        float v = acc[m][n][j];
        if (ACC) v += C[idx];
        if (WF32) C[idx] = v;
        if (WBF16) Cb[idx] = f2bf(v);
      }
    }
}

// ---------------------------------------------------------------------------
// LayerNorm over DT=512 per row; writes bf16 q_txt
// ---------------------------------------------------------------------------
__global__ __launch_bounds__(256) void ln_kernel(
    const float* __restrict__ m, const float* __restrict__ g,
    const float* __restrict__ bta, u16* __restrict__ q) {
  int row = blockIdx.x;
  int tid = threadIdx.x;
  float v0 = m[(size_t)row * 512 + tid];
  float v1 = m[(size_t)row * 512 + 256 + tid];
  __shared__ float red[4], red2[4];
  float s = v0 + v1;
#pragma unroll
  for (int d = 32; d; d >>= 1) s += __shfl_xor(s, d);
  if ((tid & 63) == 0) red[tid >> 6] = s;
  __syncthreads();
  float mu = (red[0] + red[1] + red[2] + red[3]) * (1.0f / 512.0f);
  float d0 = v0 - mu, d1 = v1 - mu;
  float s2 = d0 * d0 + d1 * d1;
#pragma unroll
  for (int d = 32; d; d >>= 1) s2 += __shfl_xor(s2, d);
  if ((tid & 63) == 0) red2[tid >> 6] = s2;
  __syncthreads();
  float var = (red2[0] + red2[1] + red2[2] + red2[3]) * (1.0f / 512.0f);
  float r = rsqrtf(var + 1e-5f);
  q[(size_t)row * 512 + tid] = f2bf(d0 * r * g[tid] + bta[tid]);
  q[(size_t)row * 512 + 256 + tid] = f2bf(d1 * r * g[tid + 256] + bta[tid + 256]);
}

// ---------------------------------------------------------------------------
// MFMA banded attention. Block = (b, 16 l), 512 threads = 8 waves.
// ---------------------------------------------------------------------------
__global__ __launch_bounds__(512) void attn_kernel(
    const u16* __restrict__ Qb, const u16* __restrict__ KV,
    const float* __restrict__ alpha_p, float* __restrict__ A,
    u16* __restrict__ Fv) {
  __shared__ u16 KV_s[96 * 512];   // 96 KB, K then reused for V
  __shared__ u16 Q_s[16 * 520];    // padded stride 520 u16
  __shared__ float S_s[16 * 100];  // logits then attention weights

  const int bid = blockIdx.x;
  const int logical = (bid & 7) * 64 + (bid >> 3);
  const int b = logical >> 4, lg = logical & 15;
  const int l0 = lg * 16;
  const int tid = threadIdx.x;
  const int w = tid >> 6, lane = tid & 63;
  const float al = *alpha_p;

  const int c_min = (1023 * l0) / 255;
  const int kb0 = min(max(c_min - BAND_, 0), N_ - 96);

  {
    const size_t rowb = (size_t)(b * N_ + kb0);
    for (int rr = 0; rr < 12; ++rr) {
      const int r = w * 12 + rr;
      const u16* src = KV + (rowb + r) * 1024 + ((lane * 8) ^ ((r & 7) << 3));
      u16* dst = KV_s + r * 512;
      __builtin_amdgcn_global_load_lds(
          (const __attribute__((address_space(1))) void*)src,
          (__attribute__((address_space(3))) void*)dst, 16, 0, 0);
    }
  }
  {
    const int r = tid >> 5;
    const u16* qrow = Qb + (size_t)(b * L_ + l0 + r) * 512;
#pragma unroll
    for (int h = 0; h < 2; ++h) {
      const int ch = (tid & 31) + h * 32;
      u16x8 v = *(const u16x8*)(qrow + ch * 8);
      *(u16x8*)(Q_s + r * 520 + ch * 8) = v;
    }
  }
  __syncthreads();

  if (w < 6) {
    f32x4 acc = {0.f, 0.f, 0.f, 0.f};
    const int arow = (lane & 15) * 520 + ((lane >> 4) << 3);
    const int key = w * 16 + (lane & 15);
    const int swz = (key & 7) << 3;
    for (int ks = 0; ks < 16; ++ks) {
      bf16x8 aq = *(const bf16x8*)(Q_s + arow + ks * 32);
      bf16x8 bk =
          *(const bf16x8*)(KV_s + key * 512 + ((ks * 32 + ((lane >> 4) << 3)) ^ swz));
      acc = __builtin_amdgcn_mfma_f32_16x16x32_bf16(aq, bk, acc, 0, 0, 0);
    }
#pragma unroll
    for (int j = 0; j < 4; ++j)
      S_s[((lane >> 4) * 4 + j) * 100 + w * 16 + (lane & 15)] = acc[j];
  }
  __syncthreads();

  {
    const size_t rowb = (size_t)(b * N_ + kb0);
    for (int rr = 0; rr < 12; ++rr) {
      const int r = w * 12 + rr;
      const u16* src =
          KV + (rowb + r) * 1024 + 512 + ((lane * 8) ^ ((r & 7) << 3));
      u16* dst = KV_s + r * 512;
      __builtin_amdgcn_global_load_lds(
          (const __attribute__((address_space(1))) void*)src,
          (__attribute__((address_space(3))) void*)dst, 16, 0, 0);
    }
  }

#pragma unroll
  for (int rr = 0; rr < 2; ++rr) {
    const int l = 2 * w + rr;
    const int c = (1023 * (l0 + l)) / 255;
    const int g0 = kb0 + lane, g1 = kb0 + 64 + lane;
    const bool v0 = (g0 >= c - BAND_) && (g0 <= c + BAND_);
    const bool v1 = (lane < 32) && (g1 >= c - BAND_) && (g1 <= c + BAND_);
    const float sc = 0.044194173824159216f;
    float x0 = v0 ? S_s[l * 100 + lane] * sc +
                        al * ((float)(c - g0) * (1.0f / 16.000001f))
                  : -INFINITY;
    float x1 = v1 ? S_s[l * 100 + 64 + lane] * sc +
                        al * ((float)(c - g1) * (1.0f / 16.000001f))
                  : -INFINITY;
    float mx = fmaxf(x0, x1);
#pragma unroll
    for (int d = 32; d; d >>= 1) mx = fmaxf(mx, __shfl_xor(mx, d));
    float e0 = v0 ? expf(x0 - mx) : 0.0f;
    float e1 = v1 ? expf(x1 - mx) : 0.0f;
    float sm = e0 + e1;
#pragma unroll
    for (int d = 32; d; d >>= 1) sm += __shfl_xor(sm, d);
    const float inv = 1.0f / sm;
    S_s[l * 100 + lane] = e0 * inv;
    if (lane < 32) S_s[l * 100 + 64 + lane] = e1 * inv;
    const int lo = max(0, c - BAND_), hi = min(N_ - 1, c + BAND_);
    float* Arow = A + (size_t)(b * L_ + l0 + l) * N_;
#pragma unroll
    for (int p4 = 0; p4 < 4; ++p4) {
      const int p = (p4 * 64 + lane) * 4;
      float4 v;
      v.x = (p + 0 >= lo && p + 0 <= hi) ? S_s[l * 100 + p + 0 - kb0] : 0.0f;
      v.y = (p + 1 >= lo && p + 1 <= hi) ? S_s[l * 100 + p + 1 - kb0] : 0.0f;
      v.z = (p + 2 >= lo && p + 2 <= hi) ? S_s[l * 100 + p + 2 - kb0] : 0.0f;
      v.w = (p + 3 >= lo && p + 3 <= hi) ? S_s[l * 100 + p + 3 - kb0] : 0.0f;
      ((float4*)Arow)[p4 * 64 + lane] = v;
    }
  }
  __syncthreads();

#pragma unroll
  for (int rr = 0; rr < 2; ++rr) {
    const int l = 2 * w + rr;
    const int c = (1023 * (l0 + l)) / 255;
    const int jlo = max(0, c - BAND_) - kb0, jhi = min(N_ - 1, c + BAND_) - kb0;
    float acc[8] = {};
    for (int j = jlo; j <= jhi; ++j) {
      const float avj = S_s[l * 100 + j];
      const u16x8 v =
          *(const u16x8*)(KV_s + j * 512 + ((lane * 8) ^ ((j & 7) << 3)));
#pragma unroll
      for (int t = 0; t < 8; ++t) acc[t] += avj * bf2f(v[t]);
    }
    u16x8 fo;
#pragma unroll
    for (int t = 0; t < 8; ++t) fo[t] = f2bf(acc[t]);
    *(u16x8*)(Fv + (size_t)(b * L_ + l0 + l) * 512 + lane * 8) = fo;
  }
}

// ---------------------------------------------------------------------------
extern "C" void kernel_launch(void* const* d_in, const int* in_sizes, int n_in,
                              void* d_out, int out_size, void* d_ws,
                              size_t ws_size, hipStream_t stream) {
  const float* vis = (const float*)d_in[0];    // [32,1024,512]
  const int* ids = (const int*)d_in[1];        // [32,256,8]
  const float* emb = (const float*)d_in[2];    // [1024,512]
  const float* wq = (const float*)d_in[3];     // [512,512]
  const float* wk = (const float*)d_in[4];     // [512,512]
  const float* wvp = (const float*)d_in[5];    // [512,512]
  const float* wv2t = (const float*)d_in[6];   // [512,512]
  const float* dwk = (const float*)d_in[7];    // [512,1,3]
  const float* pwk = (const float*)d_in[8];    // [512,512,1]
  const float* lng = (const float*)d_in[9];    // [512]
  const float* lnb = (const float*)d_in[10];   // [512]
  const float* alpha = (const float*)d_in[11]; // scalar

  float* out_cls = (float*)d_out;                // [8192,1024]
  float* out_H = out_cls + (size_t)8192 * 1024;  // [8192,512]
  float* out_A = out_H + (size_t)8192 * 512;     // [8192,1024]

  // workspace layout
  char* p = (char*)d_ws;
  u16* visb = (u16*)p;              p += (size_t)32768 * 512 * 2;
  u16* KVb  = (u16*)p;              p += (size_t)32768 * 1024 * 2;
  u16* embb = (u16*)p;              p += (size_t)1024 * 512 * 2;
  u16* wqb  = (u16*)p;              p += (size_t)512 * 512 * 2;
  u16* wkvb = (u16*)p;              p += (size_t)1024 * 512 * 2;
  u16* wv2tb= (u16*)p;              p += (size_t)512 * 512 * 2;
  u16* pwkb = (u16*)p;              p += (size_t)512 * 512 * 2;
  u16* shmb = (u16*)p;              p += (size_t)8192 * 512 * 2;
  float* mbuf = (float*)p;          p += (size_t)8192 * 512 * 4;
  u16* qbuf = (u16*)p;              p += (size_t)8192 * 512 * 2;
  u16* Qbf  = (u16*)p;              p += (size_t)8192 * 512 * 2;
  u16* Fvb  = (u16*)p;              p += (size_t)8192 * 512 * 2;
  u16* Hb   = (u16*)p;              p += (size_t)8192 * 512 * 2;

  // fused front: text_front + vis cvt (paired) + weight cvt (paired)
  mega_front<<<13184, 256, 0, stream>>>(
      vis, visb, emb, wq, wk, wvp, wv2t, pwk,
      embb, wqb, wkvb, wv2tb, pwkb, ids, dwk, shmb, mbuf);

  // KV = visb @ [wk;wv]^T -> bf16 [32768][1024]  (256x128 ring-3, 2 blk/CU)
  gemm_kv_v2<<<dim3(8, 128), 512, 0, stream>>>(
      visb, wkvb, KVb, 32768, 1024, 512);

  // m += shm_mean @ pw^T  (pointwise conv folded through mean)
  gemm_n64<true, true, false><<<dim3(8, 64), 256, 0, stream>>>(
      shmb, pwkb, mbuf, nullptr, 8192, 512, 512);
  // LayerNorm -> q_txt (bf16)
  ln_kernel<<<8192, 256, 0, stream>>>(mbuf, lng, lnb, qbuf);
  // Q = q_txt @ wq^T (bf16 out)
  gemm_n64<false, false, true><<<dim3(8, 64), 256, 0, stream>>>(
      qbuf, wqb, nullptr, Qbf, 8192, 512, 512);
  // banded attention (MFMA) -> A (full rows, f32), Fv (bf16)
  attn_kernel<<<512, 512, 0, stream>>>(Qbf, KVb, alpha, out_A, Fvb);
  // H = Fv @ wv2t^T (f32 out + bf16 copy)
  gemm_n64<false, true, true><<<dim3(8, 64), 256, 0, stream>>>(
      Fvb, wv2tb, out_H, Hb, 8192, 512, 512);
  // cls = H @ emb^T (f32 out)
  gemm_mfma<false, true, false><<<dim3(8, 64), 256, 0, stream>>>(
      Hb, embb, out_cls, nullptr, 8192, 1024, 512);
}

// Round 21
// 184.739 us; speedup vs baseline: 1.1524x; 1.0191x over previous
//
#include <hip/hip_runtime.h>
#include <cmath>

typedef unsigned short u16;
typedef __attribute__((ext_vector_type(8))) short bf16x8;
typedef __attribute__((ext_vector_type(4))) float f32x4;
typedef __attribute__((ext_vector_type(8))) unsigned short u16x8;

#define B_  32
#define N_  1024
#define L_  256
#define S_  8
#define DT_ 512
#define BAND_ 16

__device__ __forceinline__ u16 f2bf(float f) {
  union { float f; unsigned u; } x; x.f = f;
  unsigned r = (x.u + 0x7fffu + ((x.u >> 16) & 1u)) >> 16;
  return (u16)r;
}
__device__ __forceinline__ float bf2f(u16 h) {
  union { unsigned u; float f; } x; x.u = ((unsigned)h) << 16;
  return x.f;
}
// packed f32x2 -> bf16x2 (RNE), 1 instr
__device__ __forceinline__ unsigned cvtpk(float lo, float hi) {
  unsigned r;
  asm volatile("v_cvt_pk_bf16_f32 %0, %1, %2" : "=v"(r) : "v"(lo), "v"(hi));
  return r;
}

#define B1_WAIT(N)                                       \
  asm volatile("s_waitcnt vmcnt(" #N ")" ::: "memory");  \
  __builtin_amdgcn_s_barrier();                          \
  __builtin_amdgcn_sched_barrier(0);
#define B2_BAR()                                         \
  __builtin_amdgcn_sched_barrier(0);                     \
  __builtin_amdgcn_s_barrier();

// ---------------------------------------------------------------------------
// MEGA front v4. Grid 13184 x 256, exact work mapping.
// ---------------------------------------------------------------------------
__global__ __launch_bounds__(256) void mega_front(
    const float* __restrict__ vis, u16* __restrict__ visb,
    const float* __restrict__ e, const float* __restrict__ q,
    const float* __restrict__ k, const float* __restrict__ v,
    const float* __restrict__ t, const float* __restrict__ pw,
    u16* __restrict__ eo, u16* __restrict__ qo, u16* __restrict__ kvo,
    u16* __restrict__ to, u16* __restrict__ po,
    const int* __restrict__ ids, const float* __restrict__ dwk,
    u16* __restrict__ shm, float* __restrict__ mbuf) {
  const int blk = blockIdx.x;
  const int tid = threadIdx.x;
  if (blk < 4096) {
    const int c0 = tid * 2;
    const float2 d01 = *(const float2*)(dwk + 3 * c0 + 0);
    const float2 d23 = *(const float2*)(dwk + 3 * c0 + 2);
    const float2 d45 = *(const float2*)(dwk + 3 * c0 + 4);
#pragma unroll
    for (int ii = 0; ii < 2; ++ii) {
      const int bl = blk * 2 + ii;
      int sid[S_];
#pragma unroll
      for (int s = 0; s < S_; ++s) sid[s] = ids[bl * S_ + s];
      float2 x2[S_];
#pragma unroll
      for (int s = 0; s < S_; ++s)
        x2[s] = *(const float2*)(e + (size_t)sid[s] * DT_ + c0);
      float me0 = 0.f, sh0 = 0.f, me1 = 0.f, sh1 = 0.f;
#pragma unroll
      for (int s = 0; s < S_; ++s) {
        const float xm0 = (s > 0) ? x2[s - 1].x : 0.0f;
        const float xp0 = (s < S_ - 1) ? x2[s + 1].x : 0.0f;
        const float xm1 = (s > 0) ? x2[s - 1].y : 0.0f;
        const float xp1 = (s < S_ - 1) ? x2[s + 1].y : 0.0f;
        const float h0 = d01.x * xm0 + d01.y * x2[s].x + d23.x * xp0;
        const float h1 = d23.y * xm1 + d45.x * x2[s].y + d45.y * xp1;
        sh0 += h0 * __builtin_amdgcn_rcpf(1.0f + __expf(-h0));
        sh1 += h1 * __builtin_amdgcn_rcpf(1.0f + __expf(-h1));
        me0 += x2[s].x;
        me1 += x2[s].y;
      }
      ((unsigned*)shm)[((size_t)bl * DT_ + c0) >> 1] =
          cvtpk(sh0 * (1.0f / S_), sh1 * (1.0f / S_));
      *(float2*)(mbuf + (size_t)bl * DT_ + c0) =
          make_float2(me0 * (1.0f / S_), me1 * (1.0f / S_));
    }
  } else if (blk < 12288) {
    const int i0 = (blk - 4096) * 512 + tid;
    const float4 v0 = ((const float4*)vis)[i0];
    const float4 v1 = ((const float4*)vis)[i0 + 256];
    uint2 o0, o1;
    o0.x = cvtpk(v0.x, v0.y); o0.y = cvtpk(v0.z, v0.w);
    o1.x = cvtpk(v1.x, v1.y); o1.y = cvtpk(v1.z, v1.w);
    ((uint2*)visb)[i0] = o0;
    ((uint2*)visb)[i0 + 256] = o1;
  } else {
    const int base = (blk - 12288) * 512 + tid;
#pragma unroll
    for (int jj = 0; jj < 2; ++jj) {
      const int i = base + jj * 256;
      const float* src; u16* dst; int soff, doff;
      if (i < 131072)      { src = e;  dst = eo;  soff = i;          doff = soff; }
      else if (i < 196608) { src = q;  dst = qo;  soff = i - 131072; doff = soff; }
      else if (i < 262144) { src = k;  dst = kvo; soff = i - 196608; doff = soff; }
      else if (i < 327680) { src = v;  dst = kvo; soff = i - 262144; doff = soff + 65536; }
      else if (i < 393216) { src = t;  dst = to;  soff = i - 327680; doff = soff; }
      else                 { src = pw; dst = po;  soff = i - 393216; doff = soff; }
      float4 vv = ((const float4*)src)[soff];
      uint2 o;
      o.x = cvtpk(vv.x, vv.y);
      o.y = cvtpk(vv.z, vv.w);
      ((uint2*)dst)[doff] = o;
    }
  }
}

// ---------------------------------------------------------------------------
// GEMM v2 (256x128 tile, BK=32, 8 waves 4Mx2N, ring-2 LDS 48KB -> 3 blk/CU,
// counted vmcnt(3), T2 source-swizzle, setprio). C = A @ B^T, bf16 inputs.
// Output f32 (WF32) and/or bf16 (WBF16). Grid (N/128, M/256).
// ---------------------------------------------------------------------------
template <bool WF32, bool WBF16>
__global__ __launch_bounds__(512) void gemm_v2(
    const u16* __restrict__ A, const u16* __restrict__ B,
    float* __restrict__ C, u16* __restrict__ Cb, int M, int N, int K) {
  __shared__ u16 As[16384];  // [2][256][32]
  __shared__ u16 Bs[8192];   // [2][128][32]
  const int tid = threadIdx.x;
  const int w = tid >> 6;
  const int lane = tid & 63;
  const int wm = w >> 1, wn = w & 1;

  const int gx = gridDim.x;
  const int bid = blockIdx.y * gx + blockIdx.x;
  const int nwg = gx * gridDim.y;
  const int logical = (bid & 7) * (nwg >> 3) + (bid >> 3);
  const int bm = (logical / gx) << 8;
  const int bn = (logical % gx) << 7;

  const int rowA0 = (w << 5) + (lane >> 2);
  const int rowA1 = rowA0 + 16;
  const int rowB = (w << 4) + (lane >> 2);
  const int gac = (((lane & 3) ^ ((lane >> 3) & 3)) << 3);  // u16 offset
  const u16* AgS0 = A + (size_t)(bm + rowA0) * K + gac;
  const u16* AgS1 = A + (size_t)(bm + rowA1) * K + gac;
  const u16* BgS = B + (size_t)(bn + rowB) * K + gac;
  const int ldsA0 = (w << 10);
  const int ldsA1 = (w << 10) + 512;
  const int ldsB = (w << 9);

#define STAGE(step)                                                           \
  {                                                                           \
    const int bufA_ = ((step) & 1) << 13;                                     \
    const int bufB_ = ((step) & 1) << 12;                                     \
    const int ks_ = (step) << 5;                                              \
    __builtin_amdgcn_global_load_lds(                                         \
        (const __attribute__((address_space(1))) void*)(AgS0 + ks_),          \
        (__attribute__((address_space(3))) void*)(As + bufA_ + ldsA0), 16, 0, 0); \
    __builtin_amdgcn_global_load_lds(                                         \
        (const __attribute__((address_space(1))) void*)(AgS1 + ks_),          \
        (__attribute__((address_space(3))) void*)(As + bufA_ + ldsA1), 16, 0, 0); \
    __builtin_amdgcn_global_load_lds(                                         \
        (const __attribute__((address_space(1))) void*)(BgS + ks_),           \
        (__attribute__((address_space(3))) void*)(Bs + bufB_ + ldsB), 16, 0, 0); \
  }

  const int kg = lane >> 4;
  int aoff[4], boff[4];
#pragma unroll
  for (int m = 0; m < 4; ++m) {
    const int r = (wm << 6) + (m << 4) + (lane & 15);
    aoff[m] = (r << 5) + ((kg ^ ((r >> 1) & 3)) << 3);
  }
#pragma unroll
  for (int n = 0; n < 4; ++n) {
    const int r = (wn << 6) + (n << 4) + (lane & 15);
    boff[n] = (r << 5) + ((kg ^ ((r >> 1) & 3)) << 3);
  }

  f32x4 acc[4][4];
#pragma unroll
  for (int m = 0; m < 4; ++m)
#pragma unroll
    for (int n = 0; n < 4; ++n) acc[m][n] = (f32x4){0.f, 0.f, 0.f, 0.f};

#define GROUP_BODY(sbuf)                                                      \
  {                                                                           \
    const u16* Ab = As + ((sbuf) << 13);                                      \
    const u16* Bb = Bs + ((sbuf) << 12);                                      \
    bf16x8 af[4], bfr[4];                                                     \
    _Pragma("unroll")                                                         \
    for (int m = 0; m < 4; ++m) af[m] = *(const bf16x8*)(Ab + aoff[m]);       \
    _Pragma("unroll")                                                         \
    for (int n = 0; n < 4; ++n) bfr[n] = *(const bf16x8*)(Bb + boff[n]);      \
    asm volatile("s_waitcnt lgkmcnt(0)" ::: "memory");                        \
    __builtin_amdgcn_sched_barrier(0);                                        \
    __builtin_amdgcn_s_setprio(1);                                            \
    _Pragma("unroll")                                                         \
    for (int m = 0; m < 4; ++m)                                               \
      _Pragma("unroll")                                                       \
      for (int n = 0; n < 4; ++n)                                             \
        acc[m][n] = __builtin_amdgcn_mfma_f32_16x16x32_bf16(                  \
            af[m], bfr[n], acc[m][n], 0, 0, 0);                               \
    __builtin_amdgcn_s_setprio(0);                                            \
  }

  const int nt = K >> 5;  // 16
  STAGE(0)
  for (int s = 0; s < nt; ++s) {
    __builtin_amdgcn_s_barrier();  // prev group's reads done -> safe overwrite
    if (s + 1 < nt) {
      STAGE(s + 1)
      B1_WAIT(3)
    } else {
      B1_WAIT(0)
    }
    GROUP_BODY(s & 1)
  }
#undef GROUP_BODY
#undef STAGE

  const int rb = bm + (wm << 6) + ((lane >> 4) << 2);
  const int cb = bn + (wn << 6) + (lane & 15);
#pragma unroll
  for (int m = 0; m < 4; ++m)
#pragma unroll
    for (int n = 0; n < 4; ++n) {
      const int col = cb + (n << 4);
#pragma unroll
      for (int j = 0; j < 4; ++j) {
        size_t idx = (size_t)(rb + (m << 4) + j) * N + col;
        const float vv = acc[m][n][j];
        if (WF32) C[idx] = vv;
        if (WBF16) Cb[idx] = f2bf(vv);
      }
    }
}

// ---------------------------------------------------------------------------
// bf16 MFMA GEMM, 128x64 tile for N=512 GEMMs, counted-vmcnt (3 loads/STAGE).
// ---------------------------------------------------------------------------
template <bool ACC, bool WF32, bool WBF16>
__global__ __launch_bounds__(256) void gemm_n64(
    const u16* __restrict__ A, const u16* __restrict__ B,
    float* __restrict__ C, u16* __restrict__ Cb, int M, int N, int K) {
  __shared__ u16 As[8192];  // [2][128][32]
  __shared__ u16 Bs[4096];  // [2][64][32]
  const int tid = threadIdx.x;
  const int w = tid >> 6;
  const int lane = tid & 63;

  const int gx = gridDim.x;  // N/64
  const int bid = blockIdx.y * gx + blockIdx.x;
  const int nwg = gx * gridDim.y;
  const int logical = (bid & 7) * (nwg >> 3) + (bid >> 3);
  const int bm = (logical / gx) << 7;
  const int bn = (logical % gx) << 6;

  const int r0 = (w << 4) + (lane >> 2);
  const int kc = (lane & 3) << 3;
  const u16* Ag0 = A + (size_t)(bm + r0) * K + kc;
  const u16* Ag1 = Ag0 + (size_t)64 * K;
  const u16* Bg0 = B + (size_t)(bn + r0) * K + kc;

  int aoff[2], boff[4];
#pragma unroll
  for (int m = 0; m < 2; ++m)
    aoff[m] = (((w << 5) + (m << 4) + (lane & 15)) << 5) + ((lane >> 4) << 3);
#pragma unroll
  for (int n = 0; n < 4; ++n)
    boff[n] = (((n << 4) + (lane & 15)) << 5) + ((lane >> 4) << 3);

  f32x4 acc[2][4];
#pragma unroll
  for (int m = 0; m < 2; ++m)
#pragma unroll
    for (int n = 0; n < 4; ++n) acc[m][n] = (f32x4){0.f, 0.f, 0.f, 0.f};

#define STAGE(buf, kt)                                                        \
  {                                                                           \
    u16* as_ = As + (buf) * 4096 + (w << 9);                                  \
    u16* bs_ = Bs + (buf) * 2048 + (w << 9);                                  \
    __builtin_amdgcn_global_load_lds(                                         \
        (const __attribute__((address_space(1))) void*)(Ag0 + (kt)),          \
        (__attribute__((address_space(3))) void*)as_, 16, 0, 0);              \
    __builtin_amdgcn_global_load_lds(                                         \
        (const __attribute__((address_space(1))) void*)(Ag1 + (kt)),          \
        (__attribute__((address_space(3))) void*)(as_ + 2048), 16, 0, 0);     \
    __builtin_amdgcn_global_load_lds(                                         \
        (const __attribute__((address_space(1))) void*)(Bg0 + (kt)),          \
        (__attribute__((address_space(3))) void*)bs_, 16, 0, 0);              \
  }

  const int nt = K >> 5;
  STAGE(0, 0);
  int cur = 0;
  for (int t = 0; t < nt; ++t) {
    if (t + 1 < nt) {
      STAGE(cur ^ 1, (t + 1) << 5);
      B1_WAIT(3)
    } else {
      B1_WAIT(0)
    }
    const u16* Ab = As + cur * 4096;
    const u16* Bb = Bs + cur * 2048;
    bf16x8 af[2], bfr[4];
#pragma unroll
    for (int m = 0; m < 2; ++m) af[m] = *(const bf16x8*)(Ab + aoff[m]);
#pragma unroll
    for (int n = 0; n < 4; ++n) bfr[n] = *(const bf16x8*)(Bb + boff[n]);
#pragma unroll
    for (int m = 0; m < 2; ++m)
#pragma unroll
      for (int n = 0; n < 4; ++n)
        acc[m][n] = __builtin_amdgcn_mfma_f32_16x16x32_bf16(
            af[m], bfr[n], acc[m][n], 0, 0, 0);
    B2_BAR()
    cur ^= 1;
  }
#undef STAGE

  const int rb = bm + (w << 5) + ((lane >> 4) << 2);
  const int cb = bn + (lane & 15);
#pragma unroll
  for (int m = 0; m < 2; ++m)
#pragma unroll
    for (int n = 0; n < 4; ++n) {
      int col = cb + (n << 4);
#pragma unroll
      for (int j = 0; j < 4; ++j) {
        size_t idx = (size_t)(rb + (m << 4) + j) * N + col;
        float v = acc[m][n][j];
        if (ACC) v += C[idx];
        if (WF32) C[idx] = v;
        if (WBF16) Cb[idx] = f2bf(v);
      }
    }
}

// ---------------------------------------------------------------------------
// LayerNorm over DT=512 per row; writes bf16 q_txt
// ---------------------------------------------------------------------------
__global__ __launch_bounds__(256) void ln_kernel(
    const float* __restrict__ m, const float* __restrict__ g,
    const float* __restrict__ bta, u16* __restrict__ q) {
  int row = blockIdx.x;
  int tid = threadIdx.x;
  float v0 = m[(size_t)row * 512 + tid];
  float v1 = m[(size_t)row * 512 + 256 + tid];
  __shared__ float red[4], red2[4];
  float s = v0 + v1;
#pragma unroll
  for (int d = 32; d; d >>= 1) s += __shfl_xor(s, d);
  if ((tid & 63) == 0) red[tid >> 6] = s;
  __syncthreads();
  float mu = (red[0] + red[1] + red[2] + red[3]) * (1.0f / 512.0f);
  float d0 = v0 - mu, d1 = v1 - mu;
  float s2 = d0 * d0 + d1 * d1;
#pragma unroll
  for (int d = 32; d; d >>= 1) s2 += __shfl_xor(s2, d);
  if ((tid & 63) == 0) red2[tid >> 6] = s2;
  __syncthreads();
  float var = (red2[0] + red2[1] + red2[2] + red2[3]) * (1.0f / 512.0f);
  float r = rsqrtf(var + 1e-5f);
  q[(size_t)row * 512 + tid] = f2bf(d0 * r * g[tid] + bta[tid]);
  q[(size_t)row * 512 + 256 + tid] = f2bf(d1 * r * g[tid + 256] + bta[tid + 256]);
}

// ---------------------------------------------------------------------------
// MFMA banded attention. Block = (b, 16 l), 512 threads = 8 waves.
// ---------------------------------------------------------------------------
__global__ __launch_bounds__(512) void attn_kernel(
    const u16* __restrict__ Qb, const u16* __restrict__ KV,
    const float* __restrict__ alpha_p, float* __restrict__ A,
    u16* __restrict__ Fv) {
  __shared__ u16 KV_s[96 * 512];   // 96 KB, K then reused for V
  __shared__ u16 Q_s[16 * 520];    // padded stride 520 u16
  __shared__ float S_s[16 * 100];  // logits then attention weights

  const int bid = blockIdx.x;
  const int logical = (bid & 7) * 64 + (bid >> 3);
  const int b = logical >> 4, lg = logical & 15;
  const int l0 = lg * 16;
  const int tid = threadIdx.x;
  const int w = tid >> 6, lane = tid & 63;
  const float al = *alpha_p;

  const int c_min = (1023 * l0) / 255;
  const int kb0 = min(max(c_min - BAND_, 0), N_ - 96);

  {
    const size_t rowb = (size_t)(b * N_ + kb0);
    for (int rr = 0; rr < 12; ++rr) {
      const int r = w * 12 + rr;
      const u16* src = KV + (rowb + r) * 1024 + ((lane * 8) ^ ((r & 7) << 3));
      u16* dst = KV_s + r * 512;
      __builtin_amdgcn_global_load_lds(
          (const __attribute__((address_space(1))) void*)src,
          (__attribute__((address_space(3))) void*)dst, 16, 0, 0);
    }
  }
  {
    const int r = tid >> 5;
    const u16* qrow = Qb + (size_t)(b * L_ + l0 + r) * 512;
#pragma unroll
    for (int h = 0; h < 2; ++h) {
      const int ch = (tid & 31) + h * 32;
      u16x8 v = *(const u16x8*)(qrow + ch * 8);
      *(u16x8*)(Q_s + r * 520 + ch * 8) = v;
    }
  }
  __syncthreads();

  if (w < 6) {
    f32x4 acc = {0.f, 0.f, 0.f, 0.f};
    const int arow = (lane & 15) * 520 + ((lane >> 4) << 3);
    const int key = w * 16 + (lane & 15);
    const int swz = (key & 7) << 3;
    for (int ks = 0; ks < 16; ++ks) {
      bf16x8 aq = *(const bf16x8*)(Q_s + arow + ks * 32);
      bf16x8 bk =
          *(const bf16x8*)(KV_s + key * 512 + ((ks * 32 + ((lane >> 4) << 3)) ^ swz));
      acc = __builtin_amdgcn_mfma_f32_16x16x32_bf16(aq, bk, acc, 0, 0, 0);
    }
#pragma unroll
    for (int j = 0; j < 4; ++j)
      S_s[((lane >> 4) * 4 + j) * 100 + w * 16 + (lane & 15)] = acc[j];
  }
  __syncthreads();

  {
    const size_t rowb = (size_t)(b * N_ + kb0);
    for (int rr = 0; rr < 12; ++rr) {
      const int r = w * 12 + rr;
      const u16* src =
          KV + (rowb + r) * 1024 + 512 + ((lane * 8) ^ ((r & 7) << 3));
      u16* dst = KV_s + r * 512;
      __builtin_amdgcn_global_load_lds(
          (const __attribute__((address_space(1))) void*)src,
          (__attribute__((address_space(3))) void*)dst, 16, 0, 0);
    }
  }

#pragma unroll
  for (int rr = 0; rr < 2; ++rr) {
    const int l = 2 * w + rr;
    const int c = (1023 * (l0 + l)) / 255;
    const int g0 = kb0 + lane, g1 = kb0 + 64 + lane;
    const bool v0 = (g0 >= c - BAND_) && (g0 <= c + BAND_);
    const bool v1 = (lane < 32) && (g1 >= c - BAND_) && (g1 <= c + BAND_);
    const float sc = 0.044194173824159216f;
    float x0 = v0 ? S_s[l * 100 + lane] * sc +
                        al * ((float)(c - g0) * (1.0f / 16.000001f))
                  : -INFINITY;
    float x1 = v1 ? S_s[l * 100 + 64 + lane] * sc +
                        al * ((float)(c - g1) * (1.0f / 16.000001f))
                  : -INFINITY;
    float mx = fmaxf(x0, x1);
#pragma unroll
    for (int d = 32; d; d >>= 1) mx = fmaxf(mx, __shfl_xor(mx, d));
    float e0 = v0 ? expf(x0 - mx) : 0.0f;
    float e1 = v1 ? expf(x1 - mx) : 0.0f;
    float sm = e0 + e1;
#pragma unroll
    for (int d = 32; d; d >>= 1) sm += __shfl_xor(sm, d);
    const float inv = 1.0f / sm;
    S_s[l * 100 + lane] = e0 * inv;
    if (lane < 32) S_s[l * 100 + 64 + lane] = e1 * inv;
    const int lo = max(0, c - BAND_), hi = min(N_ - 1, c + BAND_);
    float* Arow = A + (size_t)(b * L_ + l0 + l) * N_;
#pragma unroll
    for (int p4 = 0; p4 < 4; ++p4) {
      const int p = (p4 * 64 + lane) * 4;
      float4 v;
      v.x = (p + 0 >= lo && p + 0 <= hi) ? S_s[l * 100 + p + 0 - kb0] : 0.0f;
      v.y = (p + 1 >= lo && p + 1 <= hi) ? S_s[l * 100 + p + 1 - kb0] : 0.0f;
      v.z = (p + 2 >= lo && p + 2 <= hi) ? S_s[l * 100 + p + 2 - kb0] : 0.0f;
      v.w = (p + 3 >= lo && p + 3 <= hi) ? S_s[l * 100 + p + 3 - kb0] : 0.0f;
      ((float4*)Arow)[p4 * 64 + lane] = v;
    }
  }
  __syncthreads();

#pragma unroll
  for (int rr = 0; rr < 2; ++rr) {
    const int l = 2 * w + rr;
    const int c = (1023 * (l0 + l)) / 255;
    const int jlo = max(0, c - BAND_) - kb0, jhi = min(N_ - 1, c + BAND_) - kb0;
    float acc[8] = {};
    for (int j = jlo; j <= jhi; ++j) {
      const float avj = S_s[l * 100 + j];
      const u16x8 v =
          *(const u16x8*)(KV_s + j * 512 + ((lane * 8) ^ ((j & 7) << 3)));
#pragma unroll
      for (int t = 0; t < 8; ++t) acc[t] += avj * bf2f(v[t]);
    }
    u16x8 fo;
#pragma unroll
    for (int t = 0; t < 8; ++t) fo[t] = f2bf(acc[t]);
    *(u16x8*)(Fv + (size_t)(b * L_ + l0 + l) * 512 + lane * 8) = fo;
  }
}

// ---------------------------------------------------------------------------
extern "C" void kernel_launch(void* const* d_in, const int* in_sizes, int n_in,
                              void* d_out, int out_size, void* d_ws,
                              size_t ws_size, hipStream_t stream) {
  const float* vis = (const float*)d_in[0];    // [32,1024,512]
  const int* ids = (const int*)d_in[1];        // [32,256,8]
  const float* emb = (const float*)d_in[2];    // [1024,512]
  const float* wq = (const float*)d_in[3];     // [512,512]
  const float* wk = (const float*)d_in[4];     // [512,512]
  const float* wvp = (const float*)d_in[5];    // [512,512]
  const float* wv2t = (const float*)d_in[6];   // [512,512]
  const float* dwk = (const float*)d_in[7];    // [512,1,3]
  const float* pwk = (const float*)d_in[8];    // [512,512,1]
  const float* lng = (const float*)d_in[9];    // [512]
  const float* lnb = (const float*)d_in[10];   // [512]
  const float* alpha = (const float*)d_in[11]; // scalar

  float* out_cls = (float*)d_out;                // [8192,1024]
  float* out_H = out_cls + (size_t)8192 * 1024;  // [8192,512]
  float* out_A = out_H + (size_t)8192 * 512;     // [8192,1024]

  // workspace layout
  char* p = (char*)d_ws;
  u16* visb = (u16*)p;              p += (size_t)32768 * 512 * 2;
  u16* KVb  = (u16*)p;              p += (size_t)32768 * 1024 * 2;
  u16* embb = (u16*)p;              p += (size_t)1024 * 512 * 2;
  u16* wqb  = (u16*)p;              p += (size_t)512 * 512 * 2;
  u16* wkvb = (u16*)p;              p += (size_t)1024 * 512 * 2;
  u16* wv2tb= (u16*)p;              p += (size_t)512 * 512 * 2;
  u16* pwkb = (u16*)p;              p += (size_t)512 * 512 * 2;
  u16* shmb = (u16*)p;              p += (size_t)8192 * 512 * 2;
  float* mbuf = (float*)p;          p += (size_t)8192 * 512 * 4;
  u16* qbuf = (u16*)p;              p += (size_t)8192 * 512 * 2;
  u16* Qbf  = (u16*)p;              p += (size_t)8192 * 512 * 2;
  u16* Fvb  = (u16*)p;              p += (size_t)8192 * 512 * 2;
  u16* Hb   = (u16*)p;              p += (size_t)8192 * 512 * 2;

  // fused front: text_front + vis cvt (paired) + weight cvt (paired)
  mega_front<<<13184, 256, 0, stream>>>(
      vis, visb, emb, wq, wk, wvp, wv2t, pwk,
      embb, wqb, wkvb, wv2tb, pwkb, ids, dwk, shmb, mbuf);

  // KV = visb @ [wk;wv]^T -> bf16 [32768][1024]  (256x128 ring-2, 3 blk/CU)
  gemm_v2<false, true><<<dim3(8, 128), 512, 0, stream>>>(
      visb, wkvb, nullptr, KVb, 32768, 1024, 512);

  // m += shm_mean @ pw^T  (pointwise conv folded through mean)
  gemm_n64<true, true, false><<<dim3(8, 64), 256, 0, stream>>>(
      shmb, pwkb, mbuf, nullptr, 8192, 512, 512);
  // LayerNorm -> q_txt (bf16)
  ln_kernel<<<8192, 256, 0, stream>>>(mbuf, lng, lnb, qbuf);
  // Q = q_txt @ wq^T (bf16 out)
  gemm_n64<false, false, true><<<dim3(8, 64), 256, 0, stream>>>(
      qbuf, wqb, nullptr, Qbf, 8192, 512, 512);
  // banded attention (MFMA) -> A (full rows, f32), Fv (bf16)
  attn_kernel<<<512, 512, 0, stream>>>(Qbf, KVb, alpha, out_A, Fvb);
  // H = Fv @ wv2t^T (f32 out + bf16 copy)
  gemm_n64<false, true, true><<<dim3(8, 64), 256, 0, stream>>>(
      Fvb, wv2tb, out_H, Hb, 8192, 512, 512);
  // cls = H @ emb^T (f32 out, 256x128 v2 structure)
  gemm_v2<true, false><<<dim3(8, 32), 512, 0, stream>>>(
      Hb, embb, out_cls, nullptr, 8192, 1024, 512);
}